// Round 1
// baseline (909.294 us; speedup 1.0000x reference)
//
#include <hip/hip_runtime.h>

#define NB 16
#define NT 960000
#define NS 6001
#define STRIDEF 160
#define WLEN 257
#define LAGS 214      // lags 0..213
#define NCAND 212
#define TOPK 15
#define NSTEPS 6000
#define CHUNK 50
#define NCHUNK 120
#define FLOORV -100000.0f

// ---- workspace layout (offsets in floats) ----
constexpr size_t OFF_NACW  = 0;                                    // 214 floats
constexpr size_t OFF_GPEAK = 256;                                  // 16 floats (max|x| bits)
constexpr size_t OFF_FREQ  = 512;
constexpr size_t PERFR     = (size_t)NB * NS * 16;                 // per-frame arrays, K padded to 16
constexpr size_t OFF_LF    = OFF_FREQ + PERFR;
constexpr size_t OFF_DELTA = OFF_LF + PERFR;
constexpr size_t OFF_VOIC  = OFF_DELTA + PERFR;
constexpr size_t OFF_P     = OFF_VOIC + PERFR;                     // NB*NCHUNK*256 chunk matrices
constexpr size_t OFF_VENT  = OFF_P + (size_t)NB * NCHUNK * 256;    // NB*(NCHUNK+1)*16 entry vectors
constexpr size_t OFF_VFIN  = OFF_VENT + (size_t)NB * (NCHUNK + 1) * 16; // 16*16 final values
constexpr size_t OFF_F0    = OFF_VFIN + 256;                       // NB*NS f0 (pre-median)
constexpr size_t OFF_BS    = OFF_F0 + 96032;                       // int32 boundary states NB*(NCHUNK+1)
constexpr size_t OFF_PTR   = OFF_BS + 2048;                        // uint8 ptrs NB*NSTEPS*16 bytes
constexpr size_t OFF_BMAP  = OFF_PTR + (size_t)NB * NSTEPS * 4;    // uint8 backmaps NB*NCHUNK*16 bytes

__device__ __forceinline__ unsigned ordf(float f) {
  unsigned u = __float_as_uint(f);
  return (u & 0x80000000u) ? ~u : (u | 0x80000000u);
}

// ---------- K0: window autocorrelation (nacw) + zero gpeak ----------
__global__ __launch_bounds__(256) void k_setup(float* __restrict__ ws) {
  __shared__ float win[WLEN];
  __shared__ float w0sh;
  const int tid = threadIdx.x;
  for (int n = tid; n < WLEN; n += 256)
    win[n] = 0.5f * (1.0f - cosf((6.2831855f * (float)n) / 257.0f));
  __syncthreads();
  float s = 0.f;
  if (tid < LAGS) {
    for (int n = 0; n + tid < WLEN; ++n) s += win[n] * win[n + tid];
  }
  if (tid == 0) w0sh = s;
  __syncthreads();
  if (tid < LAGS) ws[OFF_NACW + tid] = s / w0sh;
  if (tid < NB) ws[OFF_GPEAK + tid] = 0.0f;
}

// ---------- K1: per-batch global peak of |x| ----------
__global__ __launch_bounds__(256) void k_gpeak(const float* __restrict__ x, float* __restrict__ ws) {
  const int b = blockIdx.y;
  const float4* xb = (const float4*)(x + (size_t)b * NT);
  const int n4 = NT / 4;
  float m = 0.f;
  for (int i = blockIdx.x * blockDim.x + threadIdx.x; i < n4; i += gridDim.x * blockDim.x) {
    float4 v = xb[i];
    m = fmaxf(m, fmaxf(fmaxf(fabsf(v.x), fabsf(v.y)), fmaxf(fabsf(v.z), fabsf(v.w))));
  }
  for (int off = 32; off; off >>= 1) m = fmaxf(m, __shfl_down(m, off));
  __shared__ float sm[4];
  if ((threadIdx.x & 63) == 0) sm[threadIdx.x >> 6] = m;
  __syncthreads();
  if (threadIdx.x == 0) {
    m = fmaxf(fmaxf(sm[0], sm[1]), fmaxf(sm[2], sm[3]));
    atomicMax((unsigned*)(ws + OFF_GPEAK) + b, __float_as_uint(m));
  }
}

// ---------- K2: frames -> nacf -> candidates -> top-15 -> per-frame arrays ----------
__global__ __launch_bounds__(256) void k_frames(const float* __restrict__ x, float* __restrict__ ws) {
  const int s = blockIdx.x, b = blockIdx.y, tid = threadIdx.x;
  __shared__ float fr[480];          // windowed frame, zero-padded tail
  __shared__ float accs[4][216];     // per-part partial ACF
  __shared__ float nacf[LAGS];
  __shared__ float freq_s[NCAND];
  __shared__ float logit_s[NCAND];
  __shared__ float red[4];
  __shared__ float misc[2];          // [0]=mean, [1]=local peak
  __shared__ int sel[TOPK];

  const int base = s * STRIDEF;
  float v0, v1 = 0.f;
  {
    int n = base + tid;
    v0 = (n < NT) ? x[(size_t)b * NT + n] : 0.f;
  }
  if (tid == 0) {
    int n = base + 256;
    v1 = (n < NT) ? x[(size_t)b * NT + n] : 0.f;
  }
  // mean over 257 raw samples
  float ps = v0 + v1;
  for (int off = 32; off; off >>= 1) ps += __shfl_down(ps, off);
  if ((tid & 63) == 0) red[tid >> 6] = ps;
  __syncthreads();
  if (tid == 0) misc[0] = (red[0] + red[1] + red[2] + red[3]) / 257.0f;
  __syncthreads();
  const float mean = misc[0];
  // windowed frame + local peak
  float w0 = 0.5f * (1.0f - cosf((6.2831855f * (float)tid) / 257.0f));
  float f0v = (v0 - mean) * w0;
  fr[tid] = f0v;
  float apk = fabsf(f0v);
  if (tid == 0) {
    float w1 = 0.5f * (1.0f - cosf((6.2831855f * 256.0f) / 257.0f));
    float f1v = (v1 - mean) * w1;
    fr[256] = f1v;
    apk = fmaxf(apk, fabsf(f1v));
  }
  for (int i = WLEN + tid; i < 480; i += 256) fr[i] = 0.f;
  for (int off = 32; off; off >>= 1) apk = fmaxf(apk, __shfl_down(apk, off));
  if ((tid & 63) == 0) red[tid >> 6] = apk;
  __syncthreads();
  if (tid == 0) misc[1] = fmaxf(fmaxf(red[0], red[1]), fmaxf(red[2], red[3]));
  __syncthreads();  // fr fully visible

  // ACF: wave p handles n in [64p, 64p+63] (p=3 also n=256); lane g -> lags 4g..4g+3
  const int g = tid & 63;
  const int p = tid >> 6;
  if (g < 54) {
    const float4* fr4 = (const float4*)fr;
    const int q0 = p * 16;
    const int q1 = (p == 3) ? 65 : q0 + 16;
    float a0 = 0.f, a1 = 0.f, a2 = 0.f, a3 = 0.f;
    float4 fb = fr4[q0 + g];
    for (int q = q0; q < q1; ++q) {
      float4 fn = fr4[q];     // broadcast
      float4 fa = fb;
      fb = fr4[q + g + 1];
      a0 += fn.x * fa.x; a0 += fn.y * fa.y; a0 += fn.z * fa.z; a0 += fn.w * fa.w;
      a1 += fn.x * fa.y; a1 += fn.y * fa.z; a1 += fn.z * fa.w; a1 += fn.w * fb.x;
      a2 += fn.x * fa.z; a2 += fn.y * fa.w; a2 += fn.z * fb.x; a2 += fn.w * fb.y;
      a3 += fn.x * fa.w; a3 += fn.y * fb.x; a3 += fn.z * fb.y; a3 += fn.w * fb.z;
    }
    accs[p][4 * g + 0] = a0; accs[p][4 * g + 1] = a1;
    accs[p][4 * g + 2] = a2; accs[p][4 * g + 3] = a3;
  }
  __syncthreads();
  if (tid < 216) accs[0][tid] = accs[0][tid] + accs[1][tid] + accs[2][tid] + accs[3][tid];
  __syncthreads();
  if (tid < LAGS) nacf[tid] = accs[0][tid] / (accs[0][0] * ws[OFF_NACW + tid]);
  __syncthreads();

  // candidates (lag = tid+1)
  if (tid < NCAND) {
    float pm = nacf[tid], cm = nacf[tid + 1], nm = nacf[tid + 2];
    float dl = cm - pm, drr = nm - cm;
    bool flag = (dl >= 0.f) && (drr <= 0.f) && (cm > 0.225f);
    float dr = (0.5f * (nm - pm)) / ((2.0f * cm - nm) - pm);
    float tq = dr + (float)tid;
    tq = (tq > 0.f) ? tq : 0.f;          // NaN -> 0: output-invariant (unvoiced either way)
    float fq = 16000.0f / (1.0f + tq);
    float lg = cm;
    if (lg > 1.0f) lg = 1.0f / lg;
    lg = lg - 0.01f * log2f(75.0f / fq);
    freq_s[tid] = fq;
    logit_s[tid] = flag ? lg : FLOORV;
  }
  __syncthreads();

  // top-15, ties -> lowest index (key = ord(value)<<32 | ~index)
  if (tid < 64) {
    unsigned long long keys[4];
#pragma unroll
    for (int r = 0; r < 4; ++r) {
      int c = tid + 64 * r;
      keys[r] = (c < NCAND)
        ? ((((unsigned long long)ordf(logit_s[c])) << 32) | (unsigned long long)(0xFFFFFFFFu - (unsigned)c))
        : 0ull;
    }
    for (int k = 0; k < TOPK; ++k) {
      unsigned long long m = keys[0];
      if (keys[1] > m) m = keys[1];
      if (keys[2] > m) m = keys[2];
      if (keys[3] > m) m = keys[3];
#pragma unroll
      for (int off = 1; off < 64; off <<= 1) {
        unsigned long long o = __shfl_xor(m, off);
        if (o > m) m = o;
      }
#pragma unroll
      for (int r = 0; r < 4; ++r) if (keys[r] == m) keys[r] = 0ull;
      if (tid == 0) sel[k] = (int)(0xFFFFFFFFu - (unsigned)(m & 0xFFFFFFFFull));
    }
  }
  __syncthreads();

  if (tid < TOPK) {
    int c = sel[tid];
    float fq = freq_s[c];
    float lg = logit_s[c];
    int voi = (lg > FLOORV) && (fq < 600.0f);
    float gp = ws[OFF_GPEAK + b];
    float lp = misc[1];
    float inten = (lp > gp) ? 1.0f : (lp / gp);
    float luv = 0.45f + fmaxf(2.0f - inten / (float)(0.03 / 1.45), 0.f);
    float dlt = voi ? (lg - 0.01f * log2f(600.0f / fq)) : luv;
    size_t fi = ((size_t)b * NS + s) * 16 + tid;
    ws[OFF_FREQ + fi] = fq;
    ws[OFF_LF + fi] = log2f(fq);
    ws[OFF_DELTA + fi] = dlt;
    ws[OFF_VOIC + fi] = voi ? 1.f : 0.f;
  }
}

// transition cost (shared by chunkmat/viterbi)
__device__ __forceinline__ float trans_cost(bool vi, bool vj, float lfi, float lfj) {
  if (vi != vj) return 0.14f;
  if (!vi) return 0.f;
  return 0.35f * fabsf(lfi - lfj);
}

// ---------- K3: per-chunk max-plus product matrices ----------
__global__ __launch_bounds__(256) void k_chunkmat(float* __restrict__ ws) {
  const int c = blockIdx.x, b = blockIdx.y, tid = threadIdx.x;
  const int i = tid >> 4, j = tid & 15;
  const bool act = (i < 15) && (j < 15);
  __shared__ float P[2][15][16];
  __shared__ float M[15][16];
  __shared__ float lfA[16], vA[16], lfB[16], vB[16], dB[16];
  const int t0 = c * CHUNK;
  if (tid < TOPK) {
    size_t fi = ((size_t)b * NS + t0) * 16 + tid;
    lfA[tid] = ws[OFF_LF + fi]; vA[tid] = ws[OFF_VOIC + fi];
  }
  for (int step = 1; step <= CHUNK; ++step) {
    const int t = t0 + step;
    if (tid < TOPK) {
      size_t fi = ((size_t)b * NS + t) * 16 + tid;
      lfB[tid] = ws[OFF_LF + fi]; vB[tid] = ws[OFF_VOIC + fi]; dB[tid] = ws[OFF_DELTA + fi];
    }
    __syncthreads();
    if (act) {
      float tr = trans_cost(vA[i] != 0.f, vB[j] != 0.f, lfA[i], lfB[j]);
      M[i][j] = dB[j] - tr;
    }
    __syncthreads();
    if (act) {
      if (step == 1) {
        P[0][i][j] = M[i][j];
      } else {
        const int src = step & 1;  // step2: src 0 -> dst 1; alternate
        float best = -INFINITY;
#pragma unroll
        for (int k = 0; k < 15; ++k) best = fmaxf(best, P[src][i][k] + M[k][j]);
        P[src ^ 1][i][j] = best;
      }
    }
    if (tid < TOPK) { lfA[tid] = lfB[tid]; vA[tid] = vB[tid]; }
    __syncthreads();
  }
  if (act) ws[OFF_P + ((size_t)(b * NCHUNK + c)) * 256 + (i * 16 + j)] = P[1][i][j];
}

// ---------- K4: scan chunk matrices -> entry value vectors ----------
__global__ __launch_bounds__(256) void k_scan(float* __restrict__ ws) {
  const int b = blockIdx.x, tid = threadIdx.x;
  __shared__ float v[16];
  __shared__ float Pm[16][16];
  if (tid < TOPK) {
    float d0 = ws[OFF_DELTA + ((size_t)b * NS + 0) * 16 + tid];
    v[tid] = d0;
    ws[OFF_VENT + ((size_t)b * (NCHUNK + 1) + 0) * 16 + tid] = d0;
  }
  __syncthreads();
  for (int c = 0; c < NCHUNK; ++c) {
    Pm[tid >> 4][tid & 15] = ws[OFF_P + ((size_t)(b * NCHUNK + c)) * 256 + tid];
    __syncthreads();
    float nv = 0.f;
    if (tid < TOPK) {
      float best = -INFINITY;
#pragma unroll
      for (int k = 0; k < 15; ++k) best = fmaxf(best, v[k] + Pm[k][tid]);
      nv = best;
    }
    __syncthreads();
    if (tid < TOPK) {
      v[tid] = nv;
      ws[OFF_VENT + ((size_t)b * (NCHUNK + 1) + (c + 1)) * 16 + tid] = nv;
    }
    __syncthreads();
  }
}

// ---------- K5: per-chunk sequential Viterbi (exact op order) -> ptrs + backmaps ----------
__global__ __launch_bounds__(256) void k_viterbi(float* __restrict__ ws) {
  const int c = blockIdx.x, b = blockIdx.y, tid = threadIdx.x;
  const int i = tid & 15, j = tid >> 4;   // 16-lane groups share j
  const bool act = (i < 15) && (j < 15);
  __shared__ float val[16];
  __shared__ float lfA[16], vA[16], lfB[16], vB[16], dB[16];
  __shared__ unsigned char ptl[CHUNK][16];
  const int t0 = c * CHUNK;
  if (tid < TOPK) {
    val[tid] = ws[OFF_VENT + ((size_t)b * (NCHUNK + 1) + c) * 16 + tid];
    size_t fi = ((size_t)b * NS + t0) * 16 + tid;
    lfA[tid] = ws[OFF_LF + fi]; vA[tid] = ws[OFF_VOIC + fi];
  }
  unsigned char* pg = (unsigned char*)(ws + OFF_PTR);
  for (int step = 1; step <= CHUNK; ++step) {
    const int t = t0 + step;
    if (tid < TOPK) {
      size_t fi = ((size_t)b * NS + t) * 16 + tid;
      lfB[tid] = ws[OFF_LF + fi]; vB[tid] = ws[OFF_VOIC + fi]; dB[tid] = ws[OFF_DELTA + fi];
    }
    __syncthreads();
    float sc = -INFINITY;
    int bi = i;
    if (act) {
      float tr = trans_cost(vA[i] != 0.f, vB[j] != 0.f, lfA[i], lfB[j]);
      sc = (val[i] - tr) + dB[j];   // reference op order
    }
#pragma unroll
    for (int off = 1; off < 16; off <<= 1) {
      float so = __shfl_xor(sc, off);
      int io = __shfl_xor(bi, off);
      if (so > sc || (so == sc && io < bi)) { sc = so; bi = io; }
    }
    __syncthreads();
    if (act && i == 0) {
      val[j] = sc;
      ptl[step - 1][j] = (unsigned char)bi;
      pg[((size_t)b * NSTEPS + (t - 1)) * 16 + j] = (unsigned char)bi;
    }
    if (tid < TOPK) { lfA[tid] = lfB[tid]; vA[tid] = vB[tid]; }
    __syncthreads();
  }
  // per-chunk backtrack map: exit state -> entry state
  if (tid < TOPK) {
    int st = tid;
#pragma unroll 1
    for (int s2 = CHUNK - 1; s2 >= 0; --s2) st = ptl[s2][st];
    ((unsigned char*)(ws + OFF_BMAP))[((size_t)(b * NCHUNK + c)) * 16 + tid] = (unsigned char)st;
  }
  if (c == NCHUNK - 1 && tid < TOPK) ws[OFF_VFIN + (size_t)b * 16 + tid] = val[tid];
}

// ---------- K6: compose backmaps -> chunk-boundary states ----------
__global__ __launch_bounds__(256) void k_compose(float* __restrict__ ws) {
  __shared__ unsigned char bm[NB * NCHUNK * 16];
  const int tid = threadIdx.x;
  const unsigned char* bg = (const unsigned char*)(ws + OFF_BMAP);
  for (int idx = tid; idx < NB * NCHUNK * 16; idx += 256) bm[idx] = bg[idx];
  __syncthreads();
  if (tid < NB) {
    const int b = tid;
    float best = -INFINITY; int bi = 0;
    for (int jj = 0; jj < TOPK; ++jj) {
      float vv = ws[OFF_VFIN + (size_t)b * 16 + jj];
      if (vv > best) { best = vv; bi = jj; }   // strict > : first max
    }
    int* bs = (int*)(ws + OFF_BS);
    int st = bi;
    bs[b * (NCHUNK + 1) + NCHUNK] = st;
    for (int cc = NCHUNK - 1; cc >= 0; --cc) {
      st = bm[((size_t)(b * NCHUNK + cc)) * 16 + st];
      bs[b * (NCHUNK + 1) + cc] = st;
    }
  }
}

// ---------- K7: per-chunk state walk -> f0 ----------
__global__ __launch_bounds__(64) void k_select(float* __restrict__ ws) {
  const int c = blockIdx.x, b = blockIdx.y, tid = threadIdx.x;
  __shared__ unsigned char pl[CHUNK * 16];
  __shared__ int stt[CHUNK + 1];
  const int t0 = c * CHUNK;
  const unsigned char* pg = (const unsigned char*)(ws + OFF_PTR);
  for (int idx = tid; idx < CHUNK * 16; idx += 64)
    pl[idx] = pg[((size_t)b * NSTEPS + t0) * 16 + idx];
  __syncthreads();
  if (tid == 0) {
    const int* bs = (const int*)(ws + OFF_BS);
    int st = bs[b * (NCHUNK + 1) + (c + 1)];
    stt[CHUNK] = st;
    for (int s2 = CHUNK; s2 >= 1; --s2) { st = pl[(s2 - 1) * 16 + st]; stt[s2 - 1] = st; }
  }
  __syncthreads();
  const int nt = (c == NCHUNK - 1) ? (CHUNK + 1) : CHUNK;
  if (tid < nt) {
    const int t = t0 + tid;
    const int st = stt[tid];
    size_t fi = ((size_t)b * NS + t) * 16 + st;
    float fq = ws[OFF_FREQ + fi];
    float vv = ws[OFF_VOIC + fi];
    ws[OFF_F0 + (size_t)b * NS + t] = (vv != 0.f) ? fq : 0.f;
  }
}

// ---------- K8: median-5 with edge padding ----------
__global__ __launch_bounds__(256) void k_median(const float* __restrict__ ws, float* __restrict__ out) {
  const int b = blockIdx.y;
  const int t = blockIdx.x * 256 + threadIdx.x;
  if (t >= NS) return;
  const float* f0 = ws + OFF_F0 + (size_t)b * NS;
  float a0 = f0[max(t - 2, 0)];
  float a1 = f0[max(t - 1, 0)];
  float a2 = f0[t];
  float a3 = f0[min(t + 1, NS - 1)];
  float a4 = f0[min(t + 2, NS - 1)];
#define SW(u, w) { float lo_ = fminf(u, w), hi_ = fmaxf(u, w); u = lo_; w = hi_; }
  SW(a0, a1) SW(a1, a2) SW(a2, a3) SW(a3, a4)
  SW(a0, a1) SW(a1, a2) SW(a2, a3)
  SW(a0, a1) SW(a1, a2)
#undef SW
  out[(size_t)b * NS + t] = a2;
}

extern "C" void kernel_launch(void* const* d_in, const int* in_sizes, int n_in,
                              void* d_out, int out_size, void* d_ws, size_t ws_size,
                              hipStream_t stream) {
  const float* x = (const float*)d_in[0];
  float* ws = (float*)d_ws;
  float* out = (float*)d_out;
  hipLaunchKernelGGL(k_setup, dim3(1), dim3(256), 0, stream, ws);
  hipLaunchKernelGGL(k_gpeak, dim3(64, NB), dim3(256), 0, stream, x, ws);
  hipLaunchKernelGGL(k_frames, dim3(NS, NB), dim3(256), 0, stream, x, ws);
  hipLaunchKernelGGL(k_chunkmat, dim3(NCHUNK, NB), dim3(256), 0, stream, ws);
  hipLaunchKernelGGL(k_scan, dim3(NB), dim3(256), 0, stream, ws);
  hipLaunchKernelGGL(k_viterbi, dim3(NCHUNK, NB), dim3(256), 0, stream, ws);
  hipLaunchKernelGGL(k_compose, dim3(1), dim3(256), 0, stream, ws);
  hipLaunchKernelGGL(k_select, dim3(NCHUNK, NB), dim3(64), 0, stream, ws);
  hipLaunchKernelGGL(k_median, dim3((NS + 255) / 256, NB), dim3(256), 0, stream, ws, out);
}

// Round 2
// 642.561 us; speedup vs baseline: 1.4151x; 1.4151x over previous
//
#include <hip/hip_runtime.h>

#define NB 16
#define NT 960000
#define NS 6001
#define STRIDEF 160
#define WLEN 257
#define LAGS 214
#define NCAND 212
#define TOPK 15
#define NSTEPS 6000
#define CHUNK 50
#define NCHUNK 120
#define FLOORV -100000.0f

// ---- workspace layout (offsets in floats) ----
constexpr size_t OFF_NACW  = 0;                                    // 216 floats (INVERSE nacw)
constexpr size_t OFF_WIN   = 256;                                  // 257 floats (hann window)
constexpr size_t OFF_GPEAK = 520;                                  // 16 floats (max|x| bits)
constexpr size_t OFF_FREQ  = 576;
constexpr size_t PERFR     = (size_t)NB * NS * 16;                 // per-frame arrays, K padded to 16
constexpr size_t OFF_LF    = OFF_FREQ + PERFR;
constexpr size_t OFF_DELTA = OFF_LF + PERFR;
constexpr size_t OFF_VOIC  = OFF_DELTA + PERFR;
constexpr size_t OFF_P     = OFF_VOIC + PERFR;                     // NB*NCHUNK*256 chunk matrices
constexpr size_t OFF_VENT  = OFF_P + (size_t)NB * NCHUNK * 256;    // NB*(NCHUNK+1)*16 entry vectors
constexpr size_t OFF_VFIN  = OFF_VENT + (size_t)NB * (NCHUNK + 1) * 16; // 16*16 final values
constexpr size_t OFF_F0    = OFF_VFIN + 256;                       // NB*NS f0 (pre-median)
constexpr size_t OFF_BS    = OFF_F0 + 96032;                       // int32 boundary states NB*(NCHUNK+1)
constexpr size_t OFF_PTR   = OFF_BS + 2048;                        // uint8 ptrs NB*NSTEPS*16 bytes
constexpr size_t OFF_BMAP  = OFF_PTR + (size_t)NB * NSTEPS * 4;    // uint8 backmaps NB*NCHUNK*16 bytes

__device__ __forceinline__ float rdlane(float v, int lane) {
  return __int_as_float(__builtin_amdgcn_readlane(__float_as_int(v), lane));
}

// ---------- K0: window + inverse window-ACF + zero gpeak ----------
__global__ __launch_bounds__(256) void k_setup(float* __restrict__ ws) {
  __shared__ float win[WLEN];
  __shared__ float w0sh;
  const int tid = threadIdx.x;
  for (int n = tid; n < WLEN; n += 256) {
    float w = 0.5f * (1.0f - cosf((6.2831855f * (float)n) / 257.0f));
    win[n] = w;
    ws[OFF_WIN + n] = w;
  }
  __syncthreads();
  float s = 0.f;
  if (tid < 216) {
    for (int n = 0; n + tid < WLEN; ++n) s += win[n] * win[n + tid];
  }
  if (tid == 0) w0sh = s;
  __syncthreads();
  if (tid < 216) ws[OFF_NACW + tid] = w0sh / s;   // inverse of nacw
  if (tid < NB) ws[OFF_GPEAK + tid] = 0.0f;
}

// ---------- K1: per-batch global peak of |x| ----------
__global__ __launch_bounds__(256) void k_gpeak(const float* __restrict__ x, float* __restrict__ ws) {
  const int b = blockIdx.y;
  const float4* xb = (const float4*)(x + (size_t)b * NT);
  const int n4 = NT / 4;
  float m = 0.f;
  for (int i = blockIdx.x * blockDim.x + threadIdx.x; i < n4; i += gridDim.x * blockDim.x) {
    float4 v = xb[i];
    m = fmaxf(m, fmaxf(fmaxf(fabsf(v.x), fabsf(v.y)), fmaxf(fabsf(v.z), fabsf(v.w))));
  }
  for (int off = 32; off; off >>= 1) m = fmaxf(m, __shfl_down(m, off));
  __shared__ float sm[4];
  if ((threadIdx.x & 63) == 0) sm[threadIdx.x >> 6] = m;
  __syncthreads();
  if (threadIdx.x == 0) {
    m = fmaxf(fmaxf(sm[0], sm[1]), fmaxf(sm[2], sm[3]));
    atomicMax((unsigned*)(ws + OFF_GPEAK) + b, __float_as_uint(m));
  }
}

// ---------- K2: one wave = one frame, barrier-free ----------
__global__ __launch_bounds__(256, 6) void k_frames(const float* __restrict__ x, float* __restrict__ ws) {
  const int wv = threadIdx.x >> 6;
  const int g  = threadIdx.x & 63;
  const int s  = blockIdx.x * 4 + wv;
  const int b  = blockIdx.y;
  __shared__ float lds_all[4][1152];   // per wave: fr4[0..119] | nacf @480 (chunks 120..175) | freq @704 (176..229) | logit @920 (230..283)
  __shared__ int   selsh[4][16];
  if (s >= NS) return;
  float* L = lds_all[wv];
  float4* L4 = (float4*)L;
  const size_t xb = (size_t)b * NT;
  const int c0 = 40 * s;               // float4 chunk base (160s bytes-aligned: 640s/16)

  // ---- load frame ----
  float4 xv = make_float4(0.f, 0.f, 0.f, 0.f);
  if (c0 + g < NT / 4) xv = ((const float4*)(x + xb))[c0 + g];
  const int i256 = 160 * s + 256;
  const float x256 = (i256 < NT) ? x[xb + i256] : 0.f;

  // ---- mean over 257 raw samples (wave butterfly) ----
  float ps = ((xv.x + xv.y) + (xv.z + xv.w)) + ((g == 0) ? x256 : 0.f);
#pragma unroll
  for (int off = 32; off; off >>= 1) ps += __shfl_xor(ps, off);
  const float mean = ps / 257.0f;

  // ---- window + local peak ----
  float4 w4 = ((const float4*)(ws + OFF_WIN))[g];
  const float w256 = ws[OFF_WIN + 256];
  float4 f4;
  f4.x = (xv.x - mean) * w4.x;
  f4.y = (xv.y - mean) * w4.y;
  f4.z = (xv.z - mean) * w4.z;
  f4.w = (xv.w - mean) * w4.w;
  const float fr256 = (x256 - mean) * w256;
  float apk = fmaxf(fmaxf(fabsf(f4.x), fabsf(f4.y)), fmaxf(fabsf(f4.z), fabsf(f4.w)));
  apk = fmaxf(apk, fabsf(fr256));
#pragma unroll
  for (int off = 32; off; off >>= 1) apk = fmaxf(apk, __shfl_xor(apk, off));

  // ---- stage frame to LDS (zero-padded) ----
  L4[g] = f4;
  if (g == 0) L4[64] = make_float4(fr256, 0.f, 0.f, 0.f);
  if (g < 54) L4[65 + g] = make_float4(0.f, 0.f, 0.f, 0.f);

  // ---- ACF: lane g owns lags 4g..4g+3; fn broadcast via readlane (VALU, not LDS) ----
  float a0 = 0.f, a1 = 0.f, a2 = 0.f, a3 = 0.f;
  if (g < 54) {
    float4 fb = L4[g];
    for (int q = 0; q < 64; ++q) {
      float fnx = rdlane(f4.x, q);
      float fny = rdlane(f4.y, q);
      float fnz = rdlane(f4.z, q);
      float fnw = rdlane(f4.w, q);
      float4 fa = fb;
      fb = L4[q + g + 1];
      a0 += fnx * fa.x; a0 += fny * fa.y; a0 += fnz * fa.z; a0 += fnw * fa.w;
      a1 += fnx * fa.y; a1 += fny * fa.z; a1 += fnz * fa.w; a1 += fnw * fb.x;
      a2 += fnx * fa.z; a2 += fny * fa.w; a2 += fnz * fb.x; a2 += fnw * fb.y;
      a3 += fnx * fa.w; a3 += fny * fb.x; a3 += fnz * fb.y; a3 += fnw * fb.z;
    }
    // q = 64 tail: fn = (fr256,0,0,0), fa = chunk 64+g (== fb)
    a0 += fr256 * fb.x;
    a1 += fr256 * fb.y;
    a2 += fr256 * fb.z;
    a3 += fr256 * fb.w;
  }

  // ---- nacf ----
  const float acf0 = rdlane(a0, 0);
  const float s_inv = 1.0f / acf0;
  float4 nc = make_float4(0.f, 0.f, 0.f, 0.f);
  if (g < 54) {
    float4 inw = ((const float4*)(ws + OFF_NACW))[g];
    nc.x = a0 * s_inv * inw.x;
    nc.y = a1 * s_inv * inw.y;
    nc.z = a2 * s_inv * inw.z;
    nc.w = a3 * s_inv * inw.w;
    L4[120 + g] = nc;
  }

  // ---- candidates (lane g: candidates 4g..4g+3, valid for g<53) ----
  bool fl0 = false, fl1 = false, fl2 = false, fl3 = false;
  if (g < 53) {
    float4 nb = L4[121 + g];   // same-wave cross-lane via LDS: ordered by lgkmcnt
    float nn[8] = {nc.x, nc.y, nc.z, nc.w, nb.x, nb.y, nb.z, nb.w};
    float fqv[4], lgv[4];
    bool flv[4];
#pragma unroll
    for (int a = 0; a < 4; ++a) {
      float pm = nn[a], cm = nn[a + 1], nm = nn[a + 2];
      bool flag = (cm - pm >= 0.f) && (nm - cm <= 0.f) && (cm > 0.225f);
      float dr = (0.5f * (nm - pm)) / ((2.0f * cm - nm) - pm);
      float tq = dr + (float)(4 * g + a);
      tq = (tq > 0.f) ? tq : 0.f;     // NaN -> 0: output-invariant (candidate unvoiced either way)
      float fq = 16000.0f / (1.0f + tq);
      float lg = cm;
      if (lg > 1.0f) lg = 1.0f / lg;
      lg = lg - 0.01f * log2f(75.0f / fq);
      flv[a] = flag;
      fqv[a] = fq;
      lgv[a] = flag ? lg : FLOORV;
    }
    fl0 = flv[0]; fl1 = flv[1]; fl2 = flv[2]; fl3 = flv[3];
    L4[176 + g] = make_float4(fqv[0], fqv[1], fqv[2], fqv[3]);
    L4[230 + g] = make_float4(lgv[0], lgv[1], lgv[2], lgv[3]);
  }

  // ---- top-15: ballot fast path ----
  unsigned long long bb0 = __ballot(fl0);
  unsigned long long bb1 = __ballot(fl1);
  unsigned long long bb2 = __ballot(fl2);
  unsigned long long bb3 = __ballot(fl3);
  const int nv = __popcll(bb0) + __popcll(bb1) + __popcll(bb2) + __popcll(bb3);

  if (nv != 0 && g == 0) {
    // exact stable top-15: voiced (value desc, index asc) then FLOOR fill by index
    float bv[TOPK]; int bic[TOPK]; int cnt = 0;
    unsigned long long bba[4] = {bb0, bb1, bb2, bb3};
    for (int a = 0; a < 4; ++a) {
      unsigned long long t = bba[a];
      while (t) {
        int lz = __ffsll((long long)t) - 1;
        t &= t - 1;
        int c = 4 * lz + a;
        float v = L[920 + c];
        if (cnt < TOPK) {
          int p = cnt++;
          while (p > 0 && (bv[p - 1] < v || (bv[p - 1] == v && bic[p - 1] > c))) {
            bv[p] = bv[p - 1]; bic[p] = bic[p - 1]; --p;
          }
          bv[p] = v; bic[p] = c;
        } else if (v > bv[TOPK - 1] || (v == bv[TOPK - 1] && c < bic[TOPK - 1])) {
          int p = TOPK - 1;
          while (p > 0 && (bv[p - 1] < v || (bv[p - 1] == v && bic[p - 1] > c))) {
            bv[p] = bv[p - 1]; bic[p] = bic[p - 1]; --p;
          }
          bv[p] = v; bic[p] = c;
        }
      }
    }
    int k = cnt, c = 0;
    while (k < TOPK) {
      bool isv = (bba[c & 3] >> (c >> 2)) & 1ull;
      if (!isv) { bic[k] = c; ++k; }
      ++c;
    }
    for (int k2 = 0; k2 < TOPK; ++k2) selsh[wv][k2] = bic[k2];
  }

  // ---- per-frame outputs (lanes 0..14) ----
  if (g < TOPK) {
    int c = (nv == 0) ? g : selsh[wv][g];
    float fq = L[704 + c];
    float lg = L[920 + c];
    int voi = (lg > FLOORV) && (fq < 600.0f);
    float gp = ws[OFF_GPEAK + b];
    float inten = (apk > gp) ? 1.0f : (apk / gp);
    float luv = 0.45f + fmaxf(2.0f - inten / (float)(0.03 / 1.45), 0.f);
    float dlt = voi ? (lg - 0.01f * log2f(600.0f / fq)) : luv;
    size_t fi = ((size_t)b * NS + s) * 16 + g;
    ws[OFF_FREQ + fi] = fq;
    ws[OFF_LF + fi] = log2f(fq);
    ws[OFF_DELTA + fi] = dlt;
    ws[OFF_VOIC + fi] = voi ? 1.f : 0.f;
  }
}

// transition cost (shared by chunkmat/viterbi)
__device__ __forceinline__ float trans_cost(bool vi, bool vj, float lfi, float lfj) {
  if (vi != vj) return 0.14f;
  if (!vi) return 0.f;
  return 0.35f * fabsf(lfi - lfj);
}

// ---------- K3: per-chunk max-plus product matrices ----------
__global__ __launch_bounds__(256) void k_chunkmat(float* __restrict__ ws) {
  const int c = blockIdx.x, b = blockIdx.y, tid = threadIdx.x;
  const int i = tid >> 4, j = tid & 15;
  const bool act = (i < 15) && (j < 15);
  __shared__ float P[2][15][16];
  __shared__ float M[15][16];
  __shared__ float lfA[16], vA[16], lfB[16], vB[16], dB[16];
  const int t0 = c * CHUNK;
  if (tid < TOPK) {
    size_t fi = ((size_t)b * NS + t0) * 16 + tid;
    lfA[tid] = ws[OFF_LF + fi]; vA[tid] = ws[OFF_VOIC + fi];
  }
  for (int step = 1; step <= CHUNK; ++step) {
    const int t = t0 + step;
    if (tid < TOPK) {
      size_t fi = ((size_t)b * NS + t) * 16 + tid;
      lfB[tid] = ws[OFF_LF + fi]; vB[tid] = ws[OFF_VOIC + fi]; dB[tid] = ws[OFF_DELTA + fi];
    }
    __syncthreads();
    if (act) {
      float tr = trans_cost(vA[i] != 0.f, vB[j] != 0.f, lfA[i], lfB[j]);
      M[i][j] = dB[j] - tr;
    }
    __syncthreads();
    if (act) {
      if (step == 1) {
        P[0][i][j] = M[i][j];
      } else {
        const int src = step & 1;
        float best = -INFINITY;
#pragma unroll
        for (int k = 0; k < 15; ++k) best = fmaxf(best, P[src][i][k] + M[k][j]);
        P[src ^ 1][i][j] = best;
      }
    }
    if (tid < TOPK) { lfA[tid] = lfB[tid]; vA[tid] = vB[tid]; }
    __syncthreads();
  }
  if (act) ws[OFF_P + ((size_t)(b * NCHUNK + c)) * 256 + (i * 16 + j)] = P[1][i][j];
}

// ---------- K4: scan chunk matrices -> entry value vectors ----------
__global__ __launch_bounds__(256) void k_scan(float* __restrict__ ws) {
  const int b = blockIdx.x, tid = threadIdx.x;
  __shared__ float v[16];
  __shared__ float Pm[16][16];
  if (tid < TOPK) {
    float d0 = ws[OFF_DELTA + ((size_t)b * NS + 0) * 16 + tid];
    v[tid] = d0;
    ws[OFF_VENT + ((size_t)b * (NCHUNK + 1) + 0) * 16 + tid] = d0;
  }
  __syncthreads();
  for (int c = 0; c < NCHUNK; ++c) {
    Pm[tid >> 4][tid & 15] = ws[OFF_P + ((size_t)(b * NCHUNK + c)) * 256 + tid];
    __syncthreads();
    float nv = 0.f;
    if (tid < TOPK) {
      float best = -INFINITY;
#pragma unroll
      for (int k = 0; k < 15; ++k) best = fmaxf(best, v[k] + Pm[k][tid]);
      nv = best;
    }
    __syncthreads();
    if (tid < TOPK) {
      v[tid] = nv;
      ws[OFF_VENT + ((size_t)b * (NCHUNK + 1) + (c + 1)) * 16 + tid] = nv;
    }
    __syncthreads();
  }
}

// ---------- K5: per-chunk sequential Viterbi (exact op order) -> ptrs + backmaps ----------
__global__ __launch_bounds__(256) void k_viterbi(float* __restrict__ ws) {
  const int c = blockIdx.x, b = blockIdx.y, tid = threadIdx.x;
  const int i = tid & 15, j = tid >> 4;
  const bool act = (i < 15) && (j < 15);
  __shared__ float val[16];
  __shared__ float lfA[16], vA[16], lfB[16], vB[16], dB[16];
  __shared__ unsigned char ptl[CHUNK][16];
  const int t0 = c * CHUNK;
  if (tid < TOPK) {
    val[tid] = ws[OFF_VENT + ((size_t)b * (NCHUNK + 1) + c) * 16 + tid];
    size_t fi = ((size_t)b * NS + t0) * 16 + tid;
    lfA[tid] = ws[OFF_LF + fi]; vA[tid] = ws[OFF_VOIC + fi];
  }
  unsigned char* pg = (unsigned char*)(ws + OFF_PTR);
  for (int step = 1; step <= CHUNK; ++step) {
    const int t = t0 + step;
    if (tid < TOPK) {
      size_t fi = ((size_t)b * NS + t) * 16 + tid;
      lfB[tid] = ws[OFF_LF + fi]; vB[tid] = ws[OFF_VOIC + fi]; dB[tid] = ws[OFF_DELTA + fi];
    }
    __syncthreads();
    float sc = -INFINITY;
    int bi = i;
    if (act) {
      float tr = trans_cost(vA[i] != 0.f, vB[j] != 0.f, lfA[i], lfB[j]);
      sc = (val[i] - tr) + dB[j];   // reference op order
    }
#pragma unroll
    for (int off = 1; off < 16; off <<= 1) {
      float so = __shfl_xor(sc, off);
      int io = __shfl_xor(bi, off);
      if (so > sc || (so == sc && io < bi)) { sc = so; bi = io; }
    }
    __syncthreads();
    if (act && i == 0) {
      val[j] = sc;
      ptl[step - 1][j] = (unsigned char)bi;
      pg[((size_t)b * NSTEPS + (t - 1)) * 16 + j] = (unsigned char)bi;
    }
    if (tid < TOPK) { lfA[tid] = lfB[tid]; vA[tid] = vB[tid]; }
    __syncthreads();
  }
  if (tid < TOPK) {
    int st = tid;
#pragma unroll 1
    for (int s2 = CHUNK - 1; s2 >= 0; --s2) st = ptl[s2][st];
    ((unsigned char*)(ws + OFF_BMAP))[((size_t)(b * NCHUNK + c)) * 16 + tid] = (unsigned char)st;
  }
  if (c == NCHUNK - 1 && tid < TOPK) ws[OFF_VFIN + (size_t)b * 16 + tid] = val[tid];
}

// ---------- K6: compose backmaps -> chunk-boundary states ----------
__global__ __launch_bounds__(256) void k_compose(float* __restrict__ ws) {
  __shared__ unsigned char bm[NB * NCHUNK * 16];
  const int tid = threadIdx.x;
  const unsigned char* bg = (const unsigned char*)(ws + OFF_BMAP);
  for (int idx = tid; idx < NB * NCHUNK * 16; idx += 256) bm[idx] = bg[idx];
  __syncthreads();
  if (tid < NB) {
    const int b = tid;
    float best = -INFINITY; int bi = 0;
    for (int jj = 0; jj < TOPK; ++jj) {
      float vv = ws[OFF_VFIN + (size_t)b * 16 + jj];
      if (vv > best) { best = vv; bi = jj; }
    }
    int* bs = (int*)(ws + OFF_BS);
    int st = bi;
    bs[b * (NCHUNK + 1) + NCHUNK] = st;
    for (int cc = NCHUNK - 1; cc >= 0; --cc) {
      st = bm[((size_t)(b * NCHUNK + cc)) * 16 + st];
      bs[b * (NCHUNK + 1) + cc] = st;
    }
  }
}

// ---------- K7: per-chunk state walk -> f0 ----------
__global__ __launch_bounds__(64) void k_select(float* __restrict__ ws) {
  const int c = blockIdx.x, b = blockIdx.y, tid = threadIdx.x;
  __shared__ unsigned char pl[CHUNK * 16];
  __shared__ int stt[CHUNK + 1];
  const int t0 = c * CHUNK;
  const unsigned char* pg = (const unsigned char*)(ws + OFF_PTR);
  for (int idx = tid; idx < CHUNK * 16; idx += 64)
    pl[idx] = pg[((size_t)b * NSTEPS + t0) * 16 + idx];
  __syncthreads();
  if (tid == 0) {
    const int* bs = (const int*)(ws + OFF_BS);
    int st = bs[b * (NCHUNK + 1) + (c + 1)];
    stt[CHUNK] = st;
    for (int s2 = CHUNK; s2 >= 1; --s2) { st = pl[(s2 - 1) * 16 + st]; stt[s2 - 1] = st; }
  }
  __syncthreads();
  const int nt = (c == NCHUNK - 1) ? (CHUNK + 1) : CHUNK;
  if (tid < nt) {
    const int t = t0 + tid;
    const int st = stt[tid];
    size_t fi = ((size_t)b * NS + t) * 16 + st;
    float fq = ws[OFF_FREQ + fi];
    float vv = ws[OFF_VOIC + fi];
    ws[OFF_F0 + (size_t)b * NS + t] = (vv != 0.f) ? fq : 0.f;
  }
}

// ---------- K8: median-5 with edge padding ----------
__global__ __launch_bounds__(256) void k_median(const float* __restrict__ ws, float* __restrict__ out) {
  const int b = blockIdx.y;
  const int t = blockIdx.x * 256 + threadIdx.x;
  if (t >= NS) return;
  const float* f0 = ws + OFF_F0 + (size_t)b * NS;
  float a0 = f0[max(t - 2, 0)];
  float a1 = f0[max(t - 1, 0)];
  float a2 = f0[t];
  float a3 = f0[min(t + 1, NS - 1)];
  float a4 = f0[min(t + 2, NS - 1)];
#define SW(u, w) { float lo_ = fminf(u, w), hi_ = fmaxf(u, w); u = lo_; w = hi_; }
  SW(a0, a1) SW(a1, a2) SW(a2, a3) SW(a3, a4)
  SW(a0, a1) SW(a1, a2) SW(a2, a3)
  SW(a0, a1) SW(a1, a2)
#undef SW
  out[(size_t)b * NS + t] = a2;
}

extern "C" void kernel_launch(void* const* d_in, const int* in_sizes, int n_in,
                              void* d_out, int out_size, void* d_ws, size_t ws_size,
                              hipStream_t stream) {
  const float* x = (const float*)d_in[0];
  float* ws = (float*)d_ws;
  float* out = (float*)d_out;
  hipLaunchKernelGGL(k_setup, dim3(1), dim3(256), 0, stream, ws);
  hipLaunchKernelGGL(k_gpeak, dim3(64, NB), dim3(256), 0, stream, x, ws);
  hipLaunchKernelGGL(k_frames, dim3((NS + 3) / 4, NB), dim3(256), 0, stream, x, ws);
  hipLaunchKernelGGL(k_chunkmat, dim3(NCHUNK, NB), dim3(256), 0, stream, ws);
  hipLaunchKernelGGL(k_scan, dim3(NB), dim3(256), 0, stream, ws);
  hipLaunchKernelGGL(k_viterbi, dim3(NCHUNK, NB), dim3(256), 0, stream, ws);
  hipLaunchKernelGGL(k_compose, dim3(1), dim3(256), 0, stream, ws);
  hipLaunchKernelGGL(k_select, dim3(NCHUNK, NB), dim3(64), 0, stream, ws);
  hipLaunchKernelGGL(k_median, dim3((NS + 255) / 256, NB), dim3(256), 0, stream, ws, out);
}

// Round 3
// 370.313 us; speedup vs baseline: 2.4555x; 1.7352x over previous
//
#include <hip/hip_runtime.h>

#define NB 16
#define NT 960000
#define NS 6001
#define STRIDEF 160
#define WLEN 257
#define LAGS 214
#define NCAND 212
#define TOPK 15
#define NSTEPS 6000
#define CHUNK 50
#define NCHUNK 120
#define FLOORV -100000.0f

typedef __attribute__((ext_vector_type(8))) short short8;
typedef __attribute__((ext_vector_type(4))) float f32x4;
typedef __attribute__((ext_vector_type(2))) float f32x2;
typedef __attribute__((ext_vector_type(4))) unsigned int u32x4;

// ---- workspace layout (offsets in floats) ----
constexpr size_t OFF_NACW  = 0;                                    // 216 floats (INVERSE nacw)
constexpr size_t OFF_WIN   = 256;                                  // 257 floats (hann window)
constexpr size_t OFF_GPEAK = 520;                                  // 16 floats (max|x| bits)
constexpr size_t OFF_FREQ  = 576;
constexpr size_t PERFR     = (size_t)NB * NS * 16;                 // per-frame arrays, K padded to 16
constexpr size_t OFF_LF    = OFF_FREQ + PERFR;
constexpr size_t OFF_DELTA = OFF_LF + PERFR;
constexpr size_t OFF_VOIC  = OFF_DELTA + PERFR;
constexpr size_t OFF_P     = OFF_VOIC + PERFR;                     // NB*NCHUNK*256 chunk matrices
constexpr size_t OFF_VENT  = OFF_P + (size_t)NB * NCHUNK * 256;    // NB*(NCHUNK+1)*16 entry vectors
constexpr size_t OFF_VFIN  = OFF_VENT + (size_t)NB * (NCHUNK + 1) * 16; // 16*16 final values
constexpr size_t OFF_F0    = OFF_VFIN + 256;                       // NB*NS f0 (pre-median)
constexpr size_t OFF_BS    = OFF_F0 + 96032;                       // int32 boundary states NB*(NCHUNK+1)
constexpr size_t OFF_PTR   = OFF_BS + 2048;                        // uint8 ptrs NB*NSTEPS*16 bytes
constexpr size_t OFF_BMAP  = OFF_PTR + (size_t)NB * NSTEPS * 4;    // uint8 backmaps NB*NCHUNK*16 bytes

// ---------- K0: window + inverse window-ACF + zero gpeak ----------
__global__ __launch_bounds__(256) void k_setup(float* __restrict__ ws) {
  __shared__ float win[WLEN];
  __shared__ float w0sh;
  const int tid = threadIdx.x;
  for (int n = tid; n < WLEN; n += 256) {
    float w = 0.5f * (1.0f - cosf((6.2831855f * (float)n) / 257.0f));
    win[n] = w;
    ws[OFF_WIN + n] = w;
  }
  __syncthreads();
  float s = 0.f;
  if (tid < 216) {
    for (int n = 0; n + tid < WLEN; ++n) s += win[n] * win[n + tid];
  }
  if (tid == 0) w0sh = s;
  __syncthreads();
  if (tid < 216) ws[OFF_NACW + tid] = w0sh / s;   // inverse of nacw
  if (tid < NB) ws[OFF_GPEAK + tid] = 0.0f;
}

// ---------- K1: per-batch global peak of |x| ----------
__global__ __launch_bounds__(256) void k_gpeak(const float* __restrict__ x, float* __restrict__ ws) {
  const int b = blockIdx.y;
  const float4* xb = (const float4*)(x + (size_t)b * NT);
  const int n4 = NT / 4;
  float m = 0.f;
  for (int i = blockIdx.x * blockDim.x + threadIdx.x; i < n4; i += gridDim.x * blockDim.x) {
    float4 v = xb[i];
    m = fmaxf(m, fmaxf(fmaxf(fabsf(v.x), fabsf(v.y)), fmaxf(fabsf(v.z), fabsf(v.w))));
  }
  for (int off = 32; off; off >>= 1) m = fmaxf(m, __shfl_down(m, off));
  __shared__ float sm[4];
  if ((threadIdx.x & 63) == 0) sm[threadIdx.x >> 6] = m;
  __syncthreads();
  if (threadIdx.x == 0) {
    m = fmaxf(fmaxf(sm[0], sm[1]), fmaxf(sm[2], sm[3]));
    atomicMax((unsigned*)(ws + OFF_GPEAK) + b, __float_as_uint(m));
  }
}

__device__ __forceinline__ unsigned bf16rne(float f) {
  unsigned u = __float_as_uint(f);
  return (u + 0x7FFFu + ((u >> 16) & 1u)) >> 16;   // bf16 bits in low 16
}

__device__ __forceinline__ short8 bfrag(const char* base, int bb, int sh, bool hi2) {
  f32x2 r0 = *(const f32x2*)(base + bb);
  f32x2 r1 = *(const f32x2*)(base + bb + 8);
  f32x2 r2 = *(const f32x2*)(base + bb + 16);
  unsigned w0 = __float_as_uint(r0.x), w1 = __float_as_uint(r0.y);
  unsigned w2 = __float_as_uint(r1.x), w3 = __float_as_uint(r1.y);
  unsigned w4 = __float_as_uint(r2.x), w5 = __float_as_uint(r2.y);
  unsigned u0 = __builtin_amdgcn_alignbit(w1, w0, sh);
  unsigned u1 = __builtin_amdgcn_alignbit(w2, w1, sh);
  unsigned u2 = __builtin_amdgcn_alignbit(w3, w2, sh);
  unsigned u3 = __builtin_amdgcn_alignbit(w4, w3, sh);
  unsigned u4 = __builtin_amdgcn_alignbit(w5, w4, sh);
  u32x4 o;
  o[0] = hi2 ? u1 : u0;
  o[1] = hi2 ? u2 : u1;
  o[2] = hi2 ? u3 : u2;
  o[3] = hi2 ? u4 : u3;
  return __builtin_bit_cast(short8, o);
}

// ---------- K2: one wave = one frame; bf16x3-split MFMA ACF; parallel top-k ----------
__global__ __launch_bounds__(256, 4) void k_frames(const float* __restrict__ x, float* __restrict__ ws) {
  const int wv = threadIdx.x >> 6;
  const int g  = threadIdx.x & 63;
  const int s  = blockIdx.x * 4 + wv;
  const int b  = blockIdx.y;
  // per wave (floats): HI bf16[576] @[0,288) | LO @[288,576) | ACF @[576,800)
  //                    FREQ @[800,1016) | LOGIT @[1016,1232) | CMPV @[1232,1444)
  //                    CMPI bytes @[1444,1498) | SEL ints @[1500,1516)
  __shared__ __align__(16) float LA[4][1520];
  if (s >= NS) return;
  float* L = LA[wv];
  char* Lb = (char*)L;
  const size_t xb = (size_t)b * NT;
  const int c0 = 40 * s;               // float4 chunk base

  // ---- load frame ----
  float4 xv = make_float4(0.f, 0.f, 0.f, 0.f);
  if (c0 + g < NT / 4) xv = ((const float4*)(x + xb))[c0 + g];
  float x256 = 0.f;
  if (g == 0) {
    int i256 = 160 * s + 256;
    if (i256 < NT) x256 = x[xb + i256];
  }

  // ---- mean over 257 raw samples ----
  float ps = ((xv.x + xv.y) + (xv.z + xv.w)) + x256;
#pragma unroll
  for (int off = 32; off; off >>= 1) ps += __shfl_xor(ps, off);
  const float mean = ps / 257.0f;

  // ---- window + local peak ----
  float4 w4 = ((const float4*)(ws + OFF_WIN))[g];
  float4 f4;
  f4.x = (xv.x - mean) * w4.x;
  f4.y = (xv.y - mean) * w4.y;
  f4.z = (xv.z - mean) * w4.z;
  f4.w = (xv.w - mean) * w4.w;
  float fr256 = 0.f;
  if (g == 0) fr256 = (x256 - mean) * ws[OFF_WIN + 256];
  float apk = fmaxf(fmaxf(fabsf(f4.x), fabsf(f4.y)), fmaxf(fabsf(f4.z), fabsf(f4.w)));
  if (g == 0) apk = fmaxf(apk, fabsf(fr256));
#pragma unroll
  for (int off = 32; off; off >>= 1) apk = fmaxf(apk, __shfl_xor(apk, off));

  // ---- build hi/lo bf16 buffers: buf[i] = fr[i-16], zero-padded to 576 elems ----
  {
    unsigned ux = __float_as_uint(f4.x), uy = __float_as_uint(f4.y);
    unsigned uz = __float_as_uint(f4.z), uw = __float_as_uint(f4.w);
    unsigned hx = bf16rne(f4.x), hy = bf16rne(f4.y), hz = bf16rne(f4.z), hw = bf16rne(f4.w);
    float lx = f4.x - __uint_as_float(hx << 16);
    float ly = f4.y - __uint_as_float(hy << 16);
    float lz = f4.z - __uint_as_float(hz << 16);
    float lw = f4.w - __uint_as_float(hw << 16);
    (void)ux; (void)uy; (void)uz; (void)uw;
    unsigned ph0 = hx | (hy << 16), ph1 = hz | (hw << 16);
    unsigned pl0 = bf16rne(lx) | (bf16rne(ly) << 16);
    unsigned pl1 = bf16rne(lz) | (bf16rne(lw) << 16);
    if (g < 8) { L[g] = 0.f; L[288 + g] = 0.f; }                     // elems 0..15
    f32x2 vh = {__uint_as_float(ph0), __uint_as_float(ph1)};
    f32x2 vl = {__uint_as_float(pl0), __uint_as_float(pl1)};
    *(f32x2*)&L[8 + 2 * g] = vh;                                     // elems 16+4g..19+4g
    *(f32x2*)&L[288 + 8 + 2 * g] = vl;
    if (g < 76) {                                                    // elems 272..575 zero
      f32x2 z = {0.f, 0.f};
      *(f32x2*)&L[136 + 2 * g] = z;
      *(f32x2*)&L[288 + 136 + 2 * g] = z;
    }
    if (g == 0) {                                                    // patch elem 272 = fr[256]
      unsigned h2 = bf16rne(fr256);
      float l2 = fr256 - __uint_as_float(h2 << 16);
      ((unsigned short*)Lb)[272] = (unsigned short)h2;
      ((unsigned short*)(Lb + 1152))[272] = (unsigned short)bf16rne(l2);
    }
  }
  __builtin_amdgcn_wave_barrier();

  // ---- ACF via MFMA: C[a][b] = sum_k buf[k+16a]*buf[k+b] = acf[16a-b] ----
  const int bcol = g & 15, h = g >> 4;
  const int sh = 16 * (bcol & 1);
  const bool hi2 = (bcol & 3) >= 2;
  const int Ab0 = 16 * h + 32 * bcol;
  const int Bb0 = 16 * h + ((2 * bcol) & ~7);
  const char* Hb = Lb;
  const char* Ob = Lb + 1152;
  f32x4 acc = {0.f, 0.f, 0.f, 0.f};
#pragma unroll
  for (int kk = 0; kk < 10; ++kk) {
    short8 ah = __builtin_bit_cast(short8, *(const u32x4*)(Hb + Ab0 + 64 * kk));
    short8 al = __builtin_bit_cast(short8, *(const u32x4*)(Ob + Ab0 + 64 * kk));
    short8 bh = bfrag(Hb, Bb0 + 64 * kk, sh, hi2);
    short8 bl = bfrag(Ob, Bb0 + 64 * kk, sh, hi2);
    acc = __builtin_amdgcn_mfma_f32_16x16x32_bf16(ah, bh, acc, 0, 0, 0);
    acc = __builtin_amdgcn_mfma_f32_16x16x32_bf16(ah, bl, acc, 0, 0, 0);
    acc = __builtin_amdgcn_mfma_f32_16x16x32_bf16(al, bh, acc, 0, 0, 0);
  }
  __builtin_amdgcn_wave_barrier();
  // scatter: lane holds C rows 4h+r, col bcol
#pragma unroll
  for (int r = 0; r < 4; ++r) {
    int arow = 4 * h + r;
    int tau = 16 * arow - bcol;
    if (arow == 0 ? (bcol == 0) : (tau <= 215)) L[576 + (arow ? tau : 0)] = acc[r];
  }
  __builtin_amdgcn_wave_barrier();

  // ---- nacf + candidates (lane g<53: candidates 4g..4g+3) ----
  const float inv0 = 1.0f / L[576];
  bool  flv[4] = {false, false, false, false};
  float lgv[4];
  if (g < 53) {
    f32x4 A4 = *(const f32x4*)&L[576 + 4 * g];
    f32x2 A2 = *(const f32x2*)&L[580 + 4 * g];
    f32x4 I4 = *(const f32x4*)(ws + OFF_NACW + 4 * g);
    f32x2 I2 = *(const f32x2*)(ws + OFF_NACW + 4 * g + 4);
    float nn[6];
    nn[0] = A4[0] * inv0 * I4[0];
    nn[1] = A4[1] * inv0 * I4[1];
    nn[2] = A4[2] * inv0 * I4[2];
    nn[3] = A4[3] * inv0 * I4[3];
    nn[4] = A2.x * inv0 * I2.x;
    nn[5] = A2.y * inv0 * I2.y;
    float fqv[4];
#pragma unroll
    for (int a = 0; a < 4; ++a) {
      float pm = nn[a], cm = nn[a + 1], nm = nn[a + 2];
      bool flag = (cm - pm >= 0.f) && (nm - cm <= 0.f) && (cm > 0.225f);
      float dr = (0.5f * (nm - pm)) / ((2.0f * cm - nm) - pm);
      float tq = dr + (float)(4 * g + a);
      tq = (tq > 0.f) ? tq : 0.f;     // NaN -> 0: output-invariant
      float fq = 16000.0f / (1.0f + tq);
      float lg = cm;
      if (lg > 1.0f) lg = 1.0f / lg;
      lg = lg - 0.01f * log2f(75.0f / fq);
      flv[a] = flag;
      fqv[a] = fq;
      lgv[a] = flag ? lg : FLOORV;
    }
    f32x4 fo = {fqv[0], fqv[1], fqv[2], fqv[3]};
    f32x4 lo_ = {lgv[0], lgv[1], lgv[2], lgv[3]};
    *(f32x4*)&L[800 + 4 * g] = fo;
    *(f32x4*)&L[1016 + 4 * g] = lo_;
  }

  // ---- top-15 selection (order-free where safe) ----
  unsigned long long bb0 = __ballot(flv[0]);
  unsigned long long bb1 = __ballot(flv[1]);
  unsigned long long bb2 = __ballot(flv[2]);
  unsigned long long bb3 = __ballot(flv[3]);
  const int nv = __popcll(bb0) + __popcll(bb1) + __popcll(bb2) + __popcll(bb3);
  int* sel = (int*)&L[1500];
  if (nv > 0) {
    unsigned long long below = (1ull << g) - 1ull;
    int base = __popcll(bb0 & below) + __popcll(bb1 & below) +
               __popcll(bb2 & below) + __popcll(bb3 & below);
    if (nv <= TOPK) {
      if (g < 53) {
        int cnt = base;
#pragma unroll
        for (int a = 0; a < 4; ++a) {
          int c = 4 * g + a;
          if (flv[a]) {
            sel[cnt] = c;
            ++cnt;
          } else {
            int ur = c - cnt;
            if (ur < TOPK - nv) sel[nv + ur] = c;
          }
        }
      }
    } else {
      float* CV = &L[1232];
      unsigned char* CI = (unsigned char*)&L[1444];
      if (g < 53) {
        int cnt = base;
#pragma unroll
        for (int a = 0; a < 4; ++a) {
          if (flv[a]) {
            CV[cnt] = lgv[a];
            CI[cnt] = (unsigned char)(4 * g + a);
            ++cnt;
          }
        }
      }
      __builtin_amdgcn_wave_barrier();
      for (int l = g; l < nv; l += 64) {
        float vl = CV[l];
        int il = CI[l];
        int rank = 0;
        for (int m = 0; m < nv; ++m) {
          float vm = CV[m];
          int im = CI[m];
          rank += ((vm > vl) || (vm == vl && im < il)) ? 1 : 0;
        }
        if (rank < TOPK) sel[rank] = il;
      }
    }
  }
  __builtin_amdgcn_wave_barrier();

  // ---- per-frame outputs (lanes 0..14) ----
  if (g < TOPK) {
    int c = (nv == 0) ? g : sel[g];
    float fq = L[800 + c];
    float lg = L[1016 + c];
    int voi = (lg > FLOORV) && (fq < 600.0f);
    float gp = ws[OFF_GPEAK + b];
    float inten = (apk > gp) ? 1.0f : (apk / gp);
    float luv = 0.45f + fmaxf(2.0f - inten / (float)(0.03 / 1.45), 0.f);
    float dlt = voi ? (lg - 0.01f * log2f(600.0f / fq)) : luv;
    size_t fi = ((size_t)b * NS + s) * 16 + g;
    ws[OFF_FREQ + fi] = fq;
    ws[OFF_LF + fi] = log2f(fq);
    ws[OFF_DELTA + fi] = dlt;
    ws[OFF_VOIC + fi] = voi ? 1.f : 0.f;
  }
}

// transition cost (shared by chunkmat/viterbi)
__device__ __forceinline__ float trans_cost(bool vi, bool vj, float lfi, float lfj) {
  if (vi != vj) return 0.14f;
  if (!vi) return 0.f;
  return 0.35f * fabsf(lfi - lfj);
}

// ---------- K3: per-chunk max-plus product matrices ----------
__global__ __launch_bounds__(256) void k_chunkmat(float* __restrict__ ws) {
  const int c = blockIdx.x, b = blockIdx.y, tid = threadIdx.x;
  const int i = tid >> 4, j = tid & 15;
  const bool act = (i < 15) && (j < 15);
  __shared__ float P[2][15][16];
  __shared__ float M[15][16];
  __shared__ float lfA[16], vA[16], lfB[16], vB[16], dB[16];
  const int t0 = c * CHUNK;
  if (tid < TOPK) {
    size_t fi = ((size_t)b * NS + t0) * 16 + tid;
    lfA[tid] = ws[OFF_LF + fi]; vA[tid] = ws[OFF_VOIC + fi];
  }
  for (int step = 1; step <= CHUNK; ++step) {
    const int t = t0 + step;
    if (tid < TOPK) {
      size_t fi = ((size_t)b * NS + t) * 16 + tid;
      lfB[tid] = ws[OFF_LF + fi]; vB[tid] = ws[OFF_VOIC + fi]; dB[tid] = ws[OFF_DELTA + fi];
    }
    __syncthreads();
    if (act) {
      float tr = trans_cost(vA[i] != 0.f, vB[j] != 0.f, lfA[i], lfB[j]);
      M[i][j] = dB[j] - tr;
    }
    __syncthreads();
    if (act) {
      if (step == 1) {
        P[0][i][j] = M[i][j];
      } else {
        const int src = step & 1;
        float best = -INFINITY;
#pragma unroll
        for (int k = 0; k < 15; ++k) best = fmaxf(best, P[src][i][k] + M[k][j]);
        P[src ^ 1][i][j] = best;
      }
    }
    if (tid < TOPK) { lfA[tid] = lfB[tid]; vA[tid] = vB[tid]; }
    __syncthreads();
  }
  if (act) ws[OFF_P + ((size_t)(b * NCHUNK + c)) * 256 + (i * 16 + j)] = P[1][i][j];
}

// ---------- K4: scan chunk matrices -> entry value vectors ----------
__global__ __launch_bounds__(256) void k_scan(float* __restrict__ ws) {
  const int b = blockIdx.x, tid = threadIdx.x;
  __shared__ float v[16];
  __shared__ float Pm[16][16];
  if (tid < TOPK) {
    float d0 = ws[OFF_DELTA + ((size_t)b * NS + 0) * 16 + tid];
    v[tid] = d0;
    ws[OFF_VENT + ((size_t)b * (NCHUNK + 1) + 0) * 16 + tid] = d0;
  }
  __syncthreads();
  for (int c = 0; c < NCHUNK; ++c) {
    Pm[tid >> 4][tid & 15] = ws[OFF_P + ((size_t)(b * NCHUNK + c)) * 256 + tid];
    __syncthreads();
    float nv = 0.f;
    if (tid < TOPK) {
      float best = -INFINITY;
#pragma unroll
      for (int k = 0; k < 15; ++k) best = fmaxf(best, v[k] + Pm[k][tid]);
      nv = best;
    }
    __syncthreads();
    if (tid < TOPK) {
      v[tid] = nv;
      ws[OFF_VENT + ((size_t)b * (NCHUNK + 1) + (c + 1)) * 16 + tid] = nv;
    }
    __syncthreads();
  }
}

// ---------- K5: per-chunk sequential Viterbi (exact op order) -> ptrs + backmaps ----------
__global__ __launch_bounds__(256) void k_viterbi(float* __restrict__ ws) {
  const int c = blockIdx.x, b = blockIdx.y, tid = threadIdx.x;
  const int i = tid & 15, j = tid >> 4;
  const bool act = (i < 15) && (j < 15);
  __shared__ float val[16];
  __shared__ float lfA[16], vA[16], lfB[16], vB[16], dB[16];
  __shared__ unsigned char ptl[CHUNK][16];
  const int t0 = c * CHUNK;
  if (tid < TOPK) {
    val[tid] = ws[OFF_VENT + ((size_t)b * (NCHUNK + 1) + c) * 16 + tid];
    size_t fi = ((size_t)b * NS + t0) * 16 + tid;
    lfA[tid] = ws[OFF_LF + fi]; vA[tid] = ws[OFF_VOIC + fi];
  }
  unsigned char* pg = (unsigned char*)(ws + OFF_PTR);
  for (int step = 1; step <= CHUNK; ++step) {
    const int t = t0 + step;
    if (tid < TOPK) {
      size_t fi = ((size_t)b * NS + t) * 16 + tid;
      lfB[tid] = ws[OFF_LF + fi]; vB[tid] = ws[OFF_VOIC + fi]; dB[tid] = ws[OFF_DELTA + fi];
    }
    __syncthreads();
    float sc = -INFINITY;
    int bi = i;
    if (act) {
      float tr = trans_cost(vA[i] != 0.f, vB[j] != 0.f, lfA[i], lfB[j]);
      sc = (val[i] - tr) + dB[j];   // reference op order
    }
#pragma unroll
    for (int off = 1; off < 16; off <<= 1) {
      float so = __shfl_xor(sc, off);
      int io = __shfl_xor(bi, off);
      if (so > sc || (so == sc && io < bi)) { sc = so; bi = io; }
    }
    __syncthreads();
    if (act && i == 0) {
      val[j] = sc;
      ptl[step - 1][j] = (unsigned char)bi;
      pg[((size_t)b * NSTEPS + (t - 1)) * 16 + j] = (unsigned char)bi;
    }
    if (tid < TOPK) { lfA[tid] = lfB[tid]; vA[tid] = vB[tid]; }
    __syncthreads();
  }
  if (tid < TOPK) {
    int st = tid;
#pragma unroll 1
    for (int s2 = CHUNK - 1; s2 >= 0; --s2) st = ptl[s2][st];
    ((unsigned char*)(ws + OFF_BMAP))[((size_t)(b * NCHUNK + c)) * 16 + tid] = (unsigned char)st;
  }
  if (c == NCHUNK - 1 && tid < TOPK) ws[OFF_VFIN + (size_t)b * 16 + tid] = val[tid];
}

// ---------- K6: compose backmaps -> chunk-boundary states ----------
__global__ __launch_bounds__(256) void k_compose(float* __restrict__ ws) {
  __shared__ unsigned char bm[NB * NCHUNK * 16];
  const int tid = threadIdx.x;
  const unsigned char* bg = (const unsigned char*)(ws + OFF_BMAP);
  for (int idx = tid; idx < NB * NCHUNK * 16; idx += 256) bm[idx] = bg[idx];
  __syncthreads();
  if (tid < NB) {
    const int b = tid;
    float best = -INFINITY; int bi = 0;
    for (int jj = 0; jj < TOPK; ++jj) {
      float vv = ws[OFF_VFIN + (size_t)b * 16 + jj];
      if (vv > best) { best = vv; bi = jj; }
    }
    int* bs = (int*)(ws + OFF_BS);
    int st = bi;
    bs[b * (NCHUNK + 1) + NCHUNK] = st;
    for (int cc = NCHUNK - 1; cc >= 0; --cc) {
      st = bm[((size_t)(b * NCHUNK + cc)) * 16 + st];
      bs[b * (NCHUNK + 1) + cc] = st;
    }
  }
}

// ---------- K7: per-chunk state walk -> f0 ----------
__global__ __launch_bounds__(64) void k_select(float* __restrict__ ws) {
  const int c = blockIdx.x, b = blockIdx.y, tid = threadIdx.x;
  __shared__ unsigned char pl[CHUNK * 16];
  __shared__ int stt[CHUNK + 1];
  const int t0 = c * CHUNK;
  const unsigned char* pg = (const unsigned char*)(ws + OFF_PTR);
  for (int idx = tid; idx < CHUNK * 16; idx += 64)
    pl[idx] = pg[((size_t)b * NSTEPS + t0) * 16 + idx];
  __syncthreads();
  if (tid == 0) {
    const int* bs = (const int*)(ws + OFF_BS);
    int st = bs[b * (NCHUNK + 1) + (c + 1)];
    stt[CHUNK] = st;
    for (int s2 = CHUNK; s2 >= 1; --s2) { st = pl[(s2 - 1) * 16 + st]; stt[s2 - 1] = st; }
  }
  __syncthreads();
  const int nt = (c == NCHUNK - 1) ? (CHUNK + 1) : CHUNK;
  if (tid < nt) {
    const int t = t0 + tid;
    const int st = stt[tid];
    size_t fi = ((size_t)b * NS + t) * 16 + st;
    float fq = ws[OFF_FREQ + fi];
    float vv = ws[OFF_VOIC + fi];
    ws[OFF_F0 + (size_t)b * NS + t] = (vv != 0.f) ? fq : 0.f;
  }
}

// ---------- K8: median-5 with edge padding ----------
__global__ __launch_bounds__(256) void k_median(const float* __restrict__ ws, float* __restrict__ out) {
  const int b = blockIdx.y;
  const int t = blockIdx.x * 256 + threadIdx.x;
  if (t >= NS) return;
  const float* f0 = ws + OFF_F0 + (size_t)b * NS;
  float a0 = f0[max(t - 2, 0)];
  float a1 = f0[max(t - 1, 0)];
  float a2 = f0[t];
  float a3 = f0[min(t + 1, NS - 1)];
  float a4 = f0[min(t + 2, NS - 1)];
#define SW(u, w) { float lo_ = fminf(u, w), hi_ = fmaxf(u, w); u = lo_; w = hi_; }
  SW(a0, a1) SW(a1, a2) SW(a2, a3) SW(a3, a4)
  SW(a0, a1) SW(a1, a2) SW(a2, a3)
  SW(a0, a1) SW(a1, a2)
#undef SW
  out[(size_t)b * NS + t] = a2;
}

extern "C" void kernel_launch(void* const* d_in, const int* in_sizes, int n_in,
                              void* d_out, int out_size, void* d_ws, size_t ws_size,
                              hipStream_t stream) {
  const float* x = (const float*)d_in[0];
  float* ws = (float*)d_ws;
  float* out = (float*)d_out;
  hipLaunchKernelGGL(k_setup, dim3(1), dim3(256), 0, stream, ws);
  hipLaunchKernelGGL(k_gpeak, dim3(64, NB), dim3(256), 0, stream, x, ws);
  hipLaunchKernelGGL(k_frames, dim3((NS + 3) / 4, NB), dim3(256), 0, stream, x, ws);
  hipLaunchKernelGGL(k_chunkmat, dim3(NCHUNK, NB), dim3(256), 0, stream, ws);
  hipLaunchKernelGGL(k_scan, dim3(NB), dim3(256), 0, stream, ws);
  hipLaunchKernelGGL(k_viterbi, dim3(NCHUNK, NB), dim3(256), 0, stream, ws);
  hipLaunchKernelGGL(k_compose, dim3(1), dim3(256), 0, stream, ws);
  hipLaunchKernelGGL(k_select, dim3(NCHUNK, NB), dim3(64), 0, stream, ws);
  hipLaunchKernelGGL(k_median, dim3((NS + 255) / 256, NB), dim3(256), 0, stream, ws, out);
}

// Round 5
// 298.608 us; speedup vs baseline: 3.0451x; 1.2401x over previous
//
#include <hip/hip_runtime.h>

#define NB 16
#define NT 960000
#define NS 6001
#define STRIDEF 160
#define WLEN 257
#define LAGS 214
#define NCAND 212
#define TOPK 15
#define NSTEPS 6000
#define CHUNK 50
#define NCHUNK 120
#define FLOORV -100000.0f

typedef __attribute__((ext_vector_type(8))) short short8;
typedef __attribute__((ext_vector_type(4))) float f32x4;
typedef __attribute__((ext_vector_type(2))) float f32x2;
typedef __attribute__((ext_vector_type(4))) unsigned int u32x4;

// ---- workspace layout (offsets in floats) ----
constexpr size_t OFF_NACW  = 0;                                    // 216 floats (INVERSE nacw)
constexpr size_t OFF_WIN   = 256;                                  // 257 floats (hann window)
constexpr size_t OFF_GPEAK = 520;                                  // 16 floats (max|x| bits)
constexpr size_t OFF_FREQ  = 576;
constexpr size_t PERFR     = (size_t)NB * NS * 16;                 // per-frame arrays, K padded to 16
constexpr size_t OFF_LFV   = OFF_FREQ + PERFR;                     // packed: voiced? +log2(f) : -log2(f)
constexpr size_t OFF_DELTA = OFF_LFV + PERFR;
constexpr size_t OFF_UNUSED= OFF_DELTA + PERFR;
constexpr size_t OFF_P     = OFF_UNUSED + PERFR;                   // NB*NCHUNK*256 chunk matrices
constexpr size_t OFF_VENT  = OFF_P + (size_t)NB * NCHUNK * 256;    // NB*(NCHUNK+1)*16 entry vectors
constexpr size_t OFF_VFIN  = OFF_VENT + (size_t)NB * (NCHUNK + 1) * 16; // unused
constexpr size_t OFF_F0    = OFF_VFIN + 256;                       // NB*NS f0 (pre-median)
constexpr size_t OFF_BS    = OFF_F0 + 96032;                       // int32 boundary states NB*(NCHUNK+1)
constexpr size_t OFF_PTR   = OFF_BS + 2048;                        // uint8 ptrs NB*NSTEPS*16 bytes
constexpr size_t OFF_BMAP  = OFF_PTR + (size_t)NB * NSTEPS * 4;    // uint8 backmaps NB*NCHUNK*16 bytes

__device__ __forceinline__ unsigned ordf(float f) {
  unsigned u = __float_as_uint(f);
  return (u & 0x80000000u) ? ~u : (u | 0x80000000u);
}

// transition cost from packed lf-values (sign bit = unvoiced)
__device__ __forceinline__ float tr_of(float sa, float sb) {
  int xs = __float_as_int(sa) ^ __float_as_int(sb);
  float t = 0.35f * fabsf(sa - sb);
  t = (__float_as_int(sa) < 0) ? 0.f : t;   // both unvoiced -> 0
  return (xs < 0) ? 0.14f : t;              // mixed -> C_VUV
}

// ---------- K0: window + inverse window-ACF + zero gpeak ----------
__global__ __launch_bounds__(256) void k_setup(float* __restrict__ ws) {
  __shared__ float win[WLEN];
  __shared__ float w0sh;
  const int tid = threadIdx.x;
  for (int n = tid; n < WLEN; n += 256) {
    float w = 0.5f * (1.0f - cosf((6.2831855f * (float)n) / 257.0f));
    win[n] = w;
    ws[OFF_WIN + n] = w;
  }
  __syncthreads();
  float s = 0.f;
  if (tid < 216) {
    for (int n = 0; n + tid < WLEN; ++n) s += win[n] * win[n + tid];
  }
  if (tid == 0) w0sh = s;
  __syncthreads();
  if (tid < 216) ws[OFF_NACW + tid] = w0sh / s;   // inverse of nacw
  if (tid < NB) ws[OFF_GPEAK + tid] = 0.0f;
}

// ---------- K1: per-batch global peak of |x| ----------
__global__ __launch_bounds__(256) void k_gpeak(const float* __restrict__ x, float* __restrict__ ws) {
  const int b = blockIdx.y;
  const float4* xb = (const float4*)(x + (size_t)b * NT);
  const int n4 = NT / 4;
  float m = 0.f;
  for (int i = blockIdx.x * blockDim.x + threadIdx.x; i < n4; i += gridDim.x * blockDim.x) {
    float4 v = xb[i];
    m = fmaxf(m, fmaxf(fmaxf(fabsf(v.x), fabsf(v.y)), fmaxf(fabsf(v.z), fabsf(v.w))));
  }
  for (int off = 32; off; off >>= 1) m = fmaxf(m, __shfl_down(m, off));
  __shared__ float sm[4];
  if ((threadIdx.x & 63) == 0) sm[threadIdx.x >> 6] = m;
  __syncthreads();
  if (threadIdx.x == 0) {
    m = fmaxf(fmaxf(sm[0], sm[1]), fmaxf(sm[2], sm[3]));
    atomicMax((unsigned*)(ws + OFF_GPEAK) + b, __float_as_uint(m));
  }
}

__device__ __forceinline__ unsigned bf16rne(float f) {
  unsigned u = __float_as_uint(f);
  return (u + 0x7FFFu + ((u >> 16) & 1u)) >> 16;   // bf16 bits in low 16
}

__device__ __forceinline__ short8 bfrag(const char* p, int sh) {
  unsigned w0 = *(const unsigned*)(p);
  unsigned w1 = *(const unsigned*)(p + 4);
  unsigned w2 = *(const unsigned*)(p + 8);
  unsigned w3 = *(const unsigned*)(p + 12);
  unsigned w4 = *(const unsigned*)(p + 16);
  u32x4 o;
  o[0] = __builtin_amdgcn_alignbit(w1, w0, sh);
  o[1] = __builtin_amdgcn_alignbit(w2, w1, sh);
  o[2] = __builtin_amdgcn_alignbit(w3, w2, sh);
  o[3] = __builtin_amdgcn_alignbit(w4, w3, sh);
  return __builtin_bit_cast(short8, o);
}

// ---------- K2: one wave = one frame; bf16x3-split MFMA ACF; parallel top-k ----------
__global__ __launch_bounds__(256, 4) void k_frames(const float* __restrict__ x, float* __restrict__ ws) {
  const int wv = threadIdx.x >> 6;
  const int g  = threadIdx.x & 63;
  const int s  = blockIdx.x * 4 + wv;
  const int b  = blockIdx.y;
  // per wave (floats): HI bf16[576] @[0,288) | LO @[288,576) | ACF @[576,800)
  //                    FREQ @[800,1016) | LOGIT @[1016,1232) | CK u64 @[1232,1656) | SEL @[1656,1672)
  __shared__ __align__(16) float LA[4][1680];
  if (s >= NS) return;
  float* L = LA[wv];
  char* Lb = (char*)L;
  const size_t xb = (size_t)b * NT;
  const int c0 = 40 * s;               // float4 chunk base

  // ---- load frame ----
  float4 xv = make_float4(0.f, 0.f, 0.f, 0.f);
  if (c0 + g < NT / 4) xv = ((const float4*)(x + xb))[c0 + g];
  float x256 = 0.f;
  if (g == 0) {
    int i256 = 160 * s + 256;
    if (i256 < NT) x256 = x[xb + i256];
  }

  // ---- mean over 257 raw samples ----
  float ps = ((xv.x + xv.y) + (xv.z + xv.w)) + x256;
#pragma unroll
  for (int off = 32; off; off >>= 1) ps += __shfl_xor(ps, off);
  const float mean = ps / 257.0f;

  // ---- window + local peak ----
  float4 w4 = ((const float4*)(ws + OFF_WIN))[g];
  float4 f4;
  f4.x = (xv.x - mean) * w4.x;
  f4.y = (xv.y - mean) * w4.y;
  f4.z = (xv.z - mean) * w4.z;
  f4.w = (xv.w - mean) * w4.w;
  float fr256 = 0.f;
  if (g == 0) fr256 = (x256 - mean) * ws[OFF_WIN + 256];
  float apk = fmaxf(fmaxf(fabsf(f4.x), fabsf(f4.y)), fmaxf(fabsf(f4.z), fabsf(f4.w)));
  if (g == 0) apk = fmaxf(apk, fabsf(fr256));
#pragma unroll
  for (int off = 32; off; off >>= 1) apk = fmaxf(apk, __shfl_xor(apk, off));

  // ---- build hi/lo bf16 buffers: buf[i] = fr[i-16], zero-padded to 576 elems ----
  {
    unsigned hx = bf16rne(f4.x), hy = bf16rne(f4.y), hz = bf16rne(f4.z), hw = bf16rne(f4.w);
    float lx = f4.x - __uint_as_float(hx << 16);
    float ly = f4.y - __uint_as_float(hy << 16);
    float lz = f4.z - __uint_as_float(hz << 16);
    float lw = f4.w - __uint_as_float(hw << 16);
    unsigned ph0 = hx | (hy << 16), ph1 = hz | (hw << 16);
    unsigned pl0 = bf16rne(lx) | (bf16rne(ly) << 16);
    unsigned pl1 = bf16rne(lz) | (bf16rne(lw) << 16);
    if (g < 8) { L[g] = 0.f; L[288 + g] = 0.f; }                     // elems 0..15
    f32x2 vh = {__uint_as_float(ph0), __uint_as_float(ph1)};
    f32x2 vl = {__uint_as_float(pl0), __uint_as_float(pl1)};
    *(f32x2*)&L[8 + 2 * g] = vh;                                     // elems 16+4g..19+4g
    *(f32x2*)&L[288 + 8 + 2 * g] = vl;
    if (g < 76) {                                                    // elems 272..575 zero
      f32x2 z = {0.f, 0.f};
      *(f32x2*)&L[136 + 2 * g] = z;
      *(f32x2*)&L[288 + 136 + 2 * g] = z;
    }
    if (g == 0) {                                                    // patch elem 272 = fr[256]
      unsigned h2 = bf16rne(fr256);
      float l2 = fr256 - __uint_as_float(h2 << 16);
      ((unsigned short*)Lb)[272] = (unsigned short)h2;
      ((unsigned short*)(Lb + 1152))[272] = (unsigned short)bf16rne(l2);
    }
  }
  __builtin_amdgcn_wave_barrier();

  // ---- ACF via MFMA: C[a][b] = sum_k buf[k+16a]*buf[k+b] = acf[16a-b] ----
  const int bcol = g & 15, h = g >> 4;
  const int sh = 16 * (bcol & 1);
  const int hi4 = ((bcol & 3) >= 2) ? 4 : 0;
  const int Ab0 = 16 * h + 32 * bcol;
  const int Bb0 = 16 * h + ((2 * bcol) & ~7) + hi4;
  const char* Hb = Lb;
  const char* Ob = Lb + 1152;
  f32x4 acc = {0.f, 0.f, 0.f, 0.f};
#pragma unroll
  for (int kk = 0; kk < 10; ++kk) {
    short8 ah = __builtin_bit_cast(short8, *(const u32x4*)(Hb + Ab0 + 64 * kk));
    short8 al = __builtin_bit_cast(short8, *(const u32x4*)(Ob + Ab0 + 64 * kk));
    short8 bh = bfrag(Hb + Bb0 + 64 * kk, sh);
    short8 bl = bfrag(Ob + Bb0 + 64 * kk, sh);
    acc = __builtin_amdgcn_mfma_f32_16x16x32_bf16(ah, bh, acc, 0, 0, 0);
    acc = __builtin_amdgcn_mfma_f32_16x16x32_bf16(ah, bl, acc, 0, 0, 0);
    acc = __builtin_amdgcn_mfma_f32_16x16x32_bf16(al, bh, acc, 0, 0, 0);
  }
  __builtin_amdgcn_wave_barrier();
  // scatter: lane holds C rows 4h+r, col bcol
#pragma unroll
  for (int r = 0; r < 4; ++r) {
    int arow = 4 * h + r;
    int tau = 16 * arow - bcol;
    if (arow == 0 ? (bcol == 0) : (tau <= 215)) L[576 + (arow ? tau : 0)] = acc[r];
  }
  __builtin_amdgcn_wave_barrier();

  // ---- nacf + candidates (lane g<53: candidates 4g..4g+3) ----
  const float inv0 = 1.0f / L[576];
  bool  flv[4] = {false, false, false, false};
  float lgv[4];
  if (g < 53) {
    f32x4 A4 = *(const f32x4*)&L[576 + 4 * g];
    f32x2 A2 = *(const f32x2*)&L[580 + 4 * g];
    f32x4 I4 = *(const f32x4*)(ws + OFF_NACW + 4 * g);
    f32x2 I2 = *(const f32x2*)(ws + OFF_NACW + 4 * g + 4);
    float nn[6];
    nn[0] = A4[0] * inv0 * I4[0];
    nn[1] = A4[1] * inv0 * I4[1];
    nn[2] = A4[2] * inv0 * I4[2];
    nn[3] = A4[3] * inv0 * I4[3];
    nn[4] = A2.x * inv0 * I2.x;
    nn[5] = A2.y * inv0 * I2.y;
    float fqv[4];
#pragma unroll
    for (int a = 0; a < 4; ++a) {
      float pm = nn[a], cm = nn[a + 1], nm = nn[a + 2];
      bool flag = (cm - pm >= 0.f) && (nm - cm <= 0.f) && (cm > 0.225f);
      float dr = (0.5f * (nm - pm)) / ((2.0f * cm - nm) - pm);   // exact div (decision-adjacent)
      float tq = dr + (float)(4 * g + a);
      tq = (tq > 0.f) ? tq : 0.f;     // NaN -> 0: output-invariant
      float fq = 16000.0f / (1.0f + tq);                          // exact div (600-boundary)
      float l1p = __log2f(1.0f + tq);
      float lg = cm;
      if (lg > 1.0f) lg = __builtin_amdgcn_rcpf(lg);
      lg = lg - 0.01f * (l1p - 7.736965594166206f);   // == cm' - 0.01*log2(75/fq)
      flv[a] = flag;
      fqv[a] = fq;
      lgv[a] = flag ? lg : FLOORV;
    }
    f32x4 fo = {fqv[0], fqv[1], fqv[2], fqv[3]};
    f32x4 lo_ = {lgv[0], lgv[1], lgv[2], lgv[3]};
    *(f32x4*)&L[800 + 4 * g] = fo;
    *(f32x4*)&L[1016 + 4 * g] = lo_;
  }

  // ---- top-15 selection ----
  unsigned long long bb0 = __ballot(flv[0]);
  unsigned long long bb1 = __ballot(flv[1]);
  unsigned long long bb2 = __ballot(flv[2]);
  unsigned long long bb3 = __ballot(flv[3]);
  const int nv = __popcll(bb0) + __popcll(bb1) + __popcll(bb2) + __popcll(bb3);
  int* sel = (int*)&L[1656];
  if (nv > 0) {
    unsigned long long below = (1ull << g) - 1ull;
    int base = __popcll(bb0 & below) + __popcll(bb1 & below) +
               __popcll(bb2 & below) + __popcll(bb3 & below);
    if (nv <= TOPK) {
      if (g < 53) {
        int cnt = base;
#pragma unroll
        for (int a = 0; a < 4; ++a) {
          int c = 4 * g + a;
          if (flv[a]) {
            sel[cnt] = c;
            ++cnt;
          } else {
            int ur = c - cnt;
            if (ur < TOPK - nv) sel[nv + ur] = c;
          }
        }
      }
    } else {
      unsigned long long* CK = (unsigned long long*)&L[1232];
      if (g < 53) {
        int cnt = base;
#pragma unroll
        for (int a = 0; a < 4; ++a) {
          if (flv[a]) {
            CK[cnt] = (((unsigned long long)ordf(lgv[a])) << 32)
                    | (unsigned long long)(0xFFFFFFFFu - (unsigned)(4 * g + a));
            ++cnt;
          }
        }
      }
      __builtin_amdgcn_wave_barrier();
      for (int l = g; l < nv; l += 64) {
        unsigned long long kl = CK[l];
        int rank = 0;
        for (int m = 0; m < nv; ++m) rank += (CK[m] > kl) ? 1 : 0;
        if (rank < TOPK) sel[rank] = (int)(0xFFFFFFFFu - (unsigned)(kl & 0xFFFFFFFFull));
      }
    }
  }
  __builtin_amdgcn_wave_barrier();

  // ---- per-frame outputs (lanes 0..15; slot 15 = fixed dead-state fill) ----
  if (g < 16) {
    size_t fi = ((size_t)b * NS + s) * 16 + g;
    if (g == TOPK) {
      ws[OFF_FREQ + fi] = 0.f;
      ws[OFF_LFV + fi] = -1.0f;   // unvoiced sentinel (state 15 is never selectable)
      ws[OFF_DELTA + fi] = 0.f;
    } else {
      int c = (nv == 0) ? g : sel[g];
      float fq = L[800 + c];
      float lg = L[1016 + c];
      int voi = (lg > FLOORV) && (fq < 600.0f);
      float gp = ws[OFF_GPEAK + b];
      float inten = (apk > gp) ? 1.0f : apk * __builtin_amdgcn_rcpf(gp);
      float luv = 0.45f + fmaxf(2.0f - inten * 48.333333333333336f, 0.f);
      float l2 = __log2f(fq);
      float dlt = voi ? (lg - 0.01f * (9.228818690495881f - l2)) : luv;
      ws[OFF_FREQ + fi] = fq;
      ws[OFF_LFV + fi] = voi ? l2 : -l2;
      ws[OFF_DELTA + fi] = dlt;
    }
  }
}

// ---------- K3: per-chunk max-plus product matrices (textbook 2-barrier) ----------
__global__ __launch_bounds__(256) void k_chunkmat(float* __restrict__ ws) {
  const int c = blockIdx.x, b = blockIdx.y, tid = threadIdx.x;
  const int i = tid >> 4, j = tid & 15;
  __shared__ float Msh[16][17];
  __shared__ float Psh[2][16][17];
  const float* LFV = ws + OFF_LFV;
  const float* DEL = ws + OFF_DELTA;
  const size_t fb = (size_t)b * NS;
  const int t0 = c * CHUNK;
  float sA = LFV[(fb + t0) * 16 + i];
  float sB = LFV[(fb + t0 + 1) * 16 + j];
  float dB = DEL[(fb + t0 + 1) * 16 + j];
  Psh[0][i][j] = (i == j) ? 0.f : -INFINITY;   // max-plus identity
  int src = 0;
  float pn = 0.f;
  for (int s = 1; s <= CHUNK; ++s) {
    Msh[i][j] = dB - tr_of(sA, sB);
    __syncthreads();                 // M + P[src] visible to all
    if (s < CHUNK) {
      const int t = t0 + s;
      sA = LFV[(fb + t) * 16 + i];
      sB = LFV[(fb + t + 1) * 16 + j];
      dB = DEL[(fb + t + 1) * 16 + j];
    }
    pn = -INFINITY;
#pragma unroll
    for (int k = 0; k < 15; ++k) pn = fmaxf(pn, Psh[src][i][k] + Msh[k][j]);
    Psh[src ^ 1][i][j] = pn;
    __syncthreads();                 // all reads of M/P[src] done before next overwrite
    src ^= 1;
  }
  ws[OFF_P + ((size_t)(b * NCHUNK + c)) * 256 + tid] = pn;
}

// ---------- K4: scan chunk matrices -> entry value vectors (1 wave / batch) ----------
__global__ __launch_bounds__(64) void k_scan(float* __restrict__ ws) {
  const int b = blockIdx.x, l = threadIdx.x;
  __shared__ float v[16];
  const float* DEL = ws + OFF_DELTA;
  const size_t fb = (size_t)b * NS;
  if (l < 16) {
    float d0 = DEL[fb * 16 + l];
    v[l] = d0;
    ws[OFF_VENT + ((size_t)b * (NCHUNK + 1)) * 16 + l] = d0;
  }
  __syncthreads();
  const float4* Pg = (const float4*)(ws + OFF_P + (size_t)b * NCHUNK * 256);
  const int k = l >> 2;
  float4 cur = Pg[l];    // element offset 4l = k*16 + (l&3)*4
  for (int c = 0; c < NCHUNK; ++c) {
    float4 nxt = cur;
    if (c + 1 < NCHUNK) nxt = Pg[(size_t)(c + 1) * 64 + l];
    float vk = (k < 15) ? v[k] : -INFINITY;
    float4 t;
    t.x = vk + cur.x; t.y = vk + cur.y; t.z = vk + cur.z; t.w = vk + cur.w;
    if (k == 15) { t.x = -INFINITY; t.y = -INFINITY; t.z = -INFINITY; t.w = -INFINITY; }
#pragma unroll
    for (int off = 4; off < 64; off <<= 1) {
      t.x = fmaxf(t.x, __shfl_xor(t.x, off));
      t.y = fmaxf(t.y, __shfl_xor(t.y, off));
      t.z = fmaxf(t.z, __shfl_xor(t.z, off));
      t.w = fmaxf(t.w, __shfl_xor(t.w, off));
    }
    __syncthreads();                 // all v[k] reads done before overwrite
    if (l < 4) {
      *(float4*)&v[4 * l] = *(float4*)&t;
      ((float4*)(ws + OFF_VENT + ((size_t)b * (NCHUNK + 1) + c + 1) * 16))[l] = *(float4*)&t;
    }
    __syncthreads();                 // new v visible
    cur = nxt;
  }
}

// ---------- K5: per-chunk sequential Viterbi (exact op order) -> ptrs + backmaps ----------
__global__ __launch_bounds__(256) void k_viterbi(float* __restrict__ ws) {
  const int c = blockIdx.x, b = blockIdx.y, tid = threadIdx.x;
  const int i = tid & 15, j = tid >> 4;
  __shared__ float val[2][16];
  __shared__ __align__(16) unsigned char ptl[CHUNK][16];
  const float* LFV = ws + OFF_LFV;
  const float* DEL = ws + OFF_DELTA;
  const size_t fb = (size_t)b * NS;
  const int t0 = c * CHUNK;
  if (tid < 16) {
    val[0][tid] = ws[OFF_VENT + ((size_t)b * (NCHUNK + 1) + c) * 16 + tid];
    val[1][tid] = -INFINITY;
  }
  float sA = LFV[(fb + t0) * 16 + i];
  float sB = LFV[(fb + t0 + 1) * 16 + j];
  float dB = DEL[(fb + t0 + 1) * 16 + j];
  int src = 0;
  for (int s = 1; s <= CHUNK; ++s) {
    __syncthreads();                 // val[src] visible
    float sc = (val[src][i] - tr_of(sA, sB)) + dB;   // reference op order
    if (i == 15) sc = -INFINITY;
    if (s < CHUNK) {
      const int t = t0 + s;
      sA = LFV[(fb + t) * 16 + i];
      sB = LFV[(fb + t + 1) * 16 + j];
      dB = DEL[(fb + t + 1) * 16 + j];
    }
    float mx = sc;
#pragma unroll
    for (int off = 1; off < 16; off <<= 1) mx = fmaxf(mx, __shfl_xor(mx, off));
    unsigned long long bal = __ballot(sc == mx);
    int nib = (int)((bal >> (tid & 48)) & 0xFFFFull);
    int bi = __ffs(nib) - 1;                     // lowest i on ties (reference argmax)
    __syncthreads();                 // all val[src] reads done before overwrite of val[src^1]? (paranoid full order)
    if (i == 0 && j < 15) {
      val[src ^ 1][j] = mx;
      ptl[s - 1][j] = (unsigned char)bi;
    }
    src ^= 1;
  }
  __syncthreads();
  // dump ptrs coalesced
  unsigned* pg = (unsigned*)(ws + OFF_PTR);
  if (tid < CHUNK * 4) pg[((size_t)b * NSTEPS + t0) * 4 + tid] = ((unsigned*)ptl)[tid];
  // per-chunk backtrack map: exit state -> entry state
  if (tid < TOPK) {
    int st = tid;
#pragma unroll 1
    for (int s2 = CHUNK - 1; s2 >= 0; --s2) st = ptl[s2][st];
    ((unsigned char*)(ws + OFF_BMAP))[((size_t)(b * NCHUNK + c)) * 16 + tid] = (unsigned char)st;
  }
}

// ---------- K6: compose backmaps -> chunk-boundary states ----------
__global__ __launch_bounds__(256) void k_compose(float* __restrict__ ws) {
  __shared__ unsigned char bm[NB * NCHUNK * 16];
  const int tid = threadIdx.x;
  const unsigned char* bg = (const unsigned char*)(ws + OFF_BMAP);
  for (int idx = tid; idx < NB * NCHUNK * 16; idx += 256) bm[idx] = bg[idx];
  __syncthreads();
  if (tid < NB) {
    const int b = tid;
    float best = -INFINITY; int bi = 0;
    for (int jj = 0; jj < TOPK; ++jj) {
      float vv = ws[OFF_VENT + ((size_t)b * (NCHUNK + 1) + NCHUNK) * 16 + jj];
      if (vv > best) { best = vv; bi = jj; }   // strict > : first max
    }
    int* bs = (int*)(ws + OFF_BS);
    int st = bi;
    bs[b * (NCHUNK + 1) + NCHUNK] = st;
    for (int cc = NCHUNK - 1; cc >= 0; --cc) {
      st = bm[((size_t)(b * NCHUNK + cc)) * 16 + st];
      bs[b * (NCHUNK + 1) + cc] = st;
    }
  }
}

// ---------- K7: per-chunk state walk -> f0 ----------
__global__ __launch_bounds__(64) void k_select(float* __restrict__ ws) {
  const int c = blockIdx.x, b = blockIdx.y, tid = threadIdx.x;
  __shared__ unsigned char pl[CHUNK * 16];
  __shared__ int stt[CHUNK + 1];
  const int t0 = c * CHUNK;
  const unsigned char* pg = (const unsigned char*)(ws + OFF_PTR);
  for (int idx = tid; idx < CHUNK * 16; idx += 64)
    pl[idx] = pg[((size_t)b * NSTEPS + t0) * 16 + idx];
  __syncthreads();
  if (tid == 0) {
    const int* bs = (const int*)(ws + OFF_BS);
    int st = bs[b * (NCHUNK + 1) + (c + 1)];
    stt[CHUNK] = st;
    for (int s2 = CHUNK; s2 >= 1; --s2) { st = pl[(s2 - 1) * 16 + st]; stt[s2 - 1] = st; }
  }
  __syncthreads();
  const int nt = (c == NCHUNK - 1) ? (CHUNK + 1) : CHUNK;
  if (tid < nt) {
    const int t = t0 + tid;
    const int st = stt[tid];
    size_t fi = ((size_t)b * NS + t) * 16 + st;
    float fq = ws[OFF_FREQ + fi];
    float lv = ws[OFF_LFV + fi];
    ws[OFF_F0 + (size_t)b * NS + t] = (lv > 0.f) ? fq : 0.f;
  }
}

// ---------- K8: median-5 with edge padding ----------
__global__ __launch_bounds__(256) void k_median(const float* __restrict__ ws, float* __restrict__ out) {
  const int b = blockIdx.y;
  const int t = blockIdx.x * 256 + threadIdx.x;
  if (t >= NS) return;
  const float* f0 = ws + OFF_F0 + (size_t)b * NS;
  float a0 = f0[max(t - 2, 0)];
  float a1 = f0[max(t - 1, 0)];
  float a2 = f0[t];
  float a3 = f0[min(t + 1, NS - 1)];
  float a4 = f0[min(t + 2, NS - 1)];
#define SW(u, w) { float lo_ = fminf(u, w), hi_ = fmaxf(u, w); u = lo_; w = hi_; }
  SW(a0, a1) SW(a1, a2) SW(a2, a3) SW(a3, a4)
  SW(a0, a1) SW(a1, a2) SW(a2, a3)
  SW(a0, a1) SW(a1, a2)
#undef SW
  out[(size_t)b * NS + t] = a2;
}

extern "C" void kernel_launch(void* const* d_in, const int* in_sizes, int n_in,
                              void* d_out, int out_size, void* d_ws, size_t ws_size,
                              hipStream_t stream) {
  const float* x = (const float*)d_in[0];
  float* ws = (float*)d_ws;
  float* out = (float*)d_out;
  hipLaunchKernelGGL(k_setup, dim3(1), dim3(256), 0, stream, ws);
  hipLaunchKernelGGL(k_gpeak, dim3(64, NB), dim3(256), 0, stream, x, ws);
  hipLaunchKernelGGL(k_frames, dim3((NS + 3) / 4, NB), dim3(256), 0, stream, x, ws);
  hipLaunchKernelGGL(k_chunkmat, dim3(NCHUNK, NB), dim3(256), 0, stream, ws);
  hipLaunchKernelGGL(k_scan, dim3(NB), dim3(64), 0, stream, ws);
  hipLaunchKernelGGL(k_viterbi, dim3(NCHUNK, NB), dim3(256), 0, stream, ws);
  hipLaunchKernelGGL(k_compose, dim3(1), dim3(256), 0, stream, ws);
  hipLaunchKernelGGL(k_select, dim3(NCHUNK, NB), dim3(64), 0, stream, ws);
  hipLaunchKernelGGL(k_median, dim3((NS + 255) / 256, NB), dim3(256), 0, stream, ws, out);
}

// Round 8
// 283.414 us; speedup vs baseline: 3.2084x; 1.0536x over previous
//
#include <hip/hip_runtime.h>

#define NB 16
#define NT 960000
#define NS 6001
#define TOPK 15
#define NSTEPS 6000
#define CHUNK 100
#define NCHUNK 60
#define FLOORV -100000.0f

typedef __attribute__((ext_vector_type(8))) short short8;
typedef __attribute__((ext_vector_type(4))) float f32x4;
typedef __attribute__((ext_vector_type(2))) float f32x2;
typedef __attribute__((ext_vector_type(4))) unsigned int u32x4;

// ---- workspace layout (offsets in floats) ----
constexpr size_t OFF_NACW  = 0;                                    // 216 floats (INVERSE nacw)
constexpr size_t OFF_WIN   = 256;                                  // 257 floats (hann window)
constexpr size_t OFF_GPEAK = 520;                                  // 16 floats (max|x| bits)
constexpr size_t OFF_FREQ  = 576;
constexpr size_t PERFR     = (size_t)NB * NS * 16;                 // per-frame arrays, K padded to 16
constexpr size_t OFF_LFV   = OFF_FREQ + PERFR;                     // packed: voiced? +log2(f) : -log2(f)
constexpr size_t OFF_DELTA = OFF_LFV + PERFR;
constexpr size_t OFF_UNUSED= OFF_DELTA + PERFR;
constexpr size_t OFF_P     = OFF_UNUSED + PERFR;                   // NB*NCHUNK*256 chunk matrices
constexpr size_t OFF_VENT  = OFF_P + (size_t)NB * NCHUNK * 256;    // NB*(NCHUNK+1)*16 entry vectors
constexpr size_t OFF_VFIN  = OFF_VENT + (size_t)NB * (NCHUNK + 1) * 16; // unused
constexpr size_t OFF_F0    = OFF_VFIN + 256;                       // NB*NS f0 (pre-median)
constexpr size_t OFF_BS    = OFF_F0 + 96032;                       // int32 boundary states NB*(NCHUNK+1)
constexpr size_t OFF_PTR   = OFF_BS + 2048;                        // uint8 ptrs NB*NSTEPS*16 bytes
constexpr size_t OFF_BMAP  = OFF_PTR + (size_t)NB * NSTEPS * 4;    // uint8 backmaps NB*NCHUNK*16 bytes

__device__ __forceinline__ unsigned ordf(float f) {
  unsigned u = __float_as_uint(f);
  return (u & 0x80000000u) ? ~u : (u | 0x80000000u);
}

// transition cost from packed lf-values (sign bit = unvoiced)
__device__ __forceinline__ float tr_of(float sa, float sb) {
  int xs = __float_as_int(sa) ^ __float_as_int(sb);
  float t = 0.35f * fabsf(sa - sb);
  t = (__float_as_int(sa) < 0) ? 0.f : t;   // both unvoiced -> 0
  return (xs < 0) ? 0.14f : t;              // mixed -> C_VUV
}

// ---------- K0: window + inverse window-ACF + zero gpeak ----------
__global__ __launch_bounds__(256) void k_setup(float* __restrict__ ws) {
  __shared__ float win[257];
  __shared__ float w0sh;
  const int tid = threadIdx.x;
  for (int n = tid; n < 257; n += 256) {
    float w = 0.5f * (1.0f - cosf((6.2831855f * (float)n) / 257.0f));
    win[n] = w;
    ws[OFF_WIN + n] = w;
  }
  __syncthreads();
  float s = 0.f;
  if (tid < 216) {
    for (int n = 0; n + tid < 257; ++n) s += win[n] * win[n + tid];
  }
  if (tid == 0) w0sh = s;
  __syncthreads();
  if (tid < 216) ws[OFF_NACW + tid] = w0sh / s;   // inverse of nacw
  if (tid < NB) ws[OFF_GPEAK + tid] = 0.0f;
}

// ---------- K1: per-batch global peak of |x| ----------
__global__ __launch_bounds__(256) void k_gpeak(const float* __restrict__ x, float* __restrict__ ws) {
  const int b = blockIdx.y;
  const float4* xb = (const float4*)(x + (size_t)b * NT);
  const int n4 = NT / 4;
  float m = 0.f;
  for (int i = blockIdx.x * blockDim.x + threadIdx.x; i < n4; i += gridDim.x * blockDim.x) {
    float4 v = xb[i];
    m = fmaxf(m, fmaxf(fmaxf(fabsf(v.x), fabsf(v.y)), fmaxf(fabsf(v.z), fabsf(v.w))));
  }
  for (int off = 32; off; off >>= 1) m = fmaxf(m, __shfl_down(m, off));
  __shared__ float sm[4];
  if ((threadIdx.x & 63) == 0) sm[threadIdx.x >> 6] = m;
  __syncthreads();
  if (threadIdx.x == 0) {
    m = fmaxf(fmaxf(sm[0], sm[1]), fmaxf(sm[2], sm[3]));
    atomicMax((unsigned*)(ws + OFF_GPEAK) + b, __float_as_uint(m));
  }
}

__device__ __forceinline__ unsigned bf16rne(float f) {
  unsigned u = __float_as_uint(f);
  return (u + 0x7FFFu + ((u >> 16) & 1u)) >> 16;   // bf16 bits in low 16
}

__device__ __forceinline__ short8 bfrag(const char* p, int sh) {
  unsigned w0 = *(const unsigned*)(p);
  unsigned w1 = *(const unsigned*)(p + 4);
  unsigned w2 = *(const unsigned*)(p + 8);
  unsigned w3 = *(const unsigned*)(p + 12);
  unsigned w4 = *(const unsigned*)(p + 16);
  u32x4 o;
  o[0] = __builtin_amdgcn_alignbit(w1, w0, sh);
  o[1] = __builtin_amdgcn_alignbit(w2, w1, sh);
  o[2] = __builtin_amdgcn_alignbit(w3, w2, sh);
  o[3] = __builtin_amdgcn_alignbit(w4, w3, sh);
  return __builtin_bit_cast(short8, o);
}

// ---------- K2: one wave = one frame; bf16x3-split MFMA ACF; parallel top-k ----------
// per wave (floats): HI bf16[576] @[0,288) | LO @[288,576) | ACF @[576,800)
//   TQ/FREQ @[800,1016) | LOGIT @[1016,1232) | CK u64 [1232,1656) | SEL @[1656,1672)
__global__ __launch_bounds__(256, 4) void k_frames(const float* __restrict__ x, float* __restrict__ ws) {
  const int wv = threadIdx.x >> 6;
  const int g  = threadIdx.x & 63;
  const int s  = blockIdx.x * 4 + wv;
  const int b  = blockIdx.y;
  __shared__ __align__(16) float LA[4][1680];
  if (s >= NS) return;
  float* L = LA[wv];
  char* Lb = (char*)L;
  const size_t xb = (size_t)b * NT;
  const int c0 = 40 * s;               // float4 chunk base

  // ---- load frame ----
  float4 xv = make_float4(0.f, 0.f, 0.f, 0.f);
  if (c0 + g < NT / 4) xv = ((const float4*)(x + xb))[c0 + g];
  float x256 = 0.f;
  if (g == 0) {
    int i256 = 160 * s + 256;
    if (i256 < NT) x256 = x[xb + i256];
  }

  // ---- mean over 257 raw samples ----
  float ps = ((xv.x + xv.y) + (xv.z + xv.w)) + x256;
#pragma unroll
  for (int off = 32; off; off >>= 1) ps += __shfl_xor(ps, off);
  const float mean = ps / 257.0f;

  // ---- window + local peak ----
  float4 w4 = ((const float4*)(ws + OFF_WIN))[g];
  float4 f4;
  f4.x = (xv.x - mean) * w4.x;
  f4.y = (xv.y - mean) * w4.y;
  f4.z = (xv.z - mean) * w4.z;
  f4.w = (xv.w - mean) * w4.w;
  float fr256 = 0.f;
  if (g == 0) fr256 = (x256 - mean) * ws[OFF_WIN + 256];
  float apk = fmaxf(fmaxf(fabsf(f4.x), fabsf(f4.y)), fmaxf(fabsf(f4.z), fabsf(f4.w)));
  if (g == 0) apk = fmaxf(apk, fabsf(fr256));
#pragma unroll
  for (int off = 32; off; off >>= 1) apk = fmaxf(apk, __shfl_xor(apk, off));

  // ---- build hi/lo bf16 buffers: buf[i] = fr[i-16], zero-padded to 576 elems ----
  {
    unsigned hx = bf16rne(f4.x), hy = bf16rne(f4.y), hz = bf16rne(f4.z), hw = bf16rne(f4.w);
    float lx = f4.x - __uint_as_float(hx << 16);
    float ly = f4.y - __uint_as_float(hy << 16);
    float lz = f4.z - __uint_as_float(hz << 16);
    float lw = f4.w - __uint_as_float(hw << 16);
    unsigned ph0 = hx | (hy << 16), ph1 = hz | (hw << 16);
    unsigned pl0 = bf16rne(lx) | (bf16rne(ly) << 16);
    unsigned pl1 = bf16rne(lz) | (bf16rne(lw) << 16);
    if (g < 8) { L[g] = 0.f; L[288 + g] = 0.f; }                     // elems 0..15
    f32x2 vh = {__uint_as_float(ph0), __uint_as_float(ph1)};
    f32x2 vl = {__uint_as_float(pl0), __uint_as_float(pl1)};
    *(f32x2*)&L[8 + 2 * g] = vh;                                     // elems 16+4g..19+4g
    *(f32x2*)&L[288 + 8 + 2 * g] = vl;
    if (g < 76) {                                                    // elems 272..575 zero
      f32x2 z = {0.f, 0.f};
      *(f32x2*)&L[136 + 2 * g] = z;
      *(f32x2*)&L[288 + 136 + 2 * g] = z;
    }
    if (g == 0) {                                                    // patch elem 272 = fr[256]
      unsigned h2 = bf16rne(fr256);
      float l2 = fr256 - __uint_as_float(h2 << 16);
      ((unsigned short*)Lb)[272] = (unsigned short)h2;
      ((unsigned short*)(Lb + 1152))[272] = (unsigned short)bf16rne(l2);
    }
  }
  __builtin_amdgcn_wave_barrier();

  // ---- ACF via MFMA: C[a][b] = sum_k buf[k+16a]*buf[k+b] = acf[16a-b] ----
  const int bcol = g & 15, h = g >> 4;
  const int sh = 16 * (bcol & 1);
  const int hi4 = ((bcol & 3) >= 2) ? 4 : 0;
  const int Ab0 = 16 * h + 32 * bcol;
  const int Bb0 = 16 * h + ((2 * bcol) & ~7) + hi4;
  const char* Hb = Lb;
  const char* Ob = Lb + 1152;
  f32x4 acc = {0.f, 0.f, 0.f, 0.f};
#pragma unroll
  for (int kk = 0; kk < 10; ++kk) {
    short8 ah = __builtin_bit_cast(short8, *(const u32x4*)(Hb + Ab0 + 64 * kk));
    short8 al = __builtin_bit_cast(short8, *(const u32x4*)(Ob + Ab0 + 64 * kk));
    short8 bh = bfrag(Hb + Bb0 + 64 * kk, sh);
    short8 bl = bfrag(Ob + Bb0 + 64 * kk, sh);
    acc = __builtin_amdgcn_mfma_f32_16x16x32_bf16(ah, bh, acc, 0, 0, 0);
    acc = __builtin_amdgcn_mfma_f32_16x16x32_bf16(ah, bl, acc, 0, 0, 0);
    acc = __builtin_amdgcn_mfma_f32_16x16x32_bf16(al, bh, acc, 0, 0, 0);
  }
  __builtin_amdgcn_wave_barrier();
  // scatter: lane holds C rows 4h+r, col bcol
#pragma unroll
  for (int r = 0; r < 4; ++r) {
    int arow = 4 * h + r;
    int tau = 16 * arow - bcol;
    if (arow == 0 ? (bcol == 0) : (tau <= 215)) L[576 + (arow ? tau : 0)] = acc[r];
  }
  __builtin_amdgcn_wave_barrier();

  // ---- nacf + candidates (lane g<53: candidates 4g..4g+3) ----
  const float inv0 = 1.0f / L[576];
  bool  flv[4] = {false, false, false, false};
  float lgv[4];
  if (g < 53) {
    f32x4 A4 = *(const f32x4*)&L[576 + 4 * g];
    f32x2 A2 = *(const f32x2*)&L[580 + 4 * g];
    f32x4 I4 = *(const f32x4*)(ws + OFF_NACW + 4 * g);
    f32x2 I2 = *(const f32x2*)(ws + OFF_NACW + 4 * g + 4);
    float nn[6];
    nn[0] = A4[0] * inv0 * I4[0];
    nn[1] = A4[1] * inv0 * I4[1];
    nn[2] = A4[2] * inv0 * I4[2];
    nn[3] = A4[3] * inv0 * I4[3];
    nn[4] = A2.x * inv0 * I2.x;
    nn[5] = A2.y * inv0 * I2.y;
    float fqv[4];
#pragma unroll
    for (int a = 0; a < 4; ++a) {
      float pm = nn[a], cm = nn[a + 1], nm = nn[a + 2];
      bool flag = (cm - pm >= 0.f) && (nm - cm <= 0.f) && (cm > 0.225f);
      float dr = (0.5f * (nm - pm)) / ((2.0f * cm - nm) - pm);   // exact div (decision-adjacent)
      float tq = dr + (float)(4 * g + a);
      tq = (tq > 0.f) ? tq : 0.f;     // NaN -> 0: output-invariant
      float fq = 16000.0f / (1.0f + tq);                          // exact div (600-boundary)
      float l1p = __log2f(1.0f + tq);
      float lg = cm;
      if (lg > 1.0f) lg = __builtin_amdgcn_rcpf(lg);
      lg = lg - 0.01f * (l1p - 7.736965594166206f);   // == cm' - 0.01*log2(75/fq)
      flv[a] = flag;
      fqv[a] = fq;
      lgv[a] = flag ? lg : FLOORV;
    }
    f32x4 fo = {fqv[0], fqv[1], fqv[2], fqv[3]};
    f32x4 lo_ = {lgv[0], lgv[1], lgv[2], lgv[3]};
    *(f32x4*)&L[800 + 4 * g] = fo;
    *(f32x4*)&L[1016 + 4 * g] = lo_;
  }

  // ---- top-15 selection ----
  unsigned long long bb0b = __ballot(flv[0]);
  unsigned long long bb1 = __ballot(flv[1]);
  unsigned long long bb2 = __ballot(flv[2]);
  unsigned long long bb3 = __ballot(flv[3]);
  const int nv = __popcll(bb0b) + __popcll(bb1) + __popcll(bb2) + __popcll(bb3);
  int* sel = (int*)&L[1656];
  if (nv > 0) {
    unsigned long long below = (1ull << g) - 1ull;
    int base = __popcll(bb0b & below) + __popcll(bb1 & below) +
               __popcll(bb2 & below) + __popcll(bb3 & below);
    if (nv <= TOPK) {
      if (g < 53) {
        int cnt = base;
#pragma unroll
        for (int a = 0; a < 4; ++a) {
          int c = 4 * g + a;
          if (flv[a]) {
            sel[cnt] = c;
            ++cnt;
          } else {
            int ur = c - cnt;
            if (ur < TOPK - nv) sel[nv + ur] = c;
          }
        }
      }
    } else {
      unsigned long long* CK = (unsigned long long*)&L[1232];   // 212 keys fit [1232,1656)
      if (g < 53) {
        int cnt = base;
#pragma unroll
        for (int a = 0; a < 4; ++a) {
          if (flv[a]) {
            CK[cnt] = (((unsigned long long)ordf(lgv[a])) << 32)
                    | (unsigned long long)(0xFFFFFFFFu - (unsigned)(4 * g + a));
            ++cnt;
          }
        }
      }
      __builtin_amdgcn_wave_barrier();
      for (int l = g; l < nv; l += 64) {
        unsigned long long kl = CK[l];
        int rank = 0;
        for (int m = 0; m < nv; ++m) rank += (CK[m] > kl) ? 1 : 0;
        if (rank < TOPK) sel[rank] = (int)(0xFFFFFFFFu - (unsigned)(kl & 0xFFFFFFFFull));
      }
    }
  }
  __builtin_amdgcn_wave_barrier();

  // ---- per-frame outputs (lanes 0..15; slot 15 = fixed dead-state fill) ----
  if (g < 16) {
    size_t fi = ((size_t)b * NS + s) * 16 + g;
    if (g == TOPK) {
      ws[OFF_FREQ + fi] = 0.f;
      ws[OFF_LFV + fi] = -1.0f;   // unvoiced sentinel (state 15 is never selectable)
      ws[OFF_DELTA + fi] = 0.f;
    } else {
      int c = (nv == 0) ? g : sel[g];
      float fq = L[800 + c];
      float lg = L[1016 + c];
      int voi = (lg > FLOORV) && (fq < 600.0f);
      float gp = ws[OFF_GPEAK + b];
      float inten = (apk > gp) ? 1.0f : apk * __builtin_amdgcn_rcpf(gp);
      float luv = 0.45f + fmaxf(2.0f - inten * 48.333333333333336f, 0.f);
      float l2 = __log2f(fq);
      float dlt = voi ? (lg - 0.01f * (9.228818690495881f - l2)) : luv;
      ws[OFF_FREQ + fi] = fq;
      ws[OFF_LFV + fi] = voi ? l2 : -l2;
      ws[OFF_DELTA + fi] = dlt;
    }
  }
}

// ---------- K3: per-chunk max-plus product matrices (textbook 2-barrier) ----------
__global__ __launch_bounds__(256) void k_chunkmat(float* __restrict__ ws) {
  const int c = blockIdx.x, b = blockIdx.y, tid = threadIdx.x;
  const int i = tid >> 4, j = tid & 15;
  __shared__ float Msh[16][17];
  __shared__ float Psh[2][16][17];
  const float* LFV = ws + OFF_LFV;
  const float* DEL = ws + OFF_DELTA;
  const size_t fb = (size_t)b * NS;
  const int t0 = c * CHUNK;
  float sA = LFV[(fb + t0) * 16 + i];
  float sB = LFV[(fb + t0 + 1) * 16 + j];
  float dB = DEL[(fb + t0 + 1) * 16 + j];
  Psh[0][i][j] = (i == j) ? 0.f : -INFINITY;   // max-plus identity
  int src = 0;
  float pn = 0.f;
  for (int s = 1; s <= CHUNK; ++s) {
    Msh[i][j] = dB - tr_of(sA, sB);
    __syncthreads();                 // M + P[src] visible to all
    if (s < CHUNK) {
      const int t = t0 + s;
      sA = LFV[(fb + t) * 16 + i];
      sB = LFV[(fb + t + 1) * 16 + j];
      dB = DEL[(fb + t + 1) * 16 + j];
    }
    pn = -INFINITY;
#pragma unroll
    for (int k = 0; k < 15; ++k) pn = fmaxf(pn, Psh[src][i][k] + Msh[k][j]);
    Psh[src ^ 1][i][j] = pn;
    __syncthreads();                 // all reads of M/P[src] done before next overwrite
    src ^= 1;
  }
  ws[OFF_P + ((size_t)(b * NCHUNK + c)) * 256 + tid] = pn;
}

// ---------- K4: scan chunk matrices -> entry value vectors (1 wave / batch) ----------
__global__ __launch_bounds__(64) void k_scan(float* __restrict__ ws) {
  const int b = blockIdx.x, l = threadIdx.x;
  __shared__ float v[16];
  const float* DEL = ws + OFF_DELTA;
  const size_t fb = (size_t)b * NS;
  if (l < 16) {
    float d0 = DEL[fb * 16 + l];
    v[l] = d0;
    ws[OFF_VENT + ((size_t)b * (NCHUNK + 1)) * 16 + l] = d0;
  }
  __syncthreads();
  const float4* Pg = (const float4*)(ws + OFF_P + (size_t)b * NCHUNK * 256);
  const int k = l >> 2;
  float4 cur = Pg[l];    // element offset 4l = k*16 + (l&3)*4
  for (int c = 0; c < NCHUNK; ++c) {
    float4 nxt = cur;
    if (c + 1 < NCHUNK) nxt = Pg[(size_t)(c + 1) * 64 + l];
    float vk = (k < 15) ? v[k] : -INFINITY;
    float4 t;
    t.x = vk + cur.x; t.y = vk + cur.y; t.z = vk + cur.z; t.w = vk + cur.w;
    if (k == 15) { t.x = -INFINITY; t.y = -INFINITY; t.z = -INFINITY; t.w = -INFINITY; }
#pragma unroll
    for (int off = 4; off < 64; off <<= 1) {
      t.x = fmaxf(t.x, __shfl_xor(t.x, off));
      t.y = fmaxf(t.y, __shfl_xor(t.y, off));
      t.z = fmaxf(t.z, __shfl_xor(t.z, off));
      t.w = fmaxf(t.w, __shfl_xor(t.w, off));
    }
    __syncthreads();                 // all v[k] reads done before overwrite
    if (l < 4) {
      *(float4*)&v[4 * l] = *(float4*)&t;
      ((float4*)(ws + OFF_VENT + ((size_t)b * (NCHUNK + 1) + c + 1) * 16))[l] = *(float4*)&t;
    }
    __syncthreads();                 // new v visible
    cur = nxt;
  }
}

// ---------- K5: per-chunk sequential Viterbi (exact op order) -> ptrs + backmaps ----------
__global__ __launch_bounds__(256) void k_viterbi(float* __restrict__ ws) {
  const int c = blockIdx.x, b = blockIdx.y, tid = threadIdx.x;
  const int i = tid & 15, j = tid >> 4;
  __shared__ float val[2][16];
  __shared__ __align__(16) unsigned char ptl[CHUNK][16];
  const float* LFV = ws + OFF_LFV;
  const float* DEL = ws + OFF_DELTA;
  const size_t fb = (size_t)b * NS;
  const int t0 = c * CHUNK;
  if (tid < 16) {
    val[0][tid] = ws[OFF_VENT + ((size_t)b * (NCHUNK + 1) + c) * 16 + tid];
    val[1][tid] = -INFINITY;
  }
  float sA = LFV[(fb + t0) * 16 + i];
  float sB = LFV[(fb + t0 + 1) * 16 + j];
  float dB = DEL[(fb + t0 + 1) * 16 + j];
  int src = 0;
  for (int s = 1; s <= CHUNK; ++s) {
    __syncthreads();                 // val[src] visible
    float sc = (val[src][i] - tr_of(sA, sB)) + dB;   // reference op order
    if (i == 15) sc = -INFINITY;
    if (s < CHUNK) {
      const int t = t0 + s;
      sA = LFV[(fb + t) * 16 + i];
      sB = LFV[(fb + t + 1) * 16 + j];
      dB = DEL[(fb + t + 1) * 16 + j];
    }
    float mx = sc;
#pragma unroll
    for (int off = 1; off < 16; off <<= 1) mx = fmaxf(mx, __shfl_xor(mx, off));
    unsigned long long bal = __ballot(sc == mx);
    int nib = (int)((bal >> (tid & 48)) & 0xFFFFull);
    int bi = __ffs(nib) - 1;                     // lowest i on ties (reference argmax)
    __syncthreads();                 // all val[src] reads done before overwrite
    if (i == 0 && j < 15) {
      val[src ^ 1][j] = mx;
      ptl[s - 1][j] = (unsigned char)bi;
    }
    src ^= 1;
  }
  __syncthreads();
  // dump ptrs coalesced (CHUNK*4 = 400 u32 > 256 threads -> loop)
  unsigned* pg = (unsigned*)(ws + OFF_PTR);
  for (int idx = tid; idx < CHUNK * 4; idx += 256)
    pg[((size_t)b * NSTEPS + t0) * 4 + idx] = ((unsigned*)ptl)[idx];
  // per-chunk backtrack map: exit state -> entry state
  if (tid < TOPK) {
    int st = tid;
#pragma unroll 1
    for (int s2 = CHUNK - 1; s2 >= 0; --s2) st = ptl[s2][st];
    ((unsigned char*)(ws + OFF_BMAP))[((size_t)(b * NCHUNK + c)) * 16 + tid] = (unsigned char)st;
  }
}

// ---------- K6: compose backmaps -> chunk-boundary states ----------
__global__ __launch_bounds__(256) void k_compose(float* __restrict__ ws) {
  __shared__ unsigned char bm[NB * NCHUNK * 16];
  const int tid = threadIdx.x;
  const unsigned char* bg = (const unsigned char*)(ws + OFF_BMAP);
  for (int idx = tid; idx < NB * NCHUNK * 16; idx += 256) bm[idx] = bg[idx];
  __syncthreads();
  if (tid < NB) {
    const int b = tid;
    float best = -INFINITY; int bi = 0;
    for (int jj = 0; jj < TOPK; ++jj) {
      float vv = ws[OFF_VENT + ((size_t)b * (NCHUNK + 1) + NCHUNK) * 16 + jj];
      if (vv > best) { best = vv; bi = jj; }   // strict > : first max
    }
    int* bs = (int*)(ws + OFF_BS);
    int st = bi;
    bs[b * (NCHUNK + 1) + NCHUNK] = st;
    for (int cc = NCHUNK - 1; cc >= 0; --cc) {
      st = bm[((size_t)(b * NCHUNK + cc)) * 16 + st];
      bs[b * (NCHUNK + 1) + cc] = st;
    }
  }
}

// ---------- K7: per-chunk state walk -> f0 ----------
__global__ __launch_bounds__(64) void k_select(float* __restrict__ ws) {
  const int c = blockIdx.x, b = blockIdx.y, tid = threadIdx.x;
  __shared__ unsigned char pl[CHUNK * 16];
  __shared__ int stt[CHUNK + 1];
  const int t0 = c * CHUNK;
  const unsigned char* pg = (const unsigned char*)(ws + OFF_PTR);
  for (int idx = tid; idx < CHUNK * 16; idx += 64)
    pl[idx] = pg[((size_t)b * NSTEPS + t0) * 16 + idx];
  __syncthreads();
  if (tid == 0) {
    const int* bs = (const int*)(ws + OFF_BS);
    int st = bs[b * (NCHUNK + 1) + (c + 1)];
    stt[CHUNK] = st;
    for (int s2 = CHUNK; s2 >= 1; --s2) { st = pl[(s2 - 1) * 16 + st]; stt[s2 - 1] = st; }
  }
  __syncthreads();
  const int nt = (c == NCHUNK - 1) ? (CHUNK + 1) : CHUNK;   // nt up to 101 > 64 -> loop
  for (int u = tid; u < nt; u += 64) {
    const int t = t0 + u;
    const int st = stt[u];
    size_t fi = ((size_t)b * NS + t) * 16 + st;
    float fq = ws[OFF_FREQ + fi];
    float lv = ws[OFF_LFV + fi];
    ws[OFF_F0 + (size_t)b * NS + t] = (lv > 0.f) ? fq : 0.f;
  }
}

// ---------- K8: median-5 with edge padding ----------
__global__ __launch_bounds__(256) void k_median(const float* __restrict__ ws, float* __restrict__ out) {
  const int b = blockIdx.y;
  const int t = blockIdx.x * 256 + threadIdx.x;
  if (t >= NS) return;
  const float* f0 = ws + OFF_F0 + (size_t)b * NS;
  float a0 = f0[max(t - 2, 0)];
  float a1 = f0[max(t - 1, 0)];
  float a2 = f0[t];
  float a3 = f0[min(t + 1, NS - 1)];
  float a4 = f0[min(t + 2, NS - 1)];
#define SW(u, w) { float lo_ = fminf(u, w), hi_ = fmaxf(u, w); u = lo_; w = hi_; }
  SW(a0, a1) SW(a1, a2) SW(a2, a3) SW(a3, a4)
  SW(a0, a1) SW(a1, a2) SW(a2, a3)
  SW(a0, a1) SW(a1, a2)
#undef SW
  out[(size_t)b * NS + t] = a2;
}

extern "C" void kernel_launch(void* const* d_in, const int* in_sizes, int n_in,
                              void* d_out, int out_size, void* d_ws, size_t ws_size,
                              hipStream_t stream) {
  const float* x = (const float*)d_in[0];
  float* ws = (float*)d_ws;
  float* out = (float*)d_out;
  hipLaunchKernelGGL(k_setup, dim3(1), dim3(256), 0, stream, ws);
  hipLaunchKernelGGL(k_gpeak, dim3(64, NB), dim3(256), 0, stream, x, ws);
  hipLaunchKernelGGL(k_frames, dim3((NS + 3) / 4, NB), dim3(256), 0, stream, x, ws);
  hipLaunchKernelGGL(k_chunkmat, dim3(NCHUNK, NB), dim3(256), 0, stream, ws);
  hipLaunchKernelGGL(k_scan, dim3(NB), dim3(64), 0, stream, ws);
  hipLaunchKernelGGL(k_viterbi, dim3(NCHUNK, NB), dim3(256), 0, stream, ws);
  hipLaunchKernelGGL(k_compose, dim3(1), dim3(256), 0, stream, ws);
  hipLaunchKernelGGL(k_select, dim3(NCHUNK, NB), dim3(64), 0, stream, ws);
  hipLaunchKernelGGL(k_median, dim3((NS + 255) / 256, NB), dim3(256), 0, stream, ws, out);
}

// Round 9
// 261.078 us; speedup vs baseline: 3.4828x; 1.0856x over previous
//
#include <hip/hip_runtime.h>

#define NB 16
#define NT 960000
#define NS 6001
#define TOPK 15
#define NSTEPS 6000
#define CHUNK 100
#define NCHUNK 60
#define FLOORV -100000.0f

typedef __attribute__((ext_vector_type(8))) short short8;
typedef __attribute__((ext_vector_type(4))) float f32x4;
typedef __attribute__((ext_vector_type(2))) float f32x2;
typedef __attribute__((ext_vector_type(4))) unsigned int u32x4;

// ---- workspace layout (offsets in floats) ----
constexpr size_t OFF_NACW  = 0;                                    // 216 floats (INVERSE nacw)
constexpr size_t OFF_WIN   = 256;                                  // 257 floats (hann window)
constexpr size_t OFF_GPEAK = 520;                                  // 16 floats (max|x| bits)
constexpr size_t OFF_FREQ  = 576;
constexpr size_t PERFR     = (size_t)NB * NS * 16;                 // per-frame arrays, K padded to 16
constexpr size_t OFF_LFV   = OFF_FREQ + PERFR;                     // packed: voiced? +log2(f) : -log2(f)
constexpr size_t OFF_DELTA = OFF_LFV + PERFR;
constexpr size_t OFF_UNUSED= OFF_DELTA + PERFR;
constexpr size_t OFF_P     = OFF_UNUSED + PERFR;                   // NB*NCHUNK*256 chunk matrices
constexpr size_t OFF_VENT  = OFF_P + (size_t)NB * NCHUNK * 256;    // NB*(NCHUNK+1)*16 entry vectors
constexpr size_t OFF_VFIN  = OFF_VENT + (size_t)NB * (NCHUNK + 1) * 16; // unused
constexpr size_t OFF_F0    = OFF_VFIN + 256;                       // NB*NS f0 (pre-median)
constexpr size_t OFF_BS    = OFF_F0 + 96032;                       // int32 boundary states NB*(NCHUNK+1)
constexpr size_t OFF_PTR   = OFF_BS + 2048;                        // uint8 ptrs NB*NSTEPS*16 bytes
constexpr size_t OFF_BMAP  = OFF_PTR + (size_t)NB * NSTEPS * 4;    // uint8 backmaps NB*NCHUNK*16 bytes

__device__ __forceinline__ unsigned ordf(float f) {
  unsigned u = __float_as_uint(f);
  return (u & 0x80000000u) ? ~u : (u | 0x80000000u);
}

// transition cost from packed lf-values (sign bit = unvoiced)
__device__ __forceinline__ float tr_of(float sa, float sb) {
  int xs = __float_as_int(sa) ^ __float_as_int(sb);
  float t = 0.35f * fabsf(sa - sb);
  t = (__float_as_int(sa) < 0) ? 0.f : t;   // both unvoiced -> 0
  return (xs < 0) ? 0.14f : t;              // mixed -> C_VUV
}

// ---------- K0: window + inverse window-ACF + zero gpeak ----------
__global__ __launch_bounds__(256) void k_setup(float* __restrict__ ws) {
  __shared__ float win[257];
  __shared__ float w0sh;
  const int tid = threadIdx.x;
  for (int n = tid; n < 257; n += 256) {
    float w = 0.5f * (1.0f - cosf((6.2831855f * (float)n) / 257.0f));
    win[n] = w;
    ws[OFF_WIN + n] = w;
  }
  __syncthreads();
  float s = 0.f;
  if (tid < 216) {
    for (int n = 0; n + tid < 257; ++n) s += win[n] * win[n + tid];
  }
  if (tid == 0) w0sh = s;
  __syncthreads();
  if (tid < 216) ws[OFF_NACW + tid] = w0sh / s;   // inverse of nacw
  if (tid < NB) ws[OFF_GPEAK + tid] = 0.0f;
}

// ---------- K1: per-batch global peak of |x| ----------
__global__ __launch_bounds__(256) void k_gpeak(const float* __restrict__ x, float* __restrict__ ws) {
  const int b = blockIdx.y;
  const float4* xb = (const float4*)(x + (size_t)b * NT);
  const int n4 = NT / 4;
  float m = 0.f;
  for (int i = blockIdx.x * blockDim.x + threadIdx.x; i < n4; i += gridDim.x * blockDim.x) {
    float4 v = xb[i];
    m = fmaxf(m, fmaxf(fmaxf(fabsf(v.x), fabsf(v.y)), fmaxf(fabsf(v.z), fabsf(v.w))));
  }
  for (int off = 32; off; off >>= 1) m = fmaxf(m, __shfl_down(m, off));
  __shared__ float sm[4];
  if ((threadIdx.x & 63) == 0) sm[threadIdx.x >> 6] = m;
  __syncthreads();
  if (threadIdx.x == 0) {
    m = fmaxf(fmaxf(sm[0], sm[1]), fmaxf(sm[2], sm[3]));
    atomicMax((unsigned*)(ws + OFF_GPEAK) + b, __float_as_uint(m));
  }
}

__device__ __forceinline__ unsigned bf16rne(float f) {
  unsigned u = __float_as_uint(f);
  return (u + 0x7FFFu + ((u >> 16) & 1u)) >> 16;   // bf16 bits in low 16
}

__device__ __forceinline__ short8 bfrag(const char* p, int sh) {
  unsigned w0 = *(const unsigned*)(p);
  unsigned w1 = *(const unsigned*)(p + 4);
  unsigned w2 = *(const unsigned*)(p + 8);
  unsigned w3 = *(const unsigned*)(p + 12);
  unsigned w4 = *(const unsigned*)(p + 16);
  u32x4 o;
  o[0] = __builtin_amdgcn_alignbit(w1, w0, sh);
  o[1] = __builtin_amdgcn_alignbit(w2, w1, sh);
  o[2] = __builtin_amdgcn_alignbit(w3, w2, sh);
  o[3] = __builtin_amdgcn_alignbit(w4, w3, sh);
  return __builtin_bit_cast(short8, o);
}

// ---------- K2: one wave = one frame; bf16x3-split MFMA ACF; parallel top-k ----------
// per wave (floats): HI bf16[576] @[0,288) | LO @[288,576) | ACF @[576,800)
//   TQ @[800,1016) | LOGIT @[1016,1232) | CK u64 [1232,1656) | SEL @[1656,1672)
__global__ __launch_bounds__(256, 6) void k_frames(const float* __restrict__ x, float* __restrict__ ws) {
  const int wv = threadIdx.x >> 6;
  const int g  = threadIdx.x & 63;
  const int s  = blockIdx.x * 4 + wv;
  const int b  = blockIdx.y;
  __shared__ __align__(16) float LA[4][1680];
  if (s >= NS) return;
  float* L = LA[wv];
  char* Lb = (char*)L;
  const size_t xb = (size_t)b * NT;
  const int c0 = 40 * s;               // float4 chunk base

  // ---- load frame ----
  float4 xv = make_float4(0.f, 0.f, 0.f, 0.f);
  if (c0 + g < NT / 4) xv = ((const float4*)(x + xb))[c0 + g];
  float x256 = 0.f;
  if (g == 0) {
    int i256 = 160 * s + 256;
    if (i256 < NT) x256 = x[xb + i256];
  }

  // ---- mean over 257 raw samples ----
  float ps = ((xv.x + xv.y) + (xv.z + xv.w)) + x256;
#pragma unroll
  for (int off = 32; off; off >>= 1) ps += __shfl_xor(ps, off);
  const float mean = ps / 257.0f;

  // ---- window + local peak ----
  float4 w4 = ((const float4*)(ws + OFF_WIN))[g];
  float4 f4;
  f4.x = (xv.x - mean) * w4.x;
  f4.y = (xv.y - mean) * w4.y;
  f4.z = (xv.z - mean) * w4.z;
  f4.w = (xv.w - mean) * w4.w;
  float fr256 = 0.f;
  if (g == 0) fr256 = (x256 - mean) * ws[OFF_WIN + 256];
  float apk = fmaxf(fmaxf(fabsf(f4.x), fabsf(f4.y)), fmaxf(fabsf(f4.z), fabsf(f4.w)));
  if (g == 0) apk = fmaxf(apk, fabsf(fr256));
#pragma unroll
  for (int off = 32; off; off >>= 1) apk = fmaxf(apk, __shfl_xor(apk, off));

  // ---- build hi/lo bf16 buffers: buf[i] = fr[i-16], zero-padded to 576 elems ----
  {
    unsigned hx = bf16rne(f4.x), hy = bf16rne(f4.y), hz = bf16rne(f4.z), hw = bf16rne(f4.w);
    float lx = f4.x - __uint_as_float(hx << 16);
    float ly = f4.y - __uint_as_float(hy << 16);
    float lz = f4.z - __uint_as_float(hz << 16);
    float lw = f4.w - __uint_as_float(hw << 16);
    unsigned ph0 = hx | (hy << 16), ph1 = hz | (hw << 16);
    unsigned pl0 = bf16rne(lx) | (bf16rne(ly) << 16);
    unsigned pl1 = bf16rne(lz) | (bf16rne(lw) << 16);
    if (g < 8) { L[g] = 0.f; L[288 + g] = 0.f; }                     // elems 0..15
    f32x2 vh = {__uint_as_float(ph0), __uint_as_float(ph1)};
    f32x2 vl = {__uint_as_float(pl0), __uint_as_float(pl1)};
    *(f32x2*)&L[8 + 2 * g] = vh;                                     // elems 16+4g..19+4g
    *(f32x2*)&L[288 + 8 + 2 * g] = vl;
    if (g < 76) {                                                    // elems 272..575 zero
      f32x2 z = {0.f, 0.f};
      *(f32x2*)&L[136 + 2 * g] = z;
      *(f32x2*)&L[288 + 136 + 2 * g] = z;
    }
    if (g == 0) {                                                    // patch elem 272 = fr[256]
      unsigned h2 = bf16rne(fr256);
      float l2 = fr256 - __uint_as_float(h2 << 16);
      ((unsigned short*)Lb)[272] = (unsigned short)h2;
      ((unsigned short*)(Lb + 1152))[272] = (unsigned short)bf16rne(l2);
    }
  }
  __builtin_amdgcn_wave_barrier();

  // ---- ACF via MFMA: C[a][b] = sum_k buf[k+16a]*buf[k+b] = acf[16a-b] ----
  const int bcol = g & 15, h = g >> 4;
  const int sh = 16 * (bcol & 1);
  const int hi4 = ((bcol & 3) >= 2) ? 4 : 0;
  const int Ab0 = 16 * h + 32 * bcol;
  const int Bb0 = 16 * h + ((2 * bcol) & ~7) + hi4;
  const char* Hb = Lb;
  const char* Ob = Lb + 1152;
  f32x4 acc = {0.f, 0.f, 0.f, 0.f};
#pragma unroll
  for (int kk = 0; kk < 10; ++kk) {
    short8 ah = __builtin_bit_cast(short8, *(const u32x4*)(Hb + Ab0 + 64 * kk));
    short8 al = __builtin_bit_cast(short8, *(const u32x4*)(Ob + Ab0 + 64 * kk));
    short8 bh = bfrag(Hb + Bb0 + 64 * kk, sh);
    short8 bl = bfrag(Ob + Bb0 + 64 * kk, sh);
    acc = __builtin_amdgcn_mfma_f32_16x16x32_bf16(ah, bh, acc, 0, 0, 0);
    acc = __builtin_amdgcn_mfma_f32_16x16x32_bf16(ah, bl, acc, 0, 0, 0);
    acc = __builtin_amdgcn_mfma_f32_16x16x32_bf16(al, bh, acc, 0, 0, 0);
  }
  __builtin_amdgcn_wave_barrier();
  // scatter: lane holds C rows 4h+r, col bcol
#pragma unroll
  for (int r = 0; r < 4; ++r) {
    int arow = 4 * h + r;
    int tau = 16 * arow - bcol;
    if (arow == 0 ? (bcol == 0) : (tau <= 215)) L[576 + (arow ? tau : 0)] = acc[r];
  }
  __builtin_amdgcn_wave_barrier();

  // ---- nacf + candidates (lane g<53: candidates 4g..4g+3); fq DEFERRED to selection ----
  const float inv0 = 1.0f / L[576];
  bool  flv[4] = {false, false, false, false};
  float lgv[4];
  if (g < 53) {
    f32x4 A4 = *(const f32x4*)&L[576 + 4 * g];
    f32x2 A2 = *(const f32x2*)&L[580 + 4 * g];
    f32x4 I4 = *(const f32x4*)(ws + OFF_NACW + 4 * g);
    f32x2 I2 = *(const f32x2*)(ws + OFF_NACW + 4 * g + 4);
    float nn[6];
    nn[0] = A4[0] * inv0 * I4[0];
    nn[1] = A4[1] * inv0 * I4[1];
    nn[2] = A4[2] * inv0 * I4[2];
    nn[3] = A4[3] * inv0 * I4[3];
    nn[4] = A2.x * inv0 * I2.x;
    nn[5] = A2.y * inv0 * I2.y;
    float tqv[4];
#pragma unroll
    for (int a = 0; a < 4; ++a) {
      float pm = nn[a], cm = nn[a + 1], nm = nn[a + 2];
      bool flag = (cm - pm >= 0.f) && (nm - cm <= 0.f) && (cm > 0.225f);
      float dr = (0.5f * (nm - pm)) / ((2.0f * cm - nm) - pm);   // exact div (decision-adjacent)
      float tq = dr + (float)(4 * g + a);
      tq = (tq > 0.f) ? tq : 0.f;     // NaN -> 0: output-invariant
      float l1p = __log2f(1.0f + tq);
      float lg = cm;
      if (lg > 1.0f) lg = __builtin_amdgcn_rcpf(lg);
      lg = lg - 0.01f * (l1p - 7.736965594166206f);   // == cm' - 0.01*log2(75/fq)
      flv[a] = flag;
      tqv[a] = tq;
      lgv[a] = flag ? lg : FLOORV;
    }
    f32x4 to_ = {tqv[0], tqv[1], tqv[2], tqv[3]};
    f32x4 lo_ = {lgv[0], lgv[1], lgv[2], lgv[3]};
    *(f32x4*)&L[800 + 4 * g] = to_;
    *(f32x4*)&L[1016 + 4 * g] = lo_;
  }

  // ---- top-15 selection ----
  unsigned long long bb0b = __ballot(flv[0]);
  unsigned long long bb1 = __ballot(flv[1]);
  unsigned long long bb2 = __ballot(flv[2]);
  unsigned long long bb3 = __ballot(flv[3]);
  const int nv = __popcll(bb0b) + __popcll(bb1) + __popcll(bb2) + __popcll(bb3);
  int* sel = (int*)&L[1656];
  if (nv > 0) {
    unsigned long long below = (1ull << g) - 1ull;
    int base = __popcll(bb0b & below) + __popcll(bb1 & below) +
               __popcll(bb2 & below) + __popcll(bb3 & below);
    if (nv <= TOPK) {
      if (g < 53) {
        int cnt = base;
#pragma unroll
        for (int a = 0; a < 4; ++a) {
          int c = 4 * g + a;
          if (flv[a]) {
            sel[cnt] = c;
            ++cnt;
          } else {
            int ur = c - cnt;
            if (ur < TOPK - nv) sel[nv + ur] = c;
          }
        }
      }
    } else {
      unsigned long long* CK = (unsigned long long*)&L[1232];   // 212 keys fit [1232,1656)
      if (g < 53) {
        int cnt = base;
#pragma unroll
        for (int a = 0; a < 4; ++a) {
          if (flv[a]) {
            CK[cnt] = (((unsigned long long)ordf(lgv[a])) << 32)
                    | (unsigned long long)(0xFFFFFFFFu - (unsigned)(4 * g + a));
            ++cnt;
          }
        }
      }
      __builtin_amdgcn_wave_barrier();
      for (int l = g; l < nv; l += 64) {
        unsigned long long kl = CK[l];
        int rank = 0;
        for (int m = 0; m < nv; ++m) rank += (CK[m] > kl) ? 1 : 0;
        if (rank < TOPK) sel[rank] = (int)(0xFFFFFFFFu - (unsigned)(kl & 0xFFFFFFFFull));
      }
    }
  }
  __builtin_amdgcn_wave_barrier();

  // ---- per-frame outputs (lanes 0..15; slot 15 = fixed dead-state fill) ----
  if (g < 16) {
    size_t fi = ((size_t)b * NS + s) * 16 + g;
    if (g == TOPK) {
      ws[OFF_FREQ + fi] = 0.f;
      ws[OFF_LFV + fi] = -1.0f;   // unvoiced sentinel (state 15 is never selectable)
      ws[OFF_DELTA + fi] = 0.f;
    } else {
      int c = (nv == 0) ? g : sel[g];
      float tq = L[800 + c];
      float lg = L[1016 + c];
      float fq = 16000.0f / (1.0f + tq);                  // same div, same input bits as before
      int voi = (lg > FLOORV) && (fq < 600.0f);
      float gp = ws[OFF_GPEAK + b];
      float inten = (apk > gp) ? 1.0f : apk * __builtin_amdgcn_rcpf(gp);
      float luv = 0.45f + fmaxf(2.0f - inten * 48.333333333333336f, 0.f);
      float l2 = __log2f(fq);
      float dlt = voi ? (lg - 0.01f * (9.228818690495881f - l2)) : luv;
      ws[OFF_FREQ + fi] = fq;
      ws[OFF_LFV + fi] = voi ? l2 : -l2;
      ws[OFF_DELTA + fi] = dlt;
    }
  }
}

// ---------- K3: per-chunk max-plus product matrices (double-buffered, 1 barrier/step) ----------
__global__ __launch_bounds__(256) void k_chunkmat(float* __restrict__ ws) {
  const int c = blockIdx.x, b = blockIdx.y, tid = threadIdx.x;
  const int i = tid >> 4, j = tid & 15;
  __shared__ float MT[2][16][20];     // MT[buf][j][k], rows 80B (16B-aligned)
  __shared__ float Psh[2][16][20];
  const float* LFV = ws + OFF_LFV;
  const float* DEL = ws + OFF_DELTA;
  const size_t fb = (size_t)b * NS;
  const int t0 = c * CHUNK;
  float sA = LFV[(fb + t0) * 16 + i];
  float sB = LFV[(fb + t0 + 1) * 16 + j];
  float dB = DEL[(fb + t0 + 1) * 16 + j];
  Psh[0][i][j] = (i == j) ? 0.f : -INFINITY;   // max-plus identity
  int src = 0;
  float pn = 0.f;
  for (int s = 1; s <= CHUNK; ++s) {
    const int mb = s & 1;
    MT[mb][j][i] = dB - tr_of(sA, sB);         // transposed store
    __syncthreads();                            // MT[mb] + Psh[src] visible; prior reads done
    if (s < CHUNK) {
      const int t = t0 + s;
      sA = LFV[(fb + t) * 16 + i];
      sB = LFV[(fb + t + 1) * 16 + j];
      dB = DEL[(fb + t + 1) * 16 + j];
    }
    const float* Pr = &Psh[src][i][0];
    const float* Mr = &MT[mb][j][0];
    f32x4 t0v = *(const f32x4*)(Pr)      + *(const f32x4*)(Mr);
    f32x4 t1v = *(const f32x4*)(Pr + 4)  + *(const f32x4*)(Mr + 4);
    f32x4 t2v = *(const f32x4*)(Pr + 8)  + *(const f32x4*)(Mr + 8);
    f32x4 t3v = *(const f32x4*)(Pr + 12) + *(const f32x4*)(Mr + 12);
    f32x4 m01 = {fmaxf(t0v[0], t0v[1]), fmaxf(t0v[2], t0v[3]), fmaxf(t1v[0], t1v[1]), fmaxf(t1v[2], t1v[3])};
    f32x4 m23 = {fmaxf(t2v[0], t2v[1]), fmaxf(t2v[2], t2v[3]), fmaxf(t3v[0], t3v[1]), fmaxf(t3v[2], t3v[3])};
    pn = fmaxf(fmaxf(fmaxf(m01[0], m01[1]), fmaxf(m01[2], m01[3])),
               fmaxf(fmaxf(m23[0], m23[1]), fmaxf(m23[2], m23[3])));
    if (j == 15) pn = -INFINITY;               // dead column stays dead
    Psh[src ^ 1][i][j] = pn;
    src ^= 1;
  }
  ws[OFF_P + ((size_t)(b * NCHUNK + c)) * 256 + tid] = pn;
}

// ---------- K4: scan chunk matrices -> entry value vectors (1 wave / batch) ----------
__global__ __launch_bounds__(64) void k_scan(float* __restrict__ ws) {
  const int b = blockIdx.x, l = threadIdx.x;
  __shared__ float v[16];
  const float* DEL = ws + OFF_DELTA;
  const size_t fb = (size_t)b * NS;
  if (l < 16) {
    float d0 = DEL[fb * 16 + l];
    v[l] = d0;
    ws[OFF_VENT + ((size_t)b * (NCHUNK + 1)) * 16 + l] = d0;
  }
  __syncthreads();
  const float4* Pg = (const float4*)(ws + OFF_P + (size_t)b * NCHUNK * 256);
  const int k = l >> 2;
  float4 cur = Pg[l];    // element offset 4l = k*16 + (l&3)*4
  for (int c = 0; c < NCHUNK; ++c) {
    float4 nxt = cur;
    if (c + 1 < NCHUNK) nxt = Pg[(size_t)(c + 1) * 64 + l];
    float vk = (k < 15) ? v[k] : -INFINITY;
    float4 t;
    t.x = vk + cur.x; t.y = vk + cur.y; t.z = vk + cur.z; t.w = vk + cur.w;
    if (k == 15) { t.x = -INFINITY; t.y = -INFINITY; t.z = -INFINITY; t.w = -INFINITY; }
#pragma unroll
    for (int off = 4; off < 64; off <<= 1) {
      t.x = fmaxf(t.x, __shfl_xor(t.x, off));
      t.y = fmaxf(t.y, __shfl_xor(t.y, off));
      t.z = fmaxf(t.z, __shfl_xor(t.z, off));
      t.w = fmaxf(t.w, __shfl_xor(t.w, off));
    }
    __syncthreads();                 // all v[k] reads done before overwrite
    if (l < 4) {
      *(float4*)&v[4 * l] = *(float4*)&t;
      ((float4*)(ws + OFF_VENT + ((size_t)b * (NCHUNK + 1) + c + 1) * 16))[l] = *(float4*)&t;
    }
    __syncthreads();                 // new v visible
    cur = nxt;
  }
}

// ---------- K5: per-chunk sequential Viterbi (exact op order, 1 barrier/step) ----------
__global__ __launch_bounds__(256) void k_viterbi(float* __restrict__ ws) {
  const int c = blockIdx.x, b = blockIdx.y, tid = threadIdx.x;
  const int i = tid & 15, j = tid >> 4;
  __shared__ float val[2][16];
  __shared__ __align__(16) unsigned char ptl[CHUNK][16];
  const float* LFV = ws + OFF_LFV;
  const float* DEL = ws + OFF_DELTA;
  const size_t fb = (size_t)b * NS;
  const int t0 = c * CHUNK;
  if (tid < 16) {
    val[0][tid] = ws[OFF_VENT + ((size_t)b * (NCHUNK + 1) + c) * 16 + tid];
    val[1][tid] = -INFINITY;
  }
  float sA = LFV[(fb + t0) * 16 + i];
  float sB = LFV[(fb + t0 + 1) * 16 + j];
  float dB = DEL[(fb + t0 + 1) * 16 + j];
  int src = 0;
  for (int s = 1; s <= CHUNK; ++s) {
    __syncthreads();                 // val[src] writes from prev step visible; prev reads done
    float sc = (val[src][i] - tr_of(sA, sB)) + dB;   // reference op order
    if (i == 15) sc = -INFINITY;
    if (s < CHUNK) {
      const int t = t0 + s;
      sA = LFV[(fb + t) * 16 + i];
      sB = LFV[(fb + t + 1) * 16 + j];
      dB = DEL[(fb + t + 1) * 16 + j];
    }
    float mx = sc;
#pragma unroll
    for (int off = 1; off < 16; off <<= 1) mx = fmaxf(mx, __shfl_xor(mx, off));
    unsigned long long bal = __ballot(sc == mx);
    int nib = (int)((bal >> (tid & 48)) & 0xFFFFull);
    int bi = __ffs(nib) - 1;                     // lowest i on ties (reference argmax)
    if (i == 0 && j < 15) {
      val[src ^ 1][j] = mx;
      ptl[s - 1][j] = (unsigned char)bi;
    }
    src ^= 1;
  }
  __syncthreads();
  // dump ptrs coalesced (CHUNK*4 = 400 u32 > 256 threads -> loop)
  unsigned* pg = (unsigned*)(ws + OFF_PTR);
  for (int idx = tid; idx < CHUNK * 4; idx += 256)
    pg[((size_t)b * NSTEPS + t0) * 4 + idx] = ((unsigned*)ptl)[idx];
  // per-chunk backtrack map: exit state -> entry state
  if (tid < TOPK) {
    int st = tid;
#pragma unroll 1
    for (int s2 = CHUNK - 1; s2 >= 0; --s2) st = ptl[s2][st];
    ((unsigned char*)(ws + OFF_BMAP))[((size_t)(b * NCHUNK + c)) * 16 + tid] = (unsigned char)st;
  }
}

// ---------- K6: compose backmaps -> chunk-boundary states ----------
__global__ __launch_bounds__(256) void k_compose(float* __restrict__ ws) {
  __shared__ unsigned char bm[NB * NCHUNK * 16];
  const int tid = threadIdx.x;
  const unsigned char* bg = (const unsigned char*)(ws + OFF_BMAP);
  for (int idx = tid; idx < NB * NCHUNK * 16; idx += 256) bm[idx] = bg[idx];
  __syncthreads();
  if (tid < NB) {
    const int b = tid;
    float best = -INFINITY; int bi = 0;
    for (int jj = 0; jj < TOPK; ++jj) {
      float vv = ws[OFF_VENT + ((size_t)b * (NCHUNK + 1) + NCHUNK) * 16 + jj];
      if (vv > best) { best = vv; bi = jj; }   // strict > : first max
    }
    int* bs = (int*)(ws + OFF_BS);
    int st = bi;
    bs[b * (NCHUNK + 1) + NCHUNK] = st;
    for (int cc = NCHUNK - 1; cc >= 0; --cc) {
      st = bm[((size_t)(b * NCHUNK + cc)) * 16 + st];
      bs[b * (NCHUNK + 1) + cc] = st;
    }
  }
}

// ---------- K7: per-chunk state walk -> f0 ----------
__global__ __launch_bounds__(64) void k_select(float* __restrict__ ws) {
  const int c = blockIdx.x, b = blockIdx.y, tid = threadIdx.x;
  __shared__ unsigned char pl[CHUNK * 16];
  __shared__ int stt[CHUNK + 1];
  const int t0 = c * CHUNK;
  const unsigned char* pg = (const unsigned char*)(ws + OFF_PTR);
  for (int idx = tid; idx < CHUNK * 16; idx += 64)
    pl[idx] = pg[((size_t)b * NSTEPS + t0) * 16 + idx];
  __syncthreads();
  if (tid == 0) {
    const int* bs = (const int*)(ws + OFF_BS);
    int st = bs[b * (NCHUNK + 1) + (c + 1)];
    stt[CHUNK] = st;
    for (int s2 = CHUNK; s2 >= 1; --s2) { st = pl[(s2 - 1) * 16 + st]; stt[s2 - 1] = st; }
  }
  __syncthreads();
  const int nt = (c == NCHUNK - 1) ? (CHUNK + 1) : CHUNK;   // nt up to 101 > 64 -> loop
  for (int u = tid; u < nt; u += 64) {
    const int t = t0 + u;
    const int st = stt[u];
    size_t fi = ((size_t)b * NS + t) * 16 + st;
    float fq = ws[OFF_FREQ + fi];
    float lv = ws[OFF_LFV + fi];
    ws[OFF_F0 + (size_t)b * NS + t] = (lv > 0.f) ? fq : 0.f;
  }
}

// ---------- K8: median-5 with edge padding ----------
__global__ __launch_bounds__(256) void k_median(const float* __restrict__ ws, float* __restrict__ out) {
  const int b = blockIdx.y;
  const int t = blockIdx.x * 256 + threadIdx.x;
  if (t >= NS) return;
  const float* f0 = ws + OFF_F0 + (size_t)b * NS;
  float a0 = f0[max(t - 2, 0)];
  float a1 = f0[max(t - 1, 0)];
  float a2 = f0[t];
  float a3 = f0[min(t + 1, NS - 1)];
  float a4 = f0[min(t + 2, NS - 1)];
#define SW(u, w) { float lo_ = fminf(u, w), hi_ = fmaxf(u, w); u = lo_; w = hi_; }
  SW(a0, a1) SW(a1, a2) SW(a2, a3) SW(a3, a4)
  SW(a0, a1) SW(a1, a2) SW(a2, a3)
  SW(a0, a1) SW(a1, a2)
#undef SW
  out[(size_t)b * NS + t] = a2;
}

extern "C" void kernel_launch(void* const* d_in, const int* in_sizes, int n_in,
                              void* d_out, int out_size, void* d_ws, size_t ws_size,
                              hipStream_t stream) {
  const float* x = (const float*)d_in[0];
  float* ws = (float*)d_ws;
  float* out = (float*)d_out;
  hipLaunchKernelGGL(k_setup, dim3(1), dim3(256), 0, stream, ws);
  hipLaunchKernelGGL(k_gpeak, dim3(64, NB), dim3(256), 0, stream, x, ws);
  hipLaunchKernelGGL(k_frames, dim3((NS + 3) / 4, NB), dim3(256), 0, stream, x, ws);
  hipLaunchKernelGGL(k_chunkmat, dim3(NCHUNK, NB), dim3(256), 0, stream, ws);
  hipLaunchKernelGGL(k_scan, dim3(NB), dim3(64), 0, stream, ws);
  hipLaunchKernelGGL(k_viterbi, dim3(NCHUNK, NB), dim3(256), 0, stream, ws);
  hipLaunchKernelGGL(k_compose, dim3(1), dim3(256), 0, stream, ws);
  hipLaunchKernelGGL(k_select, dim3(NCHUNK, NB), dim3(64), 0, stream, ws);
  hipLaunchKernelGGL(k_median, dim3((NS + 255) / 256, NB), dim3(256), 0, stream, ws, out);
}

// Round 10
// 256.365 us; speedup vs baseline: 3.5469x; 1.0184x over previous
//
#include <hip/hip_runtime.h>

#define NB 16
#define NT 960000
#define NS 6001
#define TOPK 15
#define NSTEPS 6000
#define CHUNK 100
#define NCHUNK 60
#define FLOORV -100000.0f

typedef __attribute__((ext_vector_type(8))) short short8;
typedef __attribute__((ext_vector_type(4))) float f32x4;
typedef __attribute__((ext_vector_type(2))) float f32x2;
typedef __attribute__((ext_vector_type(4))) unsigned int u32x4;

// ---- workspace layout (offsets in floats) ----
constexpr size_t OFF_NACW  = 0;                                    // 216 floats (INVERSE nacw)
constexpr size_t OFF_WIN   = 256;                                  // 257 floats (hann window)
constexpr size_t OFF_GPEAK = 520;                                  // 16 floats (max|x| bits)
constexpr size_t OFF_FREQ  = 576;
constexpr size_t PERFR     = (size_t)NB * NS * 16;                 // per-frame arrays, K padded to 16
constexpr size_t OFF_LFV   = OFF_FREQ + PERFR;                     // packed: voiced? +log2(f) : -log2(f)
constexpr size_t OFF_DELTA = OFF_LFV + PERFR;
constexpr size_t OFF_UNUSED= OFF_DELTA + PERFR;
constexpr size_t OFF_P     = OFF_UNUSED + PERFR;                   // NB*NCHUNK*256 chunk matrices
constexpr size_t OFF_VENT  = OFF_P + (size_t)NB * NCHUNK * 256;    // NB*(NCHUNK+1)*16 entry vectors
constexpr size_t OFF_VFIN  = OFF_VENT + (size_t)NB * (NCHUNK + 1) * 16; // unused
constexpr size_t OFF_F0    = OFF_VFIN + 256;                       // NB*NS f0 (pre-median)
constexpr size_t OFF_BS    = OFF_F0 + 96032;                       // int32 boundary states NB*(NCHUNK+1)
constexpr size_t OFF_PTR   = OFF_BS + 2048;                        // uint8 ptrs NB*NSTEPS*16 bytes
constexpr size_t OFF_BMAP  = OFF_PTR + (size_t)NB * NSTEPS * 4;    // uint8 backmaps NB*NCHUNK*16 bytes

__device__ __forceinline__ unsigned ordf(float f) {
  unsigned u = __float_as_uint(f);
  return (u & 0x80000000u) ? ~u : (u | 0x80000000u);
}

// transition cost from packed lf-values (sign bit = unvoiced)
__device__ __forceinline__ float tr_of(float sa, float sb) {
  int xs = __float_as_int(sa) ^ __float_as_int(sb);
  float t = 0.35f * fabsf(sa - sb);
  t = (__float_as_int(sa) < 0) ? 0.f : t;   // both unvoiced -> 0
  return (xs < 0) ? 0.14f : t;              // mixed -> C_VUV
}

// ---------- K0: window + inverse window-ACF + zero gpeak ----------
__global__ __launch_bounds__(256) void k_setup(float* __restrict__ ws) {
  __shared__ float win[257];
  __shared__ float w0sh;
  const int tid = threadIdx.x;
  for (int n = tid; n < 257; n += 256) {
    float w = 0.5f * (1.0f - cosf((6.2831855f * (float)n) / 257.0f));
    win[n] = w;
    ws[OFF_WIN + n] = w;
  }
  __syncthreads();
  float s = 0.f;
  if (tid < 216) {
    for (int n = 0; n + tid < 257; ++n) s += win[n] * win[n + tid];
  }
  if (tid == 0) w0sh = s;
  __syncthreads();
  if (tid < 216) ws[OFF_NACW + tid] = w0sh / s;   // inverse of nacw
  if (tid < NB) ws[OFF_GPEAK + tid] = 0.0f;
}

// ---------- K1: per-batch global peak of |x| ----------
__global__ __launch_bounds__(256) void k_gpeak(const float* __restrict__ x, float* __restrict__ ws) {
  const int b = blockIdx.y;
  const float4* xb = (const float4*)(x + (size_t)b * NT);
  const int n4 = NT / 4;
  float m = 0.f;
  for (int i = blockIdx.x * blockDim.x + threadIdx.x; i < n4; i += gridDim.x * blockDim.x) {
    float4 v = xb[i];
    m = fmaxf(m, fmaxf(fmaxf(fabsf(v.x), fabsf(v.y)), fmaxf(fabsf(v.z), fabsf(v.w))));
  }
  for (int off = 32; off; off >>= 1) m = fmaxf(m, __shfl_down(m, off));
  __shared__ float sm[4];
  if ((threadIdx.x & 63) == 0) sm[threadIdx.x >> 6] = m;
  __syncthreads();
  if (threadIdx.x == 0) {
    m = fmaxf(fmaxf(sm[0], sm[1]), fmaxf(sm[2], sm[3]));
    atomicMax((unsigned*)(ws + OFF_GPEAK) + b, __float_as_uint(m));
  }
}

__device__ __forceinline__ unsigned bf16rne(float f) {
  unsigned u = __float_as_uint(f);
  return (u + 0x7FFFu + ((u >> 16) & 1u)) >> 16;   // bf16 bits in low 16
}

__device__ __forceinline__ short8 bfrag(const char* p, int sh) {
  unsigned w0 = *(const unsigned*)(p);
  unsigned w1 = *(const unsigned*)(p + 4);
  unsigned w2 = *(const unsigned*)(p + 8);
  unsigned w3 = *(const unsigned*)(p + 12);
  unsigned w4 = *(const unsigned*)(p + 16);
  u32x4 o;
  o[0] = __builtin_amdgcn_alignbit(w1, w0, sh);
  o[1] = __builtin_amdgcn_alignbit(w2, w1, sh);
  o[2] = __builtin_amdgcn_alignbit(w3, w2, sh);
  o[3] = __builtin_amdgcn_alignbit(w4, w3, sh);
  return __builtin_bit_cast(short8, o);
}

// ---------- K2: one wave = one frame; bf16x3-split MFMA ACF; parallel top-k ----------
// per-wave LDS (floats), REGION-REUSED for 8 blocks/CU occupancy:
//   phase 1 (staging+MFMA): HI bf16[576] @[0,288) | LO @[288,576)
//   phase 2 (scatter):      ACF @[576,800)
//   phase 3 (candidates):   TQ @[0,216) over HI | LG @[288,504) over LO
//   phase 4 (top-k):        CK u64 @[800,1224) | SEL @[1224,1240)
// Same-wave DS ops are in-order; wave_barriers separate the phases, so the
// TQ/LG overwrite of HI/LO cannot precede the MFMA-phase reads.
__global__ __launch_bounds__(256, 8) void k_frames(const float* __restrict__ x, float* __restrict__ ws) {
  const int wv = threadIdx.x >> 6;
  const int g  = threadIdx.x & 63;
  const int s  = blockIdx.x * 4 + wv;
  const int b  = blockIdx.y;
  __shared__ __align__(16) float LA[4][1240];
  if (s >= NS) return;
  float* L = LA[wv];
  char* Lb = (char*)L;
  const size_t xb = (size_t)b * NT;
  const int c0 = 40 * s;               // float4 chunk base

  // ---- load frame ----
  float4 xv = make_float4(0.f, 0.f, 0.f, 0.f);
  if (c0 + g < NT / 4) xv = ((const float4*)(x + xb))[c0 + g];
  float x256 = 0.f;
  if (g == 0) {
    int i256 = 160 * s + 256;
    if (i256 < NT) x256 = x[xb + i256];
  }

  // ---- mean over 257 raw samples ----
  float ps = ((xv.x + xv.y) + (xv.z + xv.w)) + x256;
#pragma unroll
  for (int off = 32; off; off >>= 1) ps += __shfl_xor(ps, off);
  const float mean = ps / 257.0f;

  // ---- window + local peak ----
  float4 w4 = ((const float4*)(ws + OFF_WIN))[g];
  float4 f4;
  f4.x = (xv.x - mean) * w4.x;
  f4.y = (xv.y - mean) * w4.y;
  f4.z = (xv.z - mean) * w4.z;
  f4.w = (xv.w - mean) * w4.w;
  float fr256 = 0.f;
  if (g == 0) fr256 = (x256 - mean) * ws[OFF_WIN + 256];
  float apk = fmaxf(fmaxf(fabsf(f4.x), fabsf(f4.y)), fmaxf(fabsf(f4.z), fabsf(f4.w)));
  if (g == 0) apk = fmaxf(apk, fabsf(fr256));
#pragma unroll
  for (int off = 32; off; off >>= 1) apk = fmaxf(apk, __shfl_xor(apk, off));

  // ---- build hi/lo bf16 buffers: buf[i] = fr[i-16], zero-padded to 576 elems ----
  {
    unsigned hx = bf16rne(f4.x), hy = bf16rne(f4.y), hz = bf16rne(f4.z), hw = bf16rne(f4.w);
    float lx = f4.x - __uint_as_float(hx << 16);
    float ly = f4.y - __uint_as_float(hy << 16);
    float lz = f4.z - __uint_as_float(hz << 16);
    float lw = f4.w - __uint_as_float(hw << 16);
    unsigned ph0 = hx | (hy << 16), ph1 = hz | (hw << 16);
    unsigned pl0 = bf16rne(lx) | (bf16rne(ly) << 16);
    unsigned pl1 = bf16rne(lz) | (bf16rne(lw) << 16);
    if (g < 8) { L[g] = 0.f; L[288 + g] = 0.f; }                     // elems 0..15
    f32x2 vh = {__uint_as_float(ph0), __uint_as_float(ph1)};
    f32x2 vl = {__uint_as_float(pl0), __uint_as_float(pl1)};
    *(f32x2*)&L[8 + 2 * g] = vh;                                     // elems 16+4g..19+4g
    *(f32x2*)&L[288 + 8 + 2 * g] = vl;
    if (g < 76) {                                                    // elems 272..575 zero
      f32x2 z = {0.f, 0.f};
      *(f32x2*)&L[136 + 2 * g] = z;
      *(f32x2*)&L[288 + 136 + 2 * g] = z;
    }
    if (g == 0) {                                                    // patch elem 272 = fr[256]
      unsigned h2 = bf16rne(fr256);
      float l2 = fr256 - __uint_as_float(h2 << 16);
      ((unsigned short*)Lb)[272] = (unsigned short)h2;
      ((unsigned short*)(Lb + 1152))[272] = (unsigned short)bf16rne(l2);
    }
  }
  __builtin_amdgcn_wave_barrier();

  // ---- ACF via MFMA: C[a][b] = sum_k buf[k+16a]*buf[k+b] = acf[16a-b] ----
  const int bcol = g & 15, h = g >> 4;
  const int sh = 16 * (bcol & 1);
  const int hi4 = ((bcol & 3) >= 2) ? 4 : 0;
  const int Ab0 = 16 * h + 32 * bcol;
  const int Bb0 = 16 * h + ((2 * bcol) & ~7) + hi4;
  const char* Hb = Lb;
  const char* Ob = Lb + 1152;
  f32x4 acc = {0.f, 0.f, 0.f, 0.f};
#pragma unroll
  for (int kk = 0; kk < 10; ++kk) {
    short8 ah = __builtin_bit_cast(short8, *(const u32x4*)(Hb + Ab0 + 64 * kk));
    short8 al = __builtin_bit_cast(short8, *(const u32x4*)(Ob + Ab0 + 64 * kk));
    short8 bh = bfrag(Hb + Bb0 + 64 * kk, sh);
    short8 bl = bfrag(Ob + Bb0 + 64 * kk, sh);
    acc = __builtin_amdgcn_mfma_f32_16x16x32_bf16(ah, bh, acc, 0, 0, 0);
    acc = __builtin_amdgcn_mfma_f32_16x16x32_bf16(ah, bl, acc, 0, 0, 0);
    acc = __builtin_amdgcn_mfma_f32_16x16x32_bf16(al, bh, acc, 0, 0, 0);
  }
  __builtin_amdgcn_wave_barrier();
  // scatter: lane holds C rows 4h+r, col bcol
#pragma unroll
  for (int r = 0; r < 4; ++r) {
    int arow = 4 * h + r;
    int tau = 16 * arow - bcol;
    if (arow == 0 ? (bcol == 0) : (tau <= 215)) L[576 + (arow ? tau : 0)] = acc[r];
  }
  __builtin_amdgcn_wave_barrier();

  // ---- nacf + candidates (lane g<53: candidates 4g..4g+3); fq deferred ----
  // TQ -> [0,216) (over HI), LG -> [288,504) (over LO): staging regions are dead.
  const float inv0 = 1.0f / L[576];
  bool  flv[4] = {false, false, false, false};
  float lgv[4];
  if (g < 53) {
    f32x4 A4 = *(const f32x4*)&L[576 + 4 * g];
    f32x2 A2 = *(const f32x2*)&L[580 + 4 * g];
    f32x4 I4 = *(const f32x4*)(ws + OFF_NACW + 4 * g);
    f32x2 I2 = *(const f32x2*)(ws + OFF_NACW + 4 * g + 4);
    float nn[6];
    nn[0] = A4[0] * inv0 * I4[0];
    nn[1] = A4[1] * inv0 * I4[1];
    nn[2] = A4[2] * inv0 * I4[2];
    nn[3] = A4[3] * inv0 * I4[3];
    nn[4] = A2.x * inv0 * I2.x;
    nn[5] = A2.y * inv0 * I2.y;
    float tqv[4];
#pragma unroll
    for (int a = 0; a < 4; ++a) {
      float pm = nn[a], cm = nn[a + 1], nm = nn[a + 2];
      bool flag = (cm - pm >= 0.f) && (nm - cm <= 0.f) && (cm > 0.225f);
      float dr = (0.5f * (nm - pm)) / ((2.0f * cm - nm) - pm);   // exact div (decision-adjacent)
      float tq = dr + (float)(4 * g + a);
      tq = (tq > 0.f) ? tq : 0.f;     // NaN -> 0: output-invariant
      float l1p = __log2f(1.0f + tq);
      float lg = cm;
      if (lg > 1.0f) lg = __builtin_amdgcn_rcpf(lg);
      lg = lg - 0.01f * (l1p - 7.736965594166206f);   // == cm' - 0.01*log2(75/fq)
      flv[a] = flag;
      tqv[a] = tq;
      lgv[a] = flag ? lg : FLOORV;
    }
    f32x4 to_ = {tqv[0], tqv[1], tqv[2], tqv[3]};
    f32x4 lo_ = {lgv[0], lgv[1], lgv[2], lgv[3]};
    *(f32x4*)&L[0 + 4 * g] = to_;
    *(f32x4*)&L[288 + 4 * g] = lo_;
  }

  // ---- top-15 selection ----
  unsigned long long bb0b = __ballot(flv[0]);
  unsigned long long bb1 = __ballot(flv[1]);
  unsigned long long bb2 = __ballot(flv[2]);
  unsigned long long bb3 = __ballot(flv[3]);
  const int nv = __popcll(bb0b) + __popcll(bb1) + __popcll(bb2) + __popcll(bb3);
  int* sel = (int*)&L[1224];
  if (nv > 0) {
    unsigned long long below = (1ull << g) - 1ull;
    int base = __popcll(bb0b & below) + __popcll(bb1 & below) +
               __popcll(bb2 & below) + __popcll(bb3 & below);
    if (nv <= TOPK) {
      if (g < 53) {
        int cnt = base;
#pragma unroll
        for (int a = 0; a < 4; ++a) {
          int c = 4 * g + a;
          if (flv[a]) {
            sel[cnt] = c;
            ++cnt;
          } else {
            int ur = c - cnt;
            if (ur < TOPK - nv) sel[nv + ur] = c;
          }
        }
      }
    } else {
      unsigned long long* CK = (unsigned long long*)&L[800];   // 212 keys fit [800,1224)
      if (g < 53) {
        int cnt = base;
#pragma unroll
        for (int a = 0; a < 4; ++a) {
          if (flv[a]) {
            CK[cnt] = (((unsigned long long)ordf(lgv[a])) << 32)
                    | (unsigned long long)(0xFFFFFFFFu - (unsigned)(4 * g + a));
            ++cnt;
          }
        }
      }
      __builtin_amdgcn_wave_barrier();
      for (int l = g; l < nv; l += 64) {
        unsigned long long kl = CK[l];
        int rank = 0;
        for (int m = 0; m < nv; ++m) rank += (CK[m] > kl) ? 1 : 0;
        if (rank < TOPK) sel[rank] = (int)(0xFFFFFFFFu - (unsigned)(kl & 0xFFFFFFFFull));
      }
    }
  }
  __builtin_amdgcn_wave_barrier();

  // ---- per-frame outputs (lanes 0..15; slot 15 = fixed dead-state fill) ----
  if (g < 16) {
    size_t fi = ((size_t)b * NS + s) * 16 + g;
    if (g == TOPK) {
      ws[OFF_FREQ + fi] = 0.f;
      ws[OFF_LFV + fi] = -1.0f;   // unvoiced sentinel (state 15 is never selectable)
      ws[OFF_DELTA + fi] = 0.f;
    } else {
      int c = (nv == 0) ? g : sel[g];
      float tq = L[0 + c];
      float lg = L[288 + c];
      float fq = 16000.0f / (1.0f + tq);                  // same div, same input bits as before
      int voi = (lg > FLOORV) && (fq < 600.0f);
      float gp = ws[OFF_GPEAK + b];
      float inten = (apk > gp) ? 1.0f : apk * __builtin_amdgcn_rcpf(gp);
      float luv = 0.45f + fmaxf(2.0f - inten * 48.333333333333336f, 0.f);
      float l2 = __log2f(fq);
      float dlt = voi ? (lg - 0.01f * (9.228818690495881f - l2)) : luv;
      ws[OFF_FREQ + fi] = fq;
      ws[OFF_LFV + fi] = voi ? l2 : -l2;
      ws[OFF_DELTA + fi] = dlt;
    }
  }
}

// ---------- K3: per-chunk max-plus product matrices (double-buffered, 1 barrier/step) ----------
__global__ __launch_bounds__(256) void k_chunkmat(float* __restrict__ ws) {
  const int c = blockIdx.x, b = blockIdx.y, tid = threadIdx.x;
  const int i = tid >> 4, j = tid & 15;
  __shared__ float MT[2][16][20];     // MT[buf][j][k], rows 80B (16B-aligned)
  __shared__ float Psh[2][16][20];
  const float* LFV = ws + OFF_LFV;
  const float* DEL = ws + OFF_DELTA;
  const size_t fb = (size_t)b * NS;
  const int t0 = c * CHUNK;
  float sA = LFV[(fb + t0) * 16 + i];
  float sB = LFV[(fb + t0 + 1) * 16 + j];
  float dB = DEL[(fb + t0 + 1) * 16 + j];
  Psh[0][i][j] = (i == j) ? 0.f : -INFINITY;   // max-plus identity
  int src = 0;
  float pn = 0.f;
  for (int s = 1; s <= CHUNK; ++s) {
    const int mb = s & 1;
    MT[mb][j][i] = dB - tr_of(sA, sB);         // transposed store
    __syncthreads();                            // MT[mb] + Psh[src] visible; prior reads done
    if (s < CHUNK) {
      const int t = t0 + s;
      sA = LFV[(fb + t) * 16 + i];
      sB = LFV[(fb + t + 1) * 16 + j];
      dB = DEL[(fb + t + 1) * 16 + j];
    }
    const float* Pr = &Psh[src][i][0];
    const float* Mr = &MT[mb][j][0];
    f32x4 t0v = *(const f32x4*)(Pr)      + *(const f32x4*)(Mr);
    f32x4 t1v = *(const f32x4*)(Pr + 4)  + *(const f32x4*)(Mr + 4);
    f32x4 t2v = *(const f32x4*)(Pr + 8)  + *(const f32x4*)(Mr + 8);
    f32x4 t3v = *(const f32x4*)(Pr + 12) + *(const f32x4*)(Mr + 12);
    f32x4 m01 = {fmaxf(t0v[0], t0v[1]), fmaxf(t0v[2], t0v[3]), fmaxf(t1v[0], t1v[1]), fmaxf(t1v[2], t1v[3])};
    f32x4 m23 = {fmaxf(t2v[0], t2v[1]), fmaxf(t2v[2], t2v[3]), fmaxf(t3v[0], t3v[1]), fmaxf(t3v[2], t3v[3])};
    pn = fmaxf(fmaxf(fmaxf(m01[0], m01[1]), fmaxf(m01[2], m01[3])),
               fmaxf(fmaxf(m23[0], m23[1]), fmaxf(m23[2], m23[3])));
    if (j == 15) pn = -INFINITY;               // dead column stays dead
    Psh[src ^ 1][i][j] = pn;
    src ^= 1;
  }
  ws[OFF_P + ((size_t)(b * NCHUNK + c)) * 256 + tid] = pn;
}

// ---------- K4: scan chunk matrices -> entry value vectors (1 wave / batch) ----------
__global__ __launch_bounds__(64) void k_scan(float* __restrict__ ws) {
  const int b = blockIdx.x, l = threadIdx.x;
  __shared__ float v[16];
  const float* DEL = ws + OFF_DELTA;
  const size_t fb = (size_t)b * NS;
  if (l < 16) {
    float d0 = DEL[fb * 16 + l];
    v[l] = d0;
    ws[OFF_VENT + ((size_t)b * (NCHUNK + 1)) * 16 + l] = d0;
  }
  __syncthreads();
  const float4* Pg = (const float4*)(ws + OFF_P + (size_t)b * NCHUNK * 256);
  const int k = l >> 2;
  float4 cur = Pg[l];    // element offset 4l = k*16 + (l&3)*4
  for (int c = 0; c < NCHUNK; ++c) {
    float4 nxt = cur;
    if (c + 1 < NCHUNK) nxt = Pg[(size_t)(c + 1) * 64 + l];
    float vk = (k < 15) ? v[k] : -INFINITY;
    float4 t;
    t.x = vk + cur.x; t.y = vk + cur.y; t.z = vk + cur.z; t.w = vk + cur.w;
    if (k == 15) { t.x = -INFINITY; t.y = -INFINITY; t.z = -INFINITY; t.w = -INFINITY; }
#pragma unroll
    for (int off = 4; off < 64; off <<= 1) {
      t.x = fmaxf(t.x, __shfl_xor(t.x, off));
      t.y = fmaxf(t.y, __shfl_xor(t.y, off));
      t.z = fmaxf(t.z, __shfl_xor(t.z, off));
      t.w = fmaxf(t.w, __shfl_xor(t.w, off));
    }
    __syncthreads();                 // all v[k] reads done before overwrite
    if (l < 4) {
      *(float4*)&v[4 * l] = *(float4*)&t;
      ((float4*)(ws + OFF_VENT + ((size_t)b * (NCHUNK + 1) + c + 1) * 16))[l] = *(float4*)&t;
    }
    __syncthreads();                 // new v visible
    cur = nxt;
  }
}

// ---------- K5: per-chunk sequential Viterbi (exact op order, 1 barrier/step) ----------
__global__ __launch_bounds__(256) void k_viterbi(float* __restrict__ ws) {
  const int c = blockIdx.x, b = blockIdx.y, tid = threadIdx.x;
  const int i = tid & 15, j = tid >> 4;
  __shared__ float val[2][16];
  __shared__ __align__(16) unsigned char ptl[CHUNK][16];
  const float* LFV = ws + OFF_LFV;
  const float* DEL = ws + OFF_DELTA;
  const size_t fb = (size_t)b * NS;
  const int t0 = c * CHUNK;
  if (tid < 16) {
    val[0][tid] = ws[OFF_VENT + ((size_t)b * (NCHUNK + 1) + c) * 16 + tid];
    val[1][tid] = -INFINITY;
  }
  float sA = LFV[(fb + t0) * 16 + i];
  float sB = LFV[(fb + t0 + 1) * 16 + j];
  float dB = DEL[(fb + t0 + 1) * 16 + j];
  int src = 0;
  for (int s = 1; s <= CHUNK; ++s) {
    __syncthreads();                 // val[src] writes from prev step visible; prev reads done
    float sc = (val[src][i] - tr_of(sA, sB)) + dB;   // reference op order
    if (i == 15) sc = -INFINITY;
    if (s < CHUNK) {
      const int t = t0 + s;
      sA = LFV[(fb + t) * 16 + i];
      sB = LFV[(fb + t + 1) * 16 + j];
      dB = DEL[(fb + t + 1) * 16 + j];
    }
    float mx = sc;
#pragma unroll
    for (int off = 1; off < 16; off <<= 1) mx = fmaxf(mx, __shfl_xor(mx, off));
    unsigned long long bal = __ballot(sc == mx);
    int nib = (int)((bal >> (tid & 48)) & 0xFFFFull);
    int bi = __ffs(nib) - 1;                     // lowest i on ties (reference argmax)
    if (i == 0 && j < 15) {
      val[src ^ 1][j] = mx;
      ptl[s - 1][j] = (unsigned char)bi;
    }
    src ^= 1;
  }
  __syncthreads();
  // dump ptrs coalesced (CHUNK*4 = 400 u32 > 256 threads -> loop)
  unsigned* pg = (unsigned*)(ws + OFF_PTR);
  for (int idx = tid; idx < CHUNK * 4; idx += 256)
    pg[((size_t)b * NSTEPS + t0) * 4 + idx] = ((unsigned*)ptl)[idx];
  // per-chunk backtrack map: exit state -> entry state
  if (tid < TOPK) {
    int st = tid;
#pragma unroll 1
    for (int s2 = CHUNK - 1; s2 >= 0; --s2) st = ptl[s2][st];
    ((unsigned char*)(ws + OFF_BMAP))[((size_t)(b * NCHUNK + c)) * 16 + tid] = (unsigned char)st;
  }
}

// ---------- K6: compose backmaps -> chunk-boundary states ----------
__global__ __launch_bounds__(256) void k_compose(float* __restrict__ ws) {
  __shared__ unsigned char bm[NB * NCHUNK * 16];
  const int tid = threadIdx.x;
  const unsigned char* bg = (const unsigned char*)(ws + OFF_BMAP);
  for (int idx = tid; idx < NB * NCHUNK * 16; idx += 256) bm[idx] = bg[idx];
  __syncthreads();
  if (tid < NB) {
    const int b = tid;
    float best = -INFINITY; int bi = 0;
    for (int jj = 0; jj < TOPK; ++jj) {
      float vv = ws[OFF_VENT + ((size_t)b * (NCHUNK + 1) + NCHUNK) * 16 + jj];
      if (vv > best) { best = vv; bi = jj; }   // strict > : first max
    }
    int* bs = (int*)(ws + OFF_BS);
    int st = bi;
    bs[b * (NCHUNK + 1) + NCHUNK] = st;
    for (int cc = NCHUNK - 1; cc >= 0; --cc) {
      st = bm[((size_t)(b * NCHUNK + cc)) * 16 + st];
      bs[b * (NCHUNK + 1) + cc] = st;
    }
  }
}

// ---------- K7: per-chunk state walk -> f0 ----------
__global__ __launch_bounds__(64) void k_select(float* __restrict__ ws) {
  const int c = blockIdx.x, b = blockIdx.y, tid = threadIdx.x;
  __shared__ unsigned char pl[CHUNK * 16];
  __shared__ int stt[CHUNK + 1];
  const int t0 = c * CHUNK;
  const unsigned char* pg = (const unsigned char*)(ws + OFF_PTR);
  for (int idx = tid; idx < CHUNK * 16; idx += 64)
    pl[idx] = pg[((size_t)b * NSTEPS + t0) * 16 + idx];
  __syncthreads();
  if (tid == 0) {
    const int* bs = (const int*)(ws + OFF_BS);
    int st = bs[b * (NCHUNK + 1) + (c + 1)];
    stt[CHUNK] = st;
    for (int s2 = CHUNK; s2 >= 1; --s2) { st = pl[(s2 - 1) * 16 + st]; stt[s2 - 1] = st; }
  }
  __syncthreads();
  const int nt = (c == NCHUNK - 1) ? (CHUNK + 1) : CHUNK;   // nt up to 101 > 64 -> loop
  for (int u = tid; u < nt; u += 64) {
    const int t = t0 + u;
    const int st = stt[u];
    size_t fi = ((size_t)b * NS + t) * 16 + st;
    float fq = ws[OFF_FREQ + fi];
    float lv = ws[OFF_LFV + fi];
    ws[OFF_F0 + (size_t)b * NS + t] = (lv > 0.f) ? fq : 0.f;
  }
}

// ---------- K8: median-5 with edge padding ----------
__global__ __launch_bounds__(256) void k_median(const float* __restrict__ ws, float* __restrict__ out) {
  const int b = blockIdx.y;
  const int t = blockIdx.x * 256 + threadIdx.x;
  if (t >= NS) return;
  const float* f0 = ws + OFF_F0 + (size_t)b * NS;
  float a0 = f0[max(t - 2, 0)];
  float a1 = f0[max(t - 1, 0)];
  float a2 = f0[t];
  float a3 = f0[min(t + 1, NS - 1)];
  float a4 = f0[min(t + 2, NS - 1)];
#define SW(u, w) { float lo_ = fminf(u, w), hi_ = fmaxf(u, w); u = lo_; w = hi_; }
  SW(a0, a1) SW(a1, a2) SW(a2, a3) SW(a3, a4)
  SW(a0, a1) SW(a1, a2) SW(a2, a3)
  SW(a0, a1) SW(a1, a2)
#undef SW
  out[(size_t)b * NS + t] = a2;
}

extern "C" void kernel_launch(void* const* d_in, const int* in_sizes, int n_in,
                              void* d_out, int out_size, void* d_ws, size_t ws_size,
                              hipStream_t stream) {
  const float* x = (const float*)d_in[0];
  float* ws = (float*)d_ws;
  float* out = (float*)d_out;
  hipLaunchKernelGGL(k_setup, dim3(1), dim3(256), 0, stream, ws);
  hipLaunchKernelGGL(k_gpeak, dim3(64, NB), dim3(256), 0, stream, x, ws);
  hipLaunchKernelGGL(k_frames, dim3((NS + 3) / 4, NB), dim3(256), 0, stream, x, ws);
  hipLaunchKernelGGL(k_chunkmat, dim3(NCHUNK, NB), dim3(256), 0, stream, ws);
  hipLaunchKernelGGL(k_scan, dim3(NB), dim3(64), 0, stream, ws);
  hipLaunchKernelGGL(k_viterbi, dim3(NCHUNK, NB), dim3(256), 0, stream, ws);
  hipLaunchKernelGGL(k_compose, dim3(1), dim3(256), 0, stream, ws);
  hipLaunchKernelGGL(k_select, dim3(NCHUNK, NB), dim3(64), 0, stream, ws);
  hipLaunchKernelGGL(k_median, dim3((NS + 255) / 256, NB), dim3(256), 0, stream, ws, out);
}

// Round 12
// 249.576 us; speedup vs baseline: 3.6433x; 1.0272x over previous
//
#include <hip/hip_runtime.h>

#define NB 16
#define NT 960000
#define NS 6001
#define TOPK 15
#define NSTEPS 6000
#define CHUNK 100
#define NCHUNK 60
#define FLOORV -100000.0f

typedef __attribute__((ext_vector_type(8))) short short8;
typedef __attribute__((ext_vector_type(4))) float f32x4;
typedef __attribute__((ext_vector_type(2))) float f32x2;
typedef __attribute__((ext_vector_type(4))) unsigned int u32x4;

// ---- workspace layout (offsets in floats) — identical to r10 except GPK reuses OFF_UNUSED ----
constexpr size_t OFF_NACW  = 0;                                    // 216 floats (INVERSE nacw)
constexpr size_t OFF_WIN   = 256;                                  // 257 floats (hann window)
constexpr size_t OFF_FREQ  = 576;
constexpr size_t PERFR     = (size_t)NB * NS * 16;                 // per-frame arrays, K padded to 16
constexpr size_t OFF_LFV   = OFF_FREQ + PERFR;                     // packed: voiced? +log2(f) : -log2(f)
constexpr size_t OFF_DELTA = OFF_LFV + PERFR;
constexpr size_t OFF_GPK   = OFF_DELTA + PERFR;                    // gpeak partials NB*64 (was UNUSED)
constexpr size_t OFF_P     = OFF_GPK + PERFR;                      // NB*NCHUNK*256 chunk matrices
constexpr size_t OFF_VENT  = OFF_P + (size_t)NB * NCHUNK * 256;    // NB*(NCHUNK+1)*16 entry vectors
constexpr size_t OFF_VFIN  = OFF_VENT + (size_t)NB * (NCHUNK + 1) * 16; // unused
constexpr size_t OFF_F0    = OFF_VFIN + 256;                       // NB*NS f0 (pre-median)
constexpr size_t OFF_BS    = OFF_F0 + 96032;                       // (unused now)
constexpr size_t OFF_PTR   = OFF_BS + 2048;                        // uint8 ptrs NB*NSTEPS*16 bytes
constexpr size_t OFF_BMAP  = OFF_PTR + (size_t)NB * NSTEPS * 4;    // uint8 backmaps NB*NCHUNK*16 bytes

__device__ __forceinline__ unsigned ordf(float f) {
  unsigned u = __float_as_uint(f);
  return (u & 0x80000000u) ? ~u : (u | 0x80000000u);
}

// transition cost from packed lf-values (sign bit = unvoiced)
__device__ __forceinline__ float tr_of(float sa, float sb) {
  int xs = __float_as_int(sa) ^ __float_as_int(sb);
  float t = 0.35f * fabsf(sa - sb);
  t = (__float_as_int(sa) < 0) ? 0.f : t;   // both unvoiced -> 0
  return (xs < 0) ? 0.14f : t;              // mixed -> C_VUV
}

// ---------- K0: gpeak partials (per-block slot, no atomic) + setup in block(0,0) ----------
__global__ __launch_bounds__(256) void k_init(const float* __restrict__ x, float* __restrict__ ws) {
  const int b = blockIdx.y;
  const float4* xb = (const float4*)(x + (size_t)b * NT);
  const int n4 = NT / 4;
  float m = 0.f;
  for (int i = blockIdx.x * blockDim.x + threadIdx.x; i < n4; i += gridDim.x * blockDim.x) {
    float4 v = xb[i];
    m = fmaxf(m, fmaxf(fmaxf(fabsf(v.x), fabsf(v.y)), fmaxf(fabsf(v.z), fabsf(v.w))));
  }
  for (int off = 32; off; off >>= 1) m = fmaxf(m, __shfl_down(m, off));
  __shared__ float sm[4];
  if ((threadIdx.x & 63) == 0) sm[threadIdx.x >> 6] = m;
  __syncthreads();
  if (threadIdx.x == 0) {
    m = fmaxf(fmaxf(sm[0], sm[1]), fmaxf(sm[2], sm[3]));
    ws[OFF_GPK + b * 64 + blockIdx.x] = m;   // plain store to own slot
  }
  if (blockIdx.x == 0 && b == 0) {
    __shared__ float win[257];
    __shared__ float w0sh;
    const int tid = threadIdx.x;
    for (int n = tid; n < 257; n += 256) {
      float w = 0.5f * (1.0f - cosf((6.2831855f * (float)n) / 257.0f));
      win[n] = w;
      ws[OFF_WIN + n] = w;
    }
    __syncthreads();
    float s = 0.f;
    if (tid < 216) {
      for (int n = 0; n + tid < 257; ++n) s += win[n] * win[n + tid];
    }
    if (tid == 0) w0sh = s;
    __syncthreads();
    if (tid < 216) ws[OFF_NACW + tid] = w0sh / s;   // inverse of nacw
  }
}

__device__ __forceinline__ unsigned bf16rne(float f) {
  unsigned u = __float_as_uint(f);
  return (u + 0x7FFFu + ((u >> 16) & 1u)) >> 16;   // bf16 bits in low 16
}

__device__ __forceinline__ short8 bfrag(const char* p, int sh) {
  unsigned w0 = *(const unsigned*)(p);
  unsigned w1 = *(const unsigned*)(p + 4);
  unsigned w2 = *(const unsigned*)(p + 8);
  unsigned w3 = *(const unsigned*)(p + 12);
  unsigned w4 = *(const unsigned*)(p + 16);
  u32x4 o;
  o[0] = __builtin_amdgcn_alignbit(w1, w0, sh);
  o[1] = __builtin_amdgcn_alignbit(w2, w1, sh);
  o[2] = __builtin_amdgcn_alignbit(w3, w2, sh);
  o[3] = __builtin_amdgcn_alignbit(w4, w3, sh);
  return __builtin_bit_cast(short8, o);
}

// ---------- K1: one wave = one frame; bf16x3-split MFMA ACF; parallel top-k ----------
// per-wave LDS (floats), REGION-REUSED for 8 blocks/CU occupancy:
//   phase 1 (staging+MFMA): HI bf16[576] @[0,288) | LO @[288,576)
//   phase 2 (scatter):      ACF @[576,800)
//   phase 3 (candidates):   TQ @[0,216) over HI | LG @[288,504) over LO
//   phase 4 (top-k):        CK u64 @[800,1224) | SEL @[1224,1240)
__global__ __launch_bounds__(256, 8) void k_frames(const float* __restrict__ x, float* __restrict__ ws) {
  const int wv = threadIdx.x >> 6;
  const int g  = threadIdx.x & 63;
  const int s  = blockIdx.x * 4 + wv;
  const int b  = blockIdx.y;
  __shared__ __align__(16) float LA[4][1240];
  if (s >= NS) return;
  float* L = LA[wv];
  char* Lb = (char*)L;
  const size_t xb = (size_t)b * NT;
  const int c0 = 40 * s;               // float4 chunk base

  // ---- load frame ----
  float4 xv = make_float4(0.f, 0.f, 0.f, 0.f);
  if (c0 + g < NT / 4) xv = ((const float4*)(x + xb))[c0 + g];
  float x256 = 0.f;
  if (g == 0) {
    int i256 = 160 * s + 256;
    if (i256 < NT) x256 = x[xb + i256];
  }

  // ---- batch gpeak from partials (fmax of the same 64 block maxima: bit-identical) ----
  float gp = ws[OFF_GPK + b * 64 + g];
#pragma unroll
  for (int off = 32; off; off >>= 1) gp = fmaxf(gp, __shfl_xor(gp, off));

  // ---- mean over 257 raw samples ----
  float ps = ((xv.x + xv.y) + (xv.z + xv.w)) + x256;
#pragma unroll
  for (int off = 32; off; off >>= 1) ps += __shfl_xor(ps, off);
  const float mean = ps / 257.0f;

  // ---- window + local peak ----
  float4 w4 = ((const float4*)(ws + OFF_WIN))[g];
  float4 f4;
  f4.x = (xv.x - mean) * w4.x;
  f4.y = (xv.y - mean) * w4.y;
  f4.z = (xv.z - mean) * w4.z;
  f4.w = (xv.w - mean) * w4.w;
  float fr256 = 0.f;
  if (g == 0) fr256 = (x256 - mean) * ws[OFF_WIN + 256];
  float apk = fmaxf(fmaxf(fabsf(f4.x), fabsf(f4.y)), fmaxf(fabsf(f4.z), fabsf(f4.w)));
  if (g == 0) apk = fmaxf(apk, fabsf(fr256));
#pragma unroll
  for (int off = 32; off; off >>= 1) apk = fmaxf(apk, __shfl_xor(apk, off));

  // ---- build hi/lo bf16 buffers: buf[i] = fr[i-16], zero-padded to 576 elems ----
  {
    unsigned hx = bf16rne(f4.x), hy = bf16rne(f4.y), hz = bf16rne(f4.z), hw = bf16rne(f4.w);
    float lx = f4.x - __uint_as_float(hx << 16);
    float ly = f4.y - __uint_as_float(hy << 16);
    float lz = f4.z - __uint_as_float(hz << 16);
    float lw = f4.w - __uint_as_float(hw << 16);
    unsigned ph0 = hx | (hy << 16), ph1 = hz | (hw << 16);
    unsigned pl0 = bf16rne(lx) | (bf16rne(ly) << 16);
    unsigned pl1 = bf16rne(lz) | (bf16rne(lw) << 16);
    if (g < 8) { L[g] = 0.f; L[288 + g] = 0.f; }                     // elems 0..15
    f32x2 vh = {__uint_as_float(ph0), __uint_as_float(ph1)};
    f32x2 vl = {__uint_as_float(pl0), __uint_as_float(pl1)};
    *(f32x2*)&L[8 + 2 * g] = vh;                                     // elems 16+4g..19+4g
    *(f32x2*)&L[288 + 8 + 2 * g] = vl;
    if (g < 76) {                                                    // elems 272..575 zero
      f32x2 z = {0.f, 0.f};
      *(f32x2*)&L[136 + 2 * g] = z;
      *(f32x2*)&L[288 + 136 + 2 * g] = z;
    }
    if (g == 0) {                                                    // patch elem 272 = fr[256]
      unsigned h2 = bf16rne(fr256);
      float l2 = fr256 - __uint_as_float(h2 << 16);
      ((unsigned short*)Lb)[272] = (unsigned short)h2;
      ((unsigned short*)(Lb + 1152))[272] = (unsigned short)bf16rne(l2);
    }
  }
  __builtin_amdgcn_wave_barrier();

  // ---- ACF via MFMA: C[a][b] = sum_k buf[k+16a]*buf[k+b] = acf[16a-b] ----
  const int bcol = g & 15, h = g >> 4;
  const int sh = 16 * (bcol & 1);
  const int hi4 = ((bcol & 3) >= 2) ? 4 : 0;
  const int Ab0 = 16 * h + 32 * bcol;
  const int Bb0 = 16 * h + ((2 * bcol) & ~7) + hi4;
  const char* Hb = Lb;
  const char* Ob = Lb + 1152;
  f32x4 acc = {0.f, 0.f, 0.f, 0.f};
#pragma unroll
  for (int kk = 0; kk < 10; ++kk) {
    short8 ah = __builtin_bit_cast(short8, *(const u32x4*)(Hb + Ab0 + 64 * kk));
    short8 al = __builtin_bit_cast(short8, *(const u32x4*)(Ob + Ab0 + 64 * kk));
    short8 bh = bfrag(Hb + Bb0 + 64 * kk, sh);
    short8 bl = bfrag(Ob + Bb0 + 64 * kk, sh);
    acc = __builtin_amdgcn_mfma_f32_16x16x32_bf16(ah, bh, acc, 0, 0, 0);
    acc = __builtin_amdgcn_mfma_f32_16x16x32_bf16(ah, bl, acc, 0, 0, 0);
    acc = __builtin_amdgcn_mfma_f32_16x16x32_bf16(al, bh, acc, 0, 0, 0);
  }
  __builtin_amdgcn_wave_barrier();
  // scatter: lane holds C rows 4h+r, col bcol
#pragma unroll
  for (int r = 0; r < 4; ++r) {
    int arow = 4 * h + r;
    int tau = 16 * arow - bcol;
    if (arow == 0 ? (bcol == 0) : (tau <= 215)) L[576 + (arow ? tau : 0)] = acc[r];
  }
  __builtin_amdgcn_wave_barrier();

  // ---- nacf + candidates (lane g<53: candidates 4g..4g+3); fq deferred ----
  const float inv0 = 1.0f / L[576];
  bool  flv[4] = {false, false, false, false};
  float lgv[4];
  if (g < 53) {
    f32x4 A4 = *(const f32x4*)&L[576 + 4 * g];
    f32x2 A2 = *(const f32x2*)&L[580 + 4 * g];
    f32x4 I4 = *(const f32x4*)(ws + OFF_NACW + 4 * g);
    f32x2 I2 = *(const f32x2*)(ws + OFF_NACW + 4 * g + 4);
    float nn[6];
    nn[0] = A4[0] * inv0 * I4[0];
    nn[1] = A4[1] * inv0 * I4[1];
    nn[2] = A4[2] * inv0 * I4[2];
    nn[3] = A4[3] * inv0 * I4[3];
    nn[4] = A2.x * inv0 * I2.x;
    nn[5] = A2.y * inv0 * I2.y;
    float tqv[4];
#pragma unroll
    for (int a = 0; a < 4; ++a) {
      float pm = nn[a], cm = nn[a + 1], nm = nn[a + 2];
      bool flag = (cm - pm >= 0.f) && (nm - cm <= 0.f) && (cm > 0.225f);
      float dr = (0.5f * (nm - pm)) / ((2.0f * cm - nm) - pm);   // exact div (decision-adjacent)
      float tq = dr + (float)(4 * g + a);
      tq = (tq > 0.f) ? tq : 0.f;     // NaN -> 0: output-invariant
      float l1p = __log2f(1.0f + tq);
      float lg = cm;
      if (lg > 1.0f) lg = __builtin_amdgcn_rcpf(lg);
      lg = lg - 0.01f * (l1p - 7.736965594166206f);   // == cm' - 0.01*log2(75/fq)
      flv[a] = flag;
      tqv[a] = tq;
      lgv[a] = flag ? lg : FLOORV;
    }
    f32x4 to_ = {tqv[0], tqv[1], tqv[2], tqv[3]};
    f32x4 lo_ = {lgv[0], lgv[1], lgv[2], lgv[3]};
    *(f32x4*)&L[0 + 4 * g] = to_;
    *(f32x4*)&L[288 + 4 * g] = lo_;
  }

  // ---- top-15 selection ----
  unsigned long long bb0b = __ballot(flv[0]);
  unsigned long long bb1 = __ballot(flv[1]);
  unsigned long long bb2 = __ballot(flv[2]);
  unsigned long long bb3 = __ballot(flv[3]);
  const int nv = __popcll(bb0b) + __popcll(bb1) + __popcll(bb2) + __popcll(bb3);
  int* sel = (int*)&L[1224];
  if (nv > 0) {
    unsigned long long below = (1ull << g) - 1ull;
    int base = __popcll(bb0b & below) + __popcll(bb1 & below) +
               __popcll(bb2 & below) + __popcll(bb3 & below);
    if (nv <= TOPK) {
      if (g < 53) {
        int cnt = base;
#pragma unroll
        for (int a = 0; a < 4; ++a) {
          int c = 4 * g + a;
          if (flv[a]) {
            sel[cnt] = c;
            ++cnt;
          } else {
            int ur = c - cnt;
            if (ur < TOPK - nv) sel[nv + ur] = c;
          }
        }
      }
    } else {
      unsigned long long* CK = (unsigned long long*)&L[800];   // 212 keys fit [800,1224)
      if (g < 53) {
        int cnt = base;
#pragma unroll
        for (int a = 0; a < 4; ++a) {
          if (flv[a]) {
            CK[cnt] = (((unsigned long long)ordf(lgv[a])) << 32)
                    | (unsigned long long)(0xFFFFFFFFu - (unsigned)(4 * g + a));
            ++cnt;
          }
        }
      }
      __builtin_amdgcn_wave_barrier();
      for (int l = g; l < nv; l += 64) {
        unsigned long long kl = CK[l];
        int rank = 0;
        for (int m = 0; m < nv; ++m) rank += (CK[m] > kl) ? 1 : 0;
        if (rank < TOPK) sel[rank] = (int)(0xFFFFFFFFu - (unsigned)(kl & 0xFFFFFFFFull));
      }
    }
  }
  __builtin_amdgcn_wave_barrier();

  // ---- per-frame outputs (lanes 0..15; slot 15 = fixed dead-state fill) ----
  if (g < 16) {
    size_t fi = ((size_t)b * NS + s) * 16 + g;
    if (g == TOPK) {
      ws[OFF_FREQ + fi] = 0.f;
      ws[OFF_LFV + fi] = -1.0f;   // unvoiced sentinel (state 15 is never selectable)
      ws[OFF_DELTA + fi] = 0.f;
    } else {
      int c = (nv == 0) ? g : sel[g];
      float tq = L[0 + c];
      float lg = L[288 + c];
      float fq = 16000.0f / (1.0f + tq);                  // same div, same input bits as before
      int voi = (lg > FLOORV) && (fq < 600.0f);
      float inten = (apk > gp) ? 1.0f : apk * __builtin_amdgcn_rcpf(gp);
      float luv = 0.45f + fmaxf(2.0f - inten * 48.333333333333336f, 0.f);
      float l2 = __log2f(fq);
      float dlt = voi ? (lg - 0.01f * (9.228818690495881f - l2)) : luv;
      ws[OFF_FREQ + fi] = fq;
      ws[OFF_LFV + fi] = voi ? l2 : -l2;
      ws[OFF_DELTA + fi] = dlt;
    }
  }
}

// ---------- K2: per-chunk max-plus product matrices (double-buffered, 1 barrier/step) ----------
__global__ __launch_bounds__(256) void k_chunkmat(float* __restrict__ ws) {
  const int c = blockIdx.x, b = blockIdx.y, tid = threadIdx.x;
  const int i = tid >> 4, j = tid & 15;
  __shared__ float MT[2][16][20];     // MT[buf][j][k], rows 80B (16B-aligned)
  __shared__ float Psh[2][16][20];
  const float* LFV = ws + OFF_LFV;
  const float* DEL = ws + OFF_DELTA;
  const size_t fb = (size_t)b * NS;
  const int t0 = c * CHUNK;
  float sA = LFV[(fb + t0) * 16 + i];
  float sB = LFV[(fb + t0 + 1) * 16 + j];
  float dB = DEL[(fb + t0 + 1) * 16 + j];
  Psh[0][i][j] = (i == j) ? 0.f : -INFINITY;   // max-plus identity
  int src = 0;
  float pn = 0.f;
  for (int s = 1; s <= CHUNK; ++s) {
    const int mb = s & 1;
    MT[mb][j][i] = dB - tr_of(sA, sB);         // transposed store
    __syncthreads();                            // MT[mb] + Psh[src] visible; prior reads done
    if (s < CHUNK) {
      const int t = t0 + s;
      sA = LFV[(fb + t) * 16 + i];
      sB = LFV[(fb + t + 1) * 16 + j];
      dB = DEL[(fb + t + 1) * 16 + j];
    }
    const float* Pr = &Psh[src][i][0];
    const float* Mr = &MT[mb][j][0];
    f32x4 t0v = *(const f32x4*)(Pr)      + *(const f32x4*)(Mr);
    f32x4 t1v = *(const f32x4*)(Pr + 4)  + *(const f32x4*)(Mr + 4);
    f32x4 t2v = *(const f32x4*)(Pr + 8)  + *(const f32x4*)(Mr + 8);
    f32x4 t3v = *(const f32x4*)(Pr + 12) + *(const f32x4*)(Mr + 12);
    f32x4 m01 = {fmaxf(t0v[0], t0v[1]), fmaxf(t0v[2], t0v[3]), fmaxf(t1v[0], t1v[1]), fmaxf(t1v[2], t1v[3])};
    f32x4 m23 = {fmaxf(t2v[0], t2v[1]), fmaxf(t2v[2], t2v[3]), fmaxf(t3v[0], t3v[1]), fmaxf(t3v[2], t3v[3])};
    pn = fmaxf(fmaxf(fmaxf(m01[0], m01[1]), fmaxf(m01[2], m01[3])),
               fmaxf(fmaxf(m23[0], m23[1]), fmaxf(m23[2], m23[3])));
    if (j == 15) pn = -INFINITY;               // dead column stays dead
    Psh[src ^ 1][i][j] = pn;
    src ^= 1;
  }
  ws[OFF_P + ((size_t)(b * NCHUNK + c)) * 256 + tid] = pn;
}

// ---------- K3: scan chunk matrices -> entry value vectors (1 wave / batch) ----------
__global__ __launch_bounds__(64) void k_scan(float* __restrict__ ws) {
  const int b = blockIdx.x, l = threadIdx.x;
  __shared__ float v[16];
  const float* DEL = ws + OFF_DELTA;
  const size_t fb = (size_t)b * NS;
  if (l < 16) {
    float d0 = DEL[fb * 16 + l];
    v[l] = d0;
    ws[OFF_VENT + ((size_t)b * (NCHUNK + 1)) * 16 + l] = d0;
  }
  __syncthreads();
  const float4* Pg = (const float4*)(ws + OFF_P + (size_t)b * NCHUNK * 256);
  const int k = l >> 2;
  float4 cur = Pg[l];    // element offset 4l = k*16 + (l&3)*4
  for (int c = 0; c < NCHUNK; ++c) {
    float4 nxt = cur;
    if (c + 1 < NCHUNK) nxt = Pg[(size_t)(c + 1) * 64 + l];
    float vk = (k < 15) ? v[k] : -INFINITY;
    float4 t;
    t.x = vk + cur.x; t.y = vk + cur.y; t.z = vk + cur.z; t.w = vk + cur.w;
    if (k == 15) { t.x = -INFINITY; t.y = -INFINITY; t.z = -INFINITY; t.w = -INFINITY; }
#pragma unroll
    for (int off = 4; off < 64; off <<= 1) {
      t.x = fmaxf(t.x, __shfl_xor(t.x, off));
      t.y = fmaxf(t.y, __shfl_xor(t.y, off));
      t.z = fmaxf(t.z, __shfl_xor(t.z, off));
      t.w = fmaxf(t.w, __shfl_xor(t.w, off));
    }
    __syncthreads();                 // all v[k] reads done before overwrite
    if (l < 4) {
      *(float4*)&v[4 * l] = *(float4*)&t;
      ((float4*)(ws + OFF_VENT + ((size_t)b * (NCHUNK + 1) + c + 1) * 16))[l] = *(float4*)&t;
    }
    __syncthreads();                 // new v visible
    cur = nxt;
  }
}

// ---------- K4: per-chunk sequential Viterbi (exact op order, 1 barrier/step) ----------
__global__ __launch_bounds__(256) void k_viterbi(float* __restrict__ ws) {
  const int c = blockIdx.x, b = blockIdx.y, tid = threadIdx.x;
  const int i = tid & 15, j = tid >> 4;
  __shared__ float val[2][16];
  __shared__ __align__(16) unsigned char ptl[CHUNK][16];
  const float* LFV = ws + OFF_LFV;
  const float* DEL = ws + OFF_DELTA;
  const size_t fb = (size_t)b * NS;
  const int t0 = c * CHUNK;
  if (tid < 16) {
    val[0][tid] = ws[OFF_VENT + ((size_t)b * (NCHUNK + 1) + c) * 16 + tid];
    val[1][tid] = -INFINITY;
  }
  float sA = LFV[(fb + t0) * 16 + i];
  float sB = LFV[(fb + t0 + 1) * 16 + j];
  float dB = DEL[(fb + t0 + 1) * 16 + j];
  int src = 0;
  for (int s = 1; s <= CHUNK; ++s) {
    __syncthreads();                 // val[src] writes from prev step visible; prev reads done
    float sc = (val[src][i] - tr_of(sA, sB)) + dB;   // reference op order
    if (i == 15) sc = -INFINITY;
    if (s < CHUNK) {
      const int t = t0 + s;
      sA = LFV[(fb + t) * 16 + i];
      sB = LFV[(fb + t + 1) * 16 + j];
      dB = DEL[(fb + t + 1) * 16 + j];
    }
    float mx = sc;
#pragma unroll
    for (int off = 1; off < 16; off <<= 1) mx = fmaxf(mx, __shfl_xor(mx, off));
    unsigned long long bal = __ballot(sc == mx);
    int nib = (int)((bal >> (tid & 48)) & 0xFFFFull);
    int bi = __ffs(nib) - 1;                     // lowest i on ties (reference argmax)
    if (i == 0 && j < 15) {
      val[src ^ 1][j] = mx;
      ptl[s - 1][j] = (unsigned char)bi;
    }
    src ^= 1;
  }
  __syncthreads();
  // dump ptrs coalesced (CHUNK*4 = 400 u32 > 256 threads -> loop)
  unsigned* pg = (unsigned*)(ws + OFF_PTR);
  for (int idx = tid; idx < CHUNK * 4; idx += 256)
    pg[((size_t)b * NSTEPS + t0) * 4 + idx] = ((unsigned*)ptl)[idx];
  // per-chunk backtrack map: exit state -> entry state
  if (tid < TOPK) {
    int st = tid;
#pragma unroll 1
    for (int s2 = CHUNK - 1; s2 >= 0; --s2) st = ptl[s2][st];
    ((unsigned char*)(ws + OFF_BMAP))[((size_t)(b * NCHUNK + c)) * 16 + tid] = (unsigned char)st;
  }
}

// ---------- K5: fused compose-replay + per-chunk state walk -> f0 (exact r10 semantics) ----------
__global__ __launch_bounds__(64) void k_sel(float* __restrict__ ws) {
  const int c = blockIdx.x, b = blockIdx.y, tid = threadIdx.x;
  const int t0 = c * CHUNK;
  __shared__ __align__(4) unsigned char pl[CHUNK][16];
  __shared__ __align__(4) unsigned char bmS[NCHUNK][16];
  __shared__ int bsS[NCHUNK + 1];
  __shared__ int stt[CHUNK + 1];
  const unsigned* pgu = (const unsigned*)((const unsigned char*)(ws + OFF_PTR) + ((size_t)b * NSTEPS + t0) * 16);
  for (int idx = tid; idx < CHUNK * 4; idx += 64) ((unsigned*)pl)[idx] = pgu[idx];
  const unsigned* bgu = (const unsigned*)((const unsigned char*)(ws + OFF_BMAP) + (size_t)b * NCHUNK * 16);
  for (int idx = tid; idx < NCHUNK * 4; idx += 64) ((unsigned*)bmS)[idx] = bgu[idx];
  __syncthreads();
  if (tid == 0) {
    // compose (strict > first-max over final value vector, then backward bmap walk) — r10 k_compose verbatim
    float best = -INFINITY; int bi = 0;
    for (int jj = 0; jj < TOPK; ++jj) {
      float vv = ws[OFF_VENT + ((size_t)b * (NCHUNK + 1) + NCHUNK) * 16 + jj];
      if (vv > best) { best = vv; bi = jj; }
    }
    int st = bi;
    bsS[NCHUNK] = st;
    for (int cc = NCHUNK - 1; cc >= 0; --cc) { st = bmS[cc][st]; bsS[cc] = st; }
    // chunk-c walk anchored at bsS[c+1] — r10 k_select verbatim
    int s2t = bsS[c + 1];
    stt[CHUNK] = s2t;
    for (int s2 = CHUNK; s2 >= 1; --s2) { s2t = pl[s2 - 1][s2t]; stt[s2 - 1] = s2t; }
  }
  __syncthreads();
  const int nt = (c == NCHUNK - 1) ? (CHUNK + 1) : CHUNK;
  for (int u = tid; u < nt; u += 64) {
    const int t = t0 + u;
    const int st = stt[u];
    size_t fi = ((size_t)b * NS + t) * 16 + st;
    float fq = ws[OFF_FREQ + fi];
    float lv = ws[OFF_LFV + fi];
    ws[OFF_F0 + (size_t)b * NS + t] = (lv > 0.f) ? fq : 0.f;
  }
}

// ---------- K6: median-5 with edge padding (r10 verbatim) ----------
__global__ __launch_bounds__(256) void k_median(const float* __restrict__ ws, float* __restrict__ out) {
  const int b = blockIdx.y;
  const int t = blockIdx.x * 256 + threadIdx.x;
  if (t >= NS) return;
  const float* f0 = ws + OFF_F0 + (size_t)b * NS;
  float a0 = f0[max(t - 2, 0)];
  float a1 = f0[max(t - 1, 0)];
  float a2 = f0[t];
  float a3 = f0[min(t + 1, NS - 1)];
  float a4 = f0[min(t + 2, NS - 1)];
#define SW(u, w) { float lo_ = fminf(u, w), hi_ = fmaxf(u, w); u = lo_; w = hi_; }
  SW(a0, a1) SW(a1, a2) SW(a2, a3) SW(a3, a4)
  SW(a0, a1) SW(a1, a2) SW(a2, a3)
  SW(a0, a1) SW(a1, a2)
#undef SW
  out[(size_t)b * NS + t] = a2;
}

extern "C" void kernel_launch(void* const* d_in, const int* in_sizes, int n_in,
                              void* d_out, int out_size, void* d_ws, size_t ws_size,
                              hipStream_t stream) {
  const float* x = (const float*)d_in[0];
  float* ws = (float*)d_ws;
  float* out = (float*)d_out;
  hipLaunchKernelGGL(k_init, dim3(64, NB), dim3(256), 0, stream, x, ws);
  hipLaunchKernelGGL(k_frames, dim3((NS + 3) / 4, NB), dim3(256), 0, stream, x, ws);
  hipLaunchKernelGGL(k_chunkmat, dim3(NCHUNK, NB), dim3(256), 0, stream, ws);
  hipLaunchKernelGGL(k_scan, dim3(NB), dim3(64), 0, stream, ws);
  hipLaunchKernelGGL(k_viterbi, dim3(NCHUNK, NB), dim3(256), 0, stream, ws);
  hipLaunchKernelGGL(k_sel, dim3(NCHUNK, NB), dim3(64), 0, stream, ws);
  hipLaunchKernelGGL(k_median, dim3((NS + 255) / 256, NB), dim3(256), 0, stream, ws, out);
}